// Round 5
// baseline (332.131 us; speedup 1.0000x reference)
//
#include <hip/hip_runtime.h>
#include <hip/hip_bf16.h>
#include <math.h>

#define Bn 512
#define Vn 6890
#define Jn 24
#define NBn 10
#define Pn 207
#define N3n 20670   // Vn*3

__constant__ int c_par[24] = {-1,0,0,0,1,2,3,4,5,6,7,8,9,9,9,12,13,14,16,17,18,19,20,21};

// ---------------- Kernel 1a: partial JS/Jt sums over V chunks ----------------
// grid = (72, 8) : x = j*3+c, y = V-chunk. 256 threads.
__global__ __launch_bounds__(256) void k_jsjt_part(
    const float* __restrict__ Jreg, const float* __restrict__ vtpl,
    const float* __restrict__ sdirs, float* __restrict__ part)
{
  const int bid = blockIdx.x;           // 0..71 = j*3+c
  const int chunk = blockIdx.y;
  const int j = bid / 3, c = bid % 3;
  const int tid = threadIdx.x;
  const int vlo = chunk * 862;
  const int vhi = min(Vn, vlo + 862);
  float acc[11];
#pragma unroll
  for (int k = 0; k < 11; k++) acc[k] = 0.f;
  for (int v = vlo + tid; v < vhi; v += 256) {
    float w = Jreg[(size_t)j * Vn + v];
    int n = v * 3 + c;
#pragma unroll
    for (int l = 0; l < 10; l++) acc[l] += w * sdirs[(size_t)n * 10 + l];
    acc[10] += w * vtpl[n];
  }
  __shared__ float red[256];
  for (int k = 0; k < 11; k++) {
    red[tid] = acc[k];
    __syncthreads();
    for (int s = 128; s > 0; s >>= 1) {
      if (tid < s) red[tid] += red[tid + s];
      __syncthreads();
    }
    if (tid == 0) part[(size_t)chunk * 792 + bid * 11 + k] = red[0];
    __syncthreads();
  }
}

// ---------------- Kernel 1b: reduce partials -> JS, Jt ----------------
__global__ __launch_bounds__(1024) void k_jsjt_red(
    const float* __restrict__ part, float* __restrict__ JS, float* __restrict__ Jt)
{
  const int t = threadIdx.x;
  if (t >= 792) return;
  float s = 0.f;
#pragma unroll
  for (int y = 0; y < 8; y++) s += part[(size_t)y * 792 + t];
  int bid = t / 11, k = t % 11;
  if (k < 10) JS[bid * 10 + k] = s;
  else        Jt[bid] = s;
}

// ---------------- Kernel 2: per-batch pose pipeline (1 wave per batch) ----------------
__global__ __launch_bounds__(64) void k_pose(
    const float* __restrict__ betas, const float* __restrict__ body_pose,
    const float* __restrict__ gorient, const float* __restrict__ transl,
    const float* __restrict__ JS, const float* __restrict__ Jt,
    float* __restrict__ pf_ws, float* __restrict__ Ar_ws,
    float* __restrict__ out_joints)
{
  const int b = blockIdx.x;
  const int tid = threadIdx.x;
  __shared__ float Rs[24][9];
  __shared__ float jnt[24][3];
  __shared__ float rel[24][3];
  __shared__ float A_s[24][12];

  if (tid < 24) {
    float x, y, z;
    if (tid == 0) { x = gorient[b*3+0]; y = gorient[b*3+1]; z = gorient[b*3+2]; }
    else { int o = b*69 + (tid-1)*3; x = body_pose[o]; y = body_pose[o+1]; z = body_pose[o+2]; }
    float ang = sqrtf(x*x + y*y + z*z) + 1e-8f;
    float inv = 1.0f / ang;
    float ux = x*inv, uy = y*inv, uz = z*inv;
    float s = sinf(ang), cc = cosf(ang), omc = 1.0f - cc;
    float K[9] = {0.f, -uz, uy,  uz, 0.f, -ux,  -uy, ux, 0.f};
#pragma unroll
    for (int mm = 0; mm < 3; mm++)
#pragma unroll
      for (int nn = 0; nn < 3; nn++) {
        float kk = K[mm*3+0]*K[0+nn] + K[mm*3+1]*K[3+nn] + K[mm*3+2]*K[6+nn];
        float eye = (mm == nn) ? 1.0f : 0.0f;
        Rs[tid][mm*3+nn] = eye + s*K[mm*3+nn] + omc*kk;
      }
  }
  for (int idx = tid; idx < 72; idx += 64) {
    float a = Jt[idx];
#pragma unroll
    for (int l = 0; l < 10; l++) a += betas[b*10 + l] * JS[idx*10 + l];
    jnt[idx/3][idx%3] = a;
  }
  __syncthreads();
  for (int idx = tid; idx < Pn; idx += 64) {
    int j = 1 + idx / 9, e = idx % 9;
    float eye = (e == 0 || e == 4 || e == 8) ? 1.0f : 0.0f;
    pf_ws[(size_t)b * Pn + idx] = Rs[j][e] - eye;
  }
  for (int idx = tid; idx < 72; idx += 64) {
    int j = idx/3, cc = idx%3;
    float r = jnt[j][cc];
    if (j > 0) r -= jnt[c_par[j]][cc];
    rel[j][cc] = r;
  }
  __syncthreads();
  if (tid < 12) {
    int m = tid/4, nn = tid%4;
    A_s[0][tid] = (nn < 3) ? Rs[0][m*3+nn] : rel[0][m];
  }
  __syncthreads();
  for (int i = 1; i < 24; i++) {
    if (tid < 12) {
      int m = tid/4, nn = tid%4;
      int p = c_par[i];
      float v;
      if (nn < 3)
        v = A_s[p][m*4+0]*Rs[i][0+nn] + A_s[p][m*4+1]*Rs[i][3+nn] + A_s[p][m*4+2]*Rs[i][6+nn];
      else
        v = A_s[p][m*4+0]*rel[i][0] + A_s[p][m*4+1]*rel[i][1] + A_s[p][m*4+2]*rel[i][2] + A_s[p][m*4+3];
      A_s[i][tid] = v;
    }
    __syncthreads();
  }
  for (int idx = tid; idx < 72; idx += 64) {
    int j = idx/3, cc = idx%3;
    out_joints[(size_t)b * 72 + idx] = A_s[j][cc*4+3] + transl[b*3+cc];
  }
  for (int idx = tid; idx < 288; idx += 64) {
    int j = idx/12, r = idx%12, m = r/4, nn = r%4;
    float v;
    if (nn < 3) v = A_s[j][m*4+nn];
    else v = A_s[j][m*4+3] - (A_s[j][m*4+0]*jnt[j][0] + A_s[j][m*4+1]*jnt[j][1] + A_s[j][m*4+2]*jnt[j][2]);
    Ar_ws[(size_t)b * 288 + idx] = v;
  }
}

// ---------------- Kernel 3: thread-per-vertex fused blendshapes + skinning ----------------
// grid = (64 b-tiles, 27 v-tiles), 256 threads. Thread = 1 vertex x 8 batches.
__global__ __launch_bounds__(256, 4) void k_verts2(
    const float* __restrict__ betas, const float* __restrict__ transl,
    const float* __restrict__ vtpl, const float* __restrict__ sdirs,
    const float* __restrict__ pdirs, const float* __restrict__ W,
    const float* __restrict__ pf_ws, const float* __restrict__ Ar_ws,
    float* __restrict__ out)
{
  const int tid = threadIdx.x;
  const int b0 = blockIdx.x * 8;
  const int v  = blockIdx.y * 256 + tid;
  const bool vok = (v < Vn);
  const int n = v * 3;

  __shared__ __align__(16) float pf_s[Pn][8];
  __shared__ __align__(16) float Ar_s[8][288];
  __shared__ float betas_s[8][NBn];
  __shared__ float transl_s[8][3];

  for (int idx = tid; idx < Pn * 8; idx += 256) {
    int p = idx >> 3, bi = idx & 7;
    pf_s[p][bi] = pf_ws[(size_t)(b0 + bi) * Pn + p];
  }
  for (int idx = tid; idx < 8 * 288; idx += 256)
    Ar_s[idx / 288][idx % 288] = Ar_ws[(size_t)b0 * 288 + idx];
  for (int idx = tid; idx < 8 * NBn; idx += 256)
    betas_s[idx / NBn][idx % NBn] = betas[(size_t)b0 * NBn + idx];
  if (tid < 24) transl_s[tid / 3][tid % 3] = transl[(size_t)b0 * 3 + tid];
  __syncthreads();

  float ax[8], ay[8], az[8];
#pragma unroll
  for (int i = 0; i < 8; i++) { ax[i] = 0.f; ay[i] = 0.f; az[i] = 0.f; }

  // pose-blendshape GEMM: acc[c][bi] += pf[bi][p] * pdirs[p][n+c]
  for (int p = 0; p < Pn; p++) {
    float px = 0.f, py = 0.f, pz = 0.f;
    if (vok) {
      px = pdirs[(size_t)p * N3n + n];
      py = pdirs[(size_t)p * N3n + n + 1];
      pz = pdirs[(size_t)p * N3n + n + 2];
    }
    float f[8];
    *(float4*)&f[0] = *(const float4*)&pf_s[p][0];
    *(float4*)&f[4] = *(const float4*)&pf_s[p][4];
#pragma unroll
    for (int bi = 0; bi < 8; bi++) {
      ax[bi] += f[bi] * px;
      ay[bi] += f[bi] * py;
      az[bi] += f[bi] * pz;
    }
  }

  // v_shaped = v_template + betas . shapedirs   (sdirs: [v][c][l] contiguous 30)
  float sd[30], vt[3] = {0.f, 0.f, 0.f};
#pragma unroll
  for (int i = 0; i < 30; i++) sd[i] = 0.f;
  if (vok) {
#pragma unroll
    for (int i = 0; i < 30; i++) sd[i] = sdirs[(size_t)n * 10 + i];
    vt[0] = vtpl[n]; vt[1] = vtpl[n + 1]; vt[2] = vtpl[n + 2];
  }
#pragma unroll
  for (int bi = 0; bi < 8; bi++) {
    float s0 = vt[0], s1 = vt[1], s2 = vt[2];
#pragma unroll
    for (int l = 0; l < 10; l++) {
      float bb = betas_s[bi][l];
      s0 += bb * sd[l];
      s1 += bb * sd[10 + l];
      s2 += bb * sd[20 + l];
    }
    ax[bi] += s0; ay[bi] += s1; az[bi] += s2;
  }

  // skinning weights for this vertex
  float Wr[24];
#pragma unroll
  for (int j = 0; j < 24; j++) Wr[j] = 0.f;
  if (vok) {
    const float4* wp = (const float4*)(W + (size_t)v * 24);
#pragma unroll
    for (int q = 0; q < 6; q++) {
      float4 f = wp[q];
      Wr[4*q] = f.x; Wr[4*q+1] = f.y; Wr[4*q+2] = f.z; Wr[4*q+3] = f.w;
    }
  }

  for (int bi = 0; bi < 8; bi++) {
    float t0=0.f,t1=0.f,t2=0.f,t3=0.f,t4=0.f,t5=0.f,t6=0.f,t7=0.f,t8=0.f,t9=0.f,t10=0.f,t11=0.f;
    const float4* arb = (const float4*)(Ar_s[bi]);   // wave-uniform -> broadcast
#pragma unroll
    for (int j = 0; j < 24; j++) {
      float w = Wr[j];
      float4 a0 = arb[j*3 + 0];
      float4 a1 = arb[j*3 + 1];
      float4 a2 = arb[j*3 + 2];
      t0 += w*a0.x; t1 += w*a0.y; t2  += w*a0.z; t3  += w*a0.w;
      t4 += w*a1.x; t5 += w*a1.y; t6  += w*a1.z; t7  += w*a1.w;
      t8 += w*a2.x; t9 += w*a2.y; t10 += w*a2.z; t11 += w*a2.w;
    }
    if (vok) {
      float x = ax[bi], y = ay[bi], z = az[bi];
      size_t o = ((size_t)(b0 + bi) * Vn + v) * 3;
      out[o]     = t0*x + t1*y + t2*z  + t3  + transl_s[bi][0];
      out[o + 1] = t4*x + t5*y + t6*z  + t7  + transl_s[bi][1];
      out[o + 2] = t8*x + t9*y + t10*z + t11 + transl_s[bi][2];
    }
  }
}

extern "C" void kernel_launch(void* const* d_in, const int* in_sizes, int n_in,
                              void* d_out, int out_size, void* d_ws, size_t ws_size,
                              hipStream_t stream)
{
  // Route inputs by element count (robust to input-order permutations).
  const float *betas=nullptr, *bpose=nullptr, *gorient=nullptr, *transl=nullptr,
              *vtpl=nullptr, *sdirs=nullptr, *pdirs=nullptr, *Jreg=nullptr, *W=nullptr;
  int seen1536 = 0, seen165360 = 0;
  for (int i = 0; i < n_in; i++) {
    const float* p = (const float*)d_in[i];
    switch (in_sizes[i]) {
      case 5120:    betas = p; break;
      case 35328:   bpose = p; break;
      case 20670:   vtpl  = p; break;
      case 206700:  sdirs = p; break;
      case 4278690: pdirs = p; break;
      case 1536:    if (seen1536++ == 0) gorient = p; else transl = p; break;
      case 165360:  if (seen165360++ == 0) Jreg = p; else W = p; break;
      default: break;
    }
  }
  float* out = (float*)d_out;

  float* ws   = (float*)d_ws;
  float* part = ws;                       // 8*792 = 6336
  float* JS   = ws + 6336;                // 720
  float* Jt   = ws + 7056;                // 72
  float* pf   = ws + 7128;                // 512*207 = 105984
  float* Ar   = ws + 7128 + Bn * Pn;      // 512*288 = 147456

  k_jsjt_part<<<dim3(72, 8), 256, 0, stream>>>(Jreg, vtpl, sdirs, part);
  k_jsjt_red<<<1, 1024, 0, stream>>>(part, JS, Jt);
  k_pose<<<Bn, 64, 0, stream>>>(betas, bpose, gorient, transl, JS, Jt, pf, Ar,
                                out + (size_t)Bn * Vn * 3);
  k_verts2<<<dim3(Bn / 8, (Vn + 255) / 256), 256, 0, stream>>>(
      betas, transl, vtpl, sdirs, pdirs, W, pf, Ar, out);
}

// Round 6
// 99.118 us; speedup vs baseline: 3.3509x; 3.3509x over previous
//
#include <hip/hip_runtime.h>
#include <hip/hip_bf16.h>
#include <math.h>

#define Bn 512
#define Vn 6890
#define NBn 10
#define Pn 207
#define N3n 20670   // Vn*3
#define KP 224      // padded K for pose GEMM (7 steps of 32)
#define NP 20736    // padded N (108 * 192)
#define NTILES 1296 // NP/16
#define VPAD 6912   // padded vertex rows for W_bf (108*64)

typedef __attribute__((ext_vector_type(8))) short short8v;
typedef __attribute__((ext_vector_type(4))) float f32x4;

__constant__ int c_par[24] = {-1,0,0,0,1,2,3,4,5,6,7,8,9,9,9,12,13,14,16,17,18,19,20,21};

static __device__ __forceinline__ unsigned short f2bf(float f) {
  union { float f; unsigned u; } x; x.f = f;
  unsigned r = x.u + 0x7FFFu + ((x.u >> 16) & 1u);   // RNE, finite inputs
  return (unsigned short)(r >> 16);
}

// ---------------- Kernel 1a: partial JS/Jt sums over V chunks ----------------
__global__ __launch_bounds__(256) void k_jsjt_part(
    const float* __restrict__ Jreg, const float* __restrict__ vtpl,
    const float* __restrict__ sdirs, float* __restrict__ part)
{
  const int bid = blockIdx.x;           // 0..71 = j*3+c
  const int chunk = blockIdx.y;
  const int j = bid / 3, c = bid % 3;
  const int tid = threadIdx.x;
  const int vlo = chunk * 862;
  const int vhi = min(Vn, vlo + 862);
  float acc[11];
#pragma unroll
  for (int k = 0; k < 11; k++) acc[k] = 0.f;
  for (int v = vlo + tid; v < vhi; v += 256) {
    float w = Jreg[(size_t)j * Vn + v];
    int n = v * 3 + c;
#pragma unroll
    for (int l = 0; l < 10; l++) acc[l] += w * sdirs[(size_t)n * 10 + l];
    acc[10] += w * vtpl[n];
  }
  __shared__ float red[256];
  for (int k = 0; k < 11; k++) {
    red[tid] = acc[k];
    __syncthreads();
    for (int s = 128; s > 0; s >>= 1) {
      if (tid < s) red[tid] += red[tid + s];
      __syncthreads();
    }
    if (tid == 0) part[(size_t)chunk * 792 + bid * 11 + k] = red[0];
    __syncthreads();
  }
}

// ---------------- Kernel 1b: reduce partials -> JS, Jt ----------------
__global__ __launch_bounds__(1024) void k_jsjt_red(
    const float* __restrict__ part, float* __restrict__ JS, float* __restrict__ Jt)
{
  const int t = threadIdx.x;
  if (t >= 792) return;
  float s = 0.f;
#pragma unroll
  for (int y = 0; y < 8; y++) s += part[(size_t)y * 792 + t];
  int bid = t / 11, k = t % 11;
  if (k < 10) JS[bid * 10 + k] = s;
  else        Jt[bid] = s;
}

// ---------------- Kernel 2: per-batch pose pipeline (1 wave per batch) ----------------
__global__ __launch_bounds__(64) void k_pose(
    const float* __restrict__ betas, const float* __restrict__ body_pose,
    const float* __restrict__ gorient, const float* __restrict__ transl,
    const float* __restrict__ JS, const float* __restrict__ Jt,
    float* __restrict__ pf_ws, unsigned short* __restrict__ pf_bf,
    float* __restrict__ Ar_ws, float* __restrict__ out_joints)
{
  const int b = blockIdx.x;
  const int tid = threadIdx.x;
  __shared__ float Rs[24][9];
  __shared__ float jnt[24][3];
  __shared__ float rel[24][3];
  __shared__ float A_s[24][12];

  if (tid < 24) {
    float x, y, z;
    if (tid == 0) { x = gorient[b*3+0]; y = gorient[b*3+1]; z = gorient[b*3+2]; }
    else { int o = b*69 + (tid-1)*3; x = body_pose[o]; y = body_pose[o+1]; z = body_pose[o+2]; }
    float ang = sqrtf(x*x + y*y + z*z) + 1e-8f;
    float inv = 1.0f / ang;
    float ux = x*inv, uy = y*inv, uz = z*inv;
    float s = sinf(ang), cc = cosf(ang), omc = 1.0f - cc;
    float K[9] = {0.f, -uz, uy,  uz, 0.f, -ux,  -uy, ux, 0.f};
#pragma unroll
    for (int mm = 0; mm < 3; mm++)
#pragma unroll
      for (int nn = 0; nn < 3; nn++) {
        float kk = K[mm*3+0]*K[0+nn] + K[mm*3+1]*K[3+nn] + K[mm*3+2]*K[6+nn];
        float eye = (mm == nn) ? 1.0f : 0.0f;
        Rs[tid][mm*3+nn] = eye + s*K[mm*3+nn] + omc*kk;
      }
  }
  for (int idx = tid; idx < 72; idx += 64) {
    float a = Jt[idx];
#pragma unroll
    for (int l = 0; l < 10; l++) a += betas[b*10 + l] * JS[idx*10 + l];
    jnt[idx/3][idx%3] = a;
  }
  __syncthreads();
  for (int idx = tid; idx < Pn; idx += 64) {
    int j = 1 + idx / 9, e = idx % 9;
    float eye = (e == 0 || e == 4 || e == 8) ? 1.0f : 0.0f;
    pf_ws[(size_t)b * Pn + idx] = Rs[j][e] - eye;
  }
  if (pf_bf) {
    for (int idx = tid; idx < KP; idx += 64) {
      unsigned short u = 0;
      if (idx < Pn) {
        int j = 1 + idx / 9, e = idx % 9;
        float eye = (e == 0 || e == 4 || e == 8) ? 1.0f : 0.0f;
        u = f2bf(Rs[j][e] - eye);
      }
      pf_bf[(size_t)b * KP + idx] = u;
    }
  }
  for (int idx = tid; idx < 72; idx += 64) {
    int j = idx/3, cc = idx%3;
    float r = jnt[j][cc];
    if (j > 0) r -= jnt[c_par[j]][cc];
    rel[j][cc] = r;
  }
  __syncthreads();
  if (tid < 12) {
    int m = tid/4, nn = tid%4;
    A_s[0][tid] = (nn < 3) ? Rs[0][m*3+nn] : rel[0][m];
  }
  __syncthreads();
  for (int i = 1; i < 24; i++) {
    if (tid < 12) {
      int m = tid/4, nn = tid%4;
      int p = c_par[i];
      float v;
      if (nn < 3)
        v = A_s[p][m*4+0]*Rs[i][0+nn] + A_s[p][m*4+1]*Rs[i][3+nn] + A_s[p][m*4+2]*Rs[i][6+nn];
      else
        v = A_s[p][m*4+0]*rel[i][0] + A_s[p][m*4+1]*rel[i][1] + A_s[p][m*4+2]*rel[i][2] + A_s[p][m*4+3];
      A_s[i][tid] = v;
    }
    __syncthreads();
  }
  for (int idx = tid; idx < 72; idx += 64) {
    int j = idx/3, cc = idx%3;
    out_joints[(size_t)b * 72 + idx] = A_s[j][cc*4+3] + transl[b*3+cc];
  }
  for (int idx = tid; idx < 288; idx += 64) {
    int j = idx/12, r = idx%12, m = r/4, nn = r%4;
    float v;
    if (nn < 3) v = A_s[j][m*4+nn];
    else v = A_s[j][m*4+3] - (A_s[j][m*4+0]*jnt[j][0] + A_s[j][m*4+1]*jnt[j][1] + A_s[j][m*4+2]*jnt[j][2]);
    Ar_ws[(size_t)b * 288 + idx] = v;
  }
}

// ---------------- Kernel C1: pdirs fp32 -> bf16 fragment-linear B ----------------
// B_lin[((nt*7+s)*64 + l)*8 + j] = bf16(pdirs[k][n]), k = s*32+(l>>4)*8+j, n = nt*16+(l&15)
__global__ __launch_bounds__(256) void k_conv(
    const float* __restrict__ pdirs, unsigned short* __restrict__ B_lin)
{
  const int pair = blockIdx.x * 4 + (threadIdx.x >> 6);   // nt*7+s, 0..9071
  const int l = threadIdx.x & 63;
  const int nt = pair / 7, s = pair % 7;
  const int col = nt * 16 + (l & 15);
  const int kb = s * 32 + ((l >> 4) << 3);
  unsigned short vals[8];
#pragma unroll
  for (int j = 0; j < 8; j++) {
    int k = kb + j;
    float f = (k < Pn && col < N3n) ? pdirs[(size_t)k * N3n + col] : 0.f;
    vals[j] = f2bf(f);
  }
  uint4 o;
  o.x = (unsigned)vals[0] | ((unsigned)vals[1] << 16);
  o.y = (unsigned)vals[2] | ((unsigned)vals[3] << 16);
  o.z = (unsigned)vals[4] | ((unsigned)vals[5] << 16);
  o.w = (unsigned)vals[6] | ((unsigned)vals[7] << 16);
  *(uint4*)(B_lin + (size_t)pair * 512 + l * 8) = o;
}

// ---------------- Kernel C2: lbs_weights fp32 -> bf16 [VPAD][32] padded ----------------
__global__ __launch_bounds__(256) void k_wconv(
    const float* __restrict__ W, unsigned short* __restrict__ W_bf)
{
  int idx = blockIdx.x * 256 + threadIdx.x;
  if (idx >= VPAD * 32) return;
  int v = idx >> 5, k = idx & 31;
  float f = (v < Vn && k < 24) ? W[(size_t)v * 24 + k] : 0.f;
  W_bf[idx] = f2bf(f);
}

// ---------------- Kernel 3: MFMA pose-GEMM + MFMA T-blend + epilogue ----------------
// grid = (32 b-tiles, 108 v-tiles), 256 threads (4 waves). Tile: 16 batches x 64 vertices.
__global__ __launch_bounds__(256) void k_mm(
    const float* __restrict__ betas, const float* __restrict__ transl,
    const float* __restrict__ vtpl, const float* __restrict__ sdirs,
    const unsigned short* __restrict__ pf_bf, const unsigned short* __restrict__ B_lin,
    const unsigned short* __restrict__ W_bf, const float* __restrict__ Ar_ws,
    float* __restrict__ out)
{
  const int tid = threadIdx.x;
  const int l = tid & 63;
  const int wave = tid >> 6;
  const int b0 = blockIdx.x * 16;
  const int v0 = blockIdx.y * 64;

  __shared__ __align__(16) float vp[16][196];      // pose-GEMM result, padded cols
  __shared__ __align__(16) float T_s[8][64][14];   // fp32 T, padded row stride
  __shared__ float betas_s[16][NBn];
  __shared__ float transl_s[16][3];

  for (int idx = tid; idx < 16 * NBn; idx += 256)
    betas_s[idx / NBn][idx % NBn] = betas[(size_t)b0 * NBn + idx];
  if (tid < 48) transl_s[tid / 3][tid % 3] = transl[(size_t)b0 * 3 + tid];

  // ---- phase 1: C[b][n] = sum_p pf[b][p] * pdirs[p][n], 16x192 tile via MFMA
  const unsigned short* pfb = pf_bf + (size_t)(b0 + (l & 15)) * KP + ((l >> 4) << 3);
  const int ntb = blockIdx.y * 12 + wave * 3;
  f32x4 acc0 = {0.f,0.f,0.f,0.f}, acc1 = {0.f,0.f,0.f,0.f}, acc2 = {0.f,0.f,0.f,0.f};
#pragma unroll
  for (int s = 0; s < 7; s++) {
    short8v a   = *(const short8v*)(pfb + s * 32);
    short8v bv0 = *(const short8v*)(B_lin + ((size_t)(ntb + 0) * 7 + s) * 512 + l * 8);
    short8v bv1 = *(const short8v*)(B_lin + ((size_t)(ntb + 1) * 7 + s) * 512 + l * 8);
    short8v bv2 = *(const short8v*)(B_lin + ((size_t)(ntb + 2) * 7 + s) * 512 + l * 8);
    acc0 = __builtin_amdgcn_mfma_f32_16x16x32_bf16(a, bv0, acc0, 0, 0, 0);
    acc1 = __builtin_amdgcn_mfma_f32_16x16x32_bf16(a, bv1, acc1, 0, 0, 0);
    acc2 = __builtin_amdgcn_mfma_f32_16x16x32_bf16(a, bv2, acc2, 0, 0, 0);
  }
  {
    const int colb = wave * 48 + (l & 15);
    const int rowb = (l >> 4) * 4;
#pragma unroll
    for (int r = 0; r < 4; r++) vp[rowb + r][colb]      = acc0[r];
#pragma unroll
    for (int r = 0; r < 4; r++) vp[rowb + r][colb + 16] = acc1[r];
#pragma unroll
    for (int r = 0; r < 4; r++) vp[rowb + r][colb + 32] = acc2[r];
  }
  __syncthreads();

  // ---- per-thread epilogue invariants
  const int vl = tid & 63;
  const int wq = tid >> 6;
  const int v = v0 + vl;
  const bool vok = (v < Vn);
  float sd[30], vt3[3] = {0.f, 0.f, 0.f};
#pragma unroll
  for (int i = 0; i < 30; i++) sd[i] = 0.f;
  if (vok) {
    for (int i = 0; i < 30; i++) sd[i] = sdirs[(size_t)v * 30 + i];
    vt3[0] = vtpl[v*3]; vt3[1] = vtpl[v*3+1]; vt3[2] = vtpl[v*3+2];
  }

  for (int h = 0; h < 2; h++) {
    // ---- phase 2: T[v][e] = sum_j W[v][j] * Ar[b][j][e] via MFMA (8 batches)
#pragma unroll
    for (int g = 0; g < 2; g++) {
      const int bl8 = wave + g * 4;          // 0..7
      const int bl = h * 8 + bl8;
      const int kk = (l >> 4) << 3;
      const int e = l & 15;
      short8v bv;
#pragma unroll
      for (int j2 = 0; j2 < 8; j2++) {
        int k = kk + j2;
        unsigned short u = 0;
        if (k < 24 && e < 12) u = f2bf(Ar_ws[(size_t)(b0 + bl) * 288 + k * 12 + e]);
        bv[j2] = (short)u;
      }
#pragma unroll
      for (int mt = 0; mt < 4; mt++) {
        short8v av = *(const short8v*)(W_bf + (size_t)(v0 + mt * 16 + (l & 15)) * 32 + kk);
        f32x4 tacc = {0.f, 0.f, 0.f, 0.f};
        tacc = __builtin_amdgcn_mfma_f32_16x16x32_bf16(av, bv, tacc, 0, 0, 0);
        if (e < 12) {
#pragma unroll
          for (int r = 0; r < 4; r++)
            T_s[bl8][mt * 16 + (l >> 4) * 4 + r][e] = tacc[r];
        }
      }
    }
    __syncthreads();

    // ---- phase 3: epilogue for this half (each thread: 1 vertex x 2 batches)
#pragma unroll
    for (int q = 0; q < 2; q++) {
      const int bl8 = wq * 2 + q;            // 0..7
      const int bl = h * 8 + bl8;
      float bx = vt3[0], by = vt3[1], bz = vt3[2];
#pragma unroll
      for (int t = 0; t < 10; t++) {
        float bb = betas_s[bl][t];
        bx += bb * sd[t]; by += bb * sd[10 + t]; bz += bb * sd[20 + t];
      }
      float x = vp[bl][3 * vl + 0] + bx;
      float y = vp[bl][3 * vl + 1] + by;
      float z = vp[bl][3 * vl + 2] + bz;
      const float* tp = T_s[bl8][vl];
      float o0 = tp[0]*x + tp[1]*y + tp[2]*z  + tp[3]  + transl_s[bl][0];
      float o1 = tp[4]*x + tp[5]*y + tp[6]*z  + tp[7]  + transl_s[bl][1];
      float o2 = tp[8]*x + tp[9]*y + tp[10]*z + tp[11] + transl_s[bl][2];
      if (vok) {
        size_t o = ((size_t)(b0 + bl) * Vn + v) * 3;
        out[o] = o0; out[o + 1] = o1; out[o + 2] = o2;
      }
    }
    __syncthreads();   // protect T_s before next half overwrites
  }
}

// ---------------- Fallback (proven round-4 path) if ws too small ----------------
__global__ __launch_bounds__(192) void k_verts_fb(
    const float* __restrict__ betas, const float* __restrict__ transl,
    const float* __restrict__ vtpl, const float* __restrict__ sdirs,
    const float* __restrict__ pdirs, const float* __restrict__ W,
    const float* __restrict__ pf_ws, const float* __restrict__ Ar_ws,
    float* __restrict__ out)
{
  const int tid = threadIdx.x;
  const int b0 = blockIdx.x * 16;
  const int v0 = blockIdx.y * 128;
  const int n0 = v0 * 3;
  __shared__ __align__(16) float pf_s[Pn][16];
  __shared__ __align__(16) float Ar_s[16][288];
  __shared__ __align__(16) float vp_s[16][384];
  __shared__ float betas_s[16][NBn];
  __shared__ float transl_s[16][3];
  for (int idx = tid; idx < Pn * 16; idx += 192) {
    int p = idx >> 4, bi = idx & 15;
    pf_s[p][bi] = pf_ws[(size_t)(b0 + bi) * Pn + p];
  }
  for (int idx = tid; idx < 16 * 288; idx += 192)
    Ar_s[idx / 288][idx % 288] = Ar_ws[(size_t)b0 * 288 + idx];
  for (int idx = tid; idx < 16 * NBn; idx += 192)
    betas_s[idx / NBn][idx % NBn] = betas[(size_t)b0 * NBn + idx];
  for (int idx = tid; idx < 48; idx += 192)
    transl_s[idx / 3][idx % 3] = transl[(size_t)b0 * 3 + idx];
  __syncthreads();
  const int n = n0 + 2 * tid;
  const bool valid = (n < N3n);
  float acc0[16], acc1[16];
#pragma unroll
  for (int i = 0; i < 16; i++) { acc0[i] = 0.f; acc1[i] = 0.f; }
  for (int p = 0; p < Pn; p++) {
    float pd0 = 0.f, pd1 = 0.f;
    if (valid) { float2 t = *(const float2*)(pdirs + (size_t)p * N3n + n); pd0 = t.x; pd1 = t.y; }
    const float4* row = (const float4*)(pf_s[p]);
#pragma unroll
    for (int q = 0; q < 4; q++) {
      float4 f = row[q];
      acc0[4*q+0] += f.x * pd0;  acc1[4*q+0] += f.x * pd1;
      acc0[4*q+1] += f.y * pd0;  acc1[4*q+1] += f.y * pd1;
      acc0[4*q+2] += f.z * pd0;  acc1[4*q+2] += f.z * pd1;
      acc0[4*q+3] += f.w * pd0;  acc1[4*q+3] += f.w * pd1;
    }
  }
  float sd0[10], sd1[10], vt0 = 0.f, vt1 = 0.f;
#pragma unroll
  for (int l = 0; l < 10; l++) { sd0[l] = 0.f; sd1[l] = 0.f; }
  if (valid) {
    for (int l = 0; l < 10; l++) { sd0[l] = sdirs[(size_t)n*10 + l]; sd1[l] = sdirs[(size_t)n*10 + 10 + l]; }
    vt0 = vtpl[n]; vt1 = vtpl[n+1];
  }
#pragma unroll
  for (int bi = 0; bi < 16; bi++) {
    float s0 = vt0, s1 = vt1;
#pragma unroll
    for (int l = 0; l < 10; l++) { float bb = betas_s[bi][l]; s0 += bb*sd0[l]; s1 += bb*sd1[l]; }
    acc0[bi] += s0; acc1[bi] += s1;
  }
#pragma unroll
  for (int bi = 0; bi < 16; bi++) { vp_s[bi][2*tid] = acc0[bi]; vp_s[bi][2*tid+1] = acc1[bi]; }
  __syncthreads();
  const int m = tid / 64;
  const int vl = tid % 64;
  const int va = v0 + vl, vb = v0 + vl + 64;
  const bool va_ok = (va < Vn), vb_ok = (vb < Vn);
  float Wr0[24], Wr1[24];
#pragma unroll
  for (int j = 0; j < 24; j++) { Wr0[j] = 0.f; Wr1[j] = 0.f; }
  if (va_ok) { const float4* wp = (const float4*)(W + (size_t)va*24);
#pragma unroll
    for (int q = 0; q < 6; q++) { float4 f = wp[q]; Wr0[4*q]=f.x; Wr0[4*q+1]=f.y; Wr0[4*q+2]=f.z; Wr0[4*q+3]=f.w; } }
  if (vb_ok) { const float4* wp = (const float4*)(W + (size_t)vb*24);
#pragma unroll
    for (int q = 0; q < 6; q++) { float4 f = wp[q]; Wr1[4*q]=f.x; Wr1[4*q+1]=f.y; Wr1[4*q+2]=f.z; Wr1[4*q+3]=f.w; } }
  for (int bi = 0; bi < 16; bi++) {
    float Ta0=0.f,Ta1=0.f,Ta2=0.f,Ta3=0.f, Tb0=0.f,Tb1=0.f,Tb2=0.f,Tb3=0.f;
    const float4* arb = (const float4*)(Ar_s[bi]);
#pragma unroll
    for (int j = 0; j < 24; j++) {
      float4 a = arb[j*3 + m];
      float wa = Wr0[j], wb = Wr1[j];
      Ta0 += wa*a.x; Ta1 += wa*a.y; Ta2 += wa*a.z; Ta3 += wa*a.w;
      Tb0 += wb*a.x; Tb1 += wb*a.y; Tb2 += wb*a.z; Tb3 += wb*a.w;
    }
    float tr = transl_s[bi][m];
    if (va_ok) {
      float x = vp_s[bi][vl*3+0], y = vp_s[bi][vl*3+1], z = vp_s[bi][vl*3+2];
      out[((size_t)(b0+bi)*Vn + va)*3 + m] = Ta0*x + Ta1*y + Ta2*z + Ta3 + tr;
    }
    if (vb_ok) {
      float x = vp_s[bi][(vl+64)*3+0], y = vp_s[bi][(vl+64)*3+1], z = vp_s[bi][(vl+64)*3+2];
      out[((size_t)(b0+bi)*Vn + vb)*3 + m] = Tb0*x + Tb1*y + Tb2*z + Tb3 + tr;
    }
  }
}

extern "C" void kernel_launch(void* const* d_in, const int* in_sizes, int n_in,
                              void* d_out, int out_size, void* d_ws, size_t ws_size,
                              hipStream_t stream)
{
  const float *betas=nullptr, *bpose=nullptr, *gorient=nullptr, *transl=nullptr,
              *vtpl=nullptr, *sdirs=nullptr, *pdirs=nullptr, *Jreg=nullptr, *W=nullptr;
  int seen1536 = 0, seen165360 = 0;
  for (int i = 0; i < n_in; i++) {
    const float* p = (const float*)d_in[i];
    switch (in_sizes[i]) {
      case 5120:    betas = p; break;
      case 35328:   bpose = p; break;
      case 20670:   vtpl  = p; break;
      case 206700:  sdirs = p; break;
      case 4278690: pdirs = p; break;
      case 1536:    if (seen1536++ == 0) gorient = p; else transl = p; break;
      case 165360:  if (seen165360++ == 0) Jreg = p; else W = p; break;
      default: break;
    }
  }
  float* out = (float*)d_out;

  float* ws   = (float*)d_ws;
  float* part = ws;                                         // 6336 floats
  float* JS   = ws + 6336;                                  // 720
  float* Jt   = ws + 7056;                                  // 72
  float* pf   = ws + 7128;                                  // 105984
  float* Ar   = ws + 113112;                                // 147456
  unsigned short* pf_bf = (unsigned short*)(ws + 260568);   // 114688 ushort
  unsigned short* B_lin = (unsigned short*)(ws + 317912);   // 4644864 ushort
  unsigned short* W_bf  = (unsigned short*)(ws + 2640344);  // 221184 ushort
  const size_t WS_NEED = (size_t)(2640344 + 110592) * 4;    // 11,003,744 bytes
  const bool big = (ws_size >= WS_NEED);

  k_jsjt_part<<<dim3(72, 8), 256, 0, stream>>>(Jreg, vtpl, sdirs, part);
  k_jsjt_red<<<1, 1024, 0, stream>>>(part, JS, Jt);
  k_pose<<<Bn, 64, 0, stream>>>(betas, bpose, gorient, transl, JS, Jt,
                                pf, big ? pf_bf : (unsigned short*)nullptr, Ar,
                                out + (size_t)Bn * Vn * 3);
  if (big) {
    k_conv<<<2268, 256, 0, stream>>>(pdirs, B_lin);
    k_wconv<<<(VPAD * 32) / 256, 256, 0, stream>>>(W, W_bf);
    k_mm<<<dim3(32, 108), 256, 0, stream>>>(betas, transl, vtpl, sdirs,
                                            pf_bf, B_lin, W_bf, Ar, out);
  } else {
    k_verts_fb<<<dim3(32, 54), 192, 0, stream>>>(betas, transl, vtpl, sdirs,
                                                 pdirs, W, pf, Ar, out);
  }
}

// Round 7
// 84.222 us; speedup vs baseline: 3.9435x; 1.1769x over previous
//
#include <hip/hip_runtime.h>
#include <hip/hip_bf16.h>
#include <math.h>

#define Bn 512
#define Vn 6890
#define NBn 10
#define Pn 207
#define N3n 20670   // Vn*3
#define KP 224      // padded K for pose GEMM (7 steps of 32); rows: 0-206 pf, 207-216 betas*sdirs, 217 vtpl_hi, 218 vtpl_lo
#define VPAD 6912   // padded vertex rows for W (108*64)

typedef __attribute__((ext_vector_type(8))) short short8v;
typedef __attribute__((ext_vector_type(4))) float f32x4;

__constant__ int c_par[24] = {-1,0,0,0,1,2,3,4,5,6,7,8,9,9,9,12,13,14,16,17,18,19,20,21};

static __device__ __forceinline__ unsigned short f2bf(float f) {
  union { float f; unsigned u; } x; x.f = f;
  unsigned r = x.u + 0x7FFFu + ((x.u >> 16) & 1u);   // RNE, finite inputs
  return (unsigned short)(r >> 16);
}
static __device__ __forceinline__ float bf2f(unsigned short h) {
  union { unsigned u; float f; } x; x.u = ((unsigned)h) << 16; return x.f;
}

// ---------------- Kernel 1a: partial JS/Jt sums over V chunks ----------------
__global__ __launch_bounds__(256) void k_jsjt_part(
    const float* __restrict__ Jreg, const float* __restrict__ vtpl,
    const float* __restrict__ sdirs, float* __restrict__ part)
{
  const int bid = blockIdx.x;           // 0..71 = j*3+c
  const int chunk = blockIdx.y;
  const int j = bid / 3, c = bid % 3;
  const int tid = threadIdx.x;
  const int vlo = chunk * 862;
  const int vhi = min(Vn, vlo + 862);
  float acc[11];
#pragma unroll
  for (int k = 0; k < 11; k++) acc[k] = 0.f;
  for (int v = vlo + tid; v < vhi; v += 256) {
    float w = Jreg[(size_t)j * Vn + v];
    int n = v * 3 + c;
#pragma unroll
    for (int l = 0; l < 10; l++) acc[l] += w * sdirs[(size_t)n * 10 + l];
    acc[10] += w * vtpl[n];
  }
  __shared__ float red[256];
  for (int k = 0; k < 11; k++) {
    red[tid] = acc[k];
    __syncthreads();
    for (int s = 128; s > 0; s >>= 1) {
      if (tid < s) red[tid] += red[tid + s];
      __syncthreads();
    }
    if (tid == 0) part[(size_t)chunk * 792 + bid * 11 + k] = red[0];
    __syncthreads();
  }
}

// ---------------- Kernel 1b: reduce partials -> JS, Jt ----------------
__global__ __launch_bounds__(1024) void k_jsjt_red(
    const float* __restrict__ part, float* __restrict__ JS, float* __restrict__ Jt)
{
  const int t = threadIdx.x;
  if (t >= 792) return;
  float s = 0.f;
#pragma unroll
  for (int y = 0; y < 8; y++) s += part[(size_t)y * 792 + t];
  int bid = t / 11, k = t % 11;
  if (k < 10) JS[bid * 10 + k] = s;
  else        Jt[bid] = s;
}

// ---------------- Kernel 2: per-batch pose pipeline (1 wave per batch) ----------------
__global__ __launch_bounds__(64) void k_pose(
    const float* __restrict__ betas, const float* __restrict__ body_pose,
    const float* __restrict__ gorient, const float* __restrict__ transl,
    const float* __restrict__ JS, const float* __restrict__ Jt,
    float* __restrict__ pf_ws, unsigned short* __restrict__ pf_bf,
    float* __restrict__ Ar_ws,
    unsigned short* __restrict__ Ar_hi, unsigned short* __restrict__ Ar_lo,
    float* __restrict__ out_joints)
{
  const int b = blockIdx.x;
  const int tid = threadIdx.x;
  __shared__ float Rs[24][9];
  __shared__ float jnt[24][3];
  __shared__ float rel[24][3];
  __shared__ float A_s[24][12];

  if (tid < 24) {
    float x, y, z;
    if (tid == 0) { x = gorient[b*3+0]; y = gorient[b*3+1]; z = gorient[b*3+2]; }
    else { int o = b*69 + (tid-1)*3; x = body_pose[o]; y = body_pose[o+1]; z = body_pose[o+2]; }
    float ang = sqrtf(x*x + y*y + z*z) + 1e-8f;
    float inv = 1.0f / ang;
    float ux = x*inv, uy = y*inv, uz = z*inv;
    float s = sinf(ang), cc = cosf(ang), omc = 1.0f - cc;
    float K[9] = {0.f, -uz, uy,  uz, 0.f, -ux,  -uy, ux, 0.f};
#pragma unroll
    for (int mm = 0; mm < 3; mm++)
#pragma unroll
      for (int nn = 0; nn < 3; nn++) {
        float kk = K[mm*3+0]*K[0+nn] + K[mm*3+1]*K[3+nn] + K[mm*3+2]*K[6+nn];
        float eye = (mm == nn) ? 1.0f : 0.0f;
        Rs[tid][mm*3+nn] = eye + s*K[mm*3+nn] + omc*kk;
      }
  }
  for (int idx = tid; idx < 72; idx += 64) {
    float a = Jt[idx];
#pragma unroll
    for (int l = 0; l < 10; l++) a += betas[b*10 + l] * JS[idx*10 + l];
    jnt[idx/3][idx%3] = a;
  }
  __syncthreads();
  for (int idx = tid; idx < Pn; idx += 64) {
    int j = 1 + idx / 9, e = idx % 9;
    float eye = (e == 0 || e == 4 || e == 8) ? 1.0f : 0.0f;
    pf_ws[(size_t)b * Pn + idx] = Rs[j][e] - eye;
  }
  if (pf_bf) {
    for (int idx = tid; idx < KP; idx += 64) {
      unsigned short u = 0;
      if (idx < Pn) {
        int j = 1 + idx / 9, e = idx % 9;
        float eye = (e == 0 || e == 4 || e == 8) ? 1.0f : 0.0f;
        u = f2bf(Rs[j][e] - eye);
      } else if (idx < 217) {
        u = f2bf(betas[b*10 + (idx - 207)]);
      } else if (idx < 219) {
        u = 0x3F80;   // 1.0f in bf16
      }
      pf_bf[(size_t)b * KP + idx] = u;
    }
  }
  for (int idx = tid; idx < 72; idx += 64) {
    int j = idx/3, cc = idx%3;
    float r = jnt[j][cc];
    if (j > 0) r -= jnt[c_par[j]][cc];
    rel[j][cc] = r;
  }
  __syncthreads();
  if (tid < 12) {
    int m = tid/4, nn = tid%4;
    A_s[0][tid] = (nn < 3) ? Rs[0][m*3+nn] : rel[0][m];
  }
  __syncthreads();
  for (int i = 1; i < 24; i++) {
    if (tid < 12) {
      int m = tid/4, nn = tid%4;
      int p = c_par[i];
      float v;
      if (nn < 3)
        v = A_s[p][m*4+0]*Rs[i][0+nn] + A_s[p][m*4+1]*Rs[i][3+nn] + A_s[p][m*4+2]*Rs[i][6+nn];
      else
        v = A_s[p][m*4+0]*rel[i][0] + A_s[p][m*4+1]*rel[i][1] + A_s[p][m*4+2]*rel[i][2] + A_s[p][m*4+3];
      A_s[i][tid] = v;
    }
    __syncthreads();
  }
  for (int idx = tid; idx < 72; idx += 64) {
    int j = idx/3, cc = idx%3;
    out_joints[(size_t)b * 72 + idx] = A_s[j][cc*4+3] + transl[b*3+cc];
  }
  // A_rel fp32 (fallback path)
  for (int idx = tid; idx < 288; idx += 64) {
    int j = idx/12, r = idx%12, m = r/4, nn = r%4;
    float v;
    if (nn < 3) v = A_s[j][m*4+nn];
    else v = A_s[j][m*4+3] - (A_s[j][m*4+0]*jnt[j][0] + A_s[j][m*4+1]*jnt[j][1] + A_s[j][m*4+2]*jnt[j][2]);
    Ar_ws[(size_t)b * 288 + idx] = v;
  }
  // A_rel MFMA fragments [e=16][k=32], split hi/lo bf16
  if (Ar_hi) {
    for (int idx = tid; idx < 512; idx += 64) {
      int e = idx >> 5, k = idx & 31;
      float a = 0.f;
      if (e < 12 && k < 24) {
        int m = e >> 2, nn = e & 3;
        if (nn < 3) a = A_s[k][m*4+nn];
        else a = A_s[k][m*4+3] - (A_s[k][m*4+0]*jnt[k][0] + A_s[k][m*4+1]*jnt[k][1] + A_s[k][m*4+2]*jnt[k][2]);
      }
      unsigned short hi = f2bf(a);
      Ar_hi[(size_t)b * 512 + idx] = hi;
      Ar_lo[(size_t)b * 512 + idx] = f2bf(a - bf2f(hi));
    }
  }
}

// ---------------- Kernel C: build bf16 B matrix (pdirs+sdirs+vtpl) and W hi/lo ----------------
// blocks 0..2267: B_lin. blocks 2268..3131: W conversion.
// B_lin[((nt*7+s)*64 + l)*8 + j] = bf16(B[k][n]), k = s*32+(l>>4)*8+j, n = nt*16+(l&15)
__global__ __launch_bounds__(256) void k_conv(
    const float* __restrict__ pdirs, const float* __restrict__ sdirs,
    const float* __restrict__ vtpl, const float* __restrict__ W,
    unsigned short* __restrict__ B_lin,
    unsigned short* __restrict__ W_hi, unsigned short* __restrict__ W_lo)
{
  if (blockIdx.x < 2268) {
    const int pair = blockIdx.x * 4 + (threadIdx.x >> 6);   // nt*7+s, 0..9071
    const int l = threadIdx.x & 63;
    const int nt = pair / 7, s = pair % 7;
    const int col = nt * 16 + (l & 15);
    const int kb = s * 32 + ((l >> 4) << 3);
    unsigned short vals[8];
#pragma unroll
    for (int j = 0; j < 8; j++) {
      int k = kb + j;
      unsigned short u = 0;
      if (col < N3n) {
        if (k < Pn) u = f2bf(pdirs[(size_t)k * N3n + col]);
        else if (k < 217) u = f2bf(sdirs[(size_t)col * 10 + (k - 207)]);
        else if (k == 217) u = f2bf(vtpl[col]);
        else if (k == 218) {
          float t = vtpl[col];
          u = f2bf(t - bf2f(f2bf(t)));
        }
      }
      vals[j] = u;
    }
    uint4 o;
    o.x = (unsigned)vals[0] | ((unsigned)vals[1] << 16);
    o.y = (unsigned)vals[2] | ((unsigned)vals[3] << 16);
    o.z = (unsigned)vals[4] | ((unsigned)vals[5] << 16);
    o.w = (unsigned)vals[6] | ((unsigned)vals[7] << 16);
    *(uint4*)(B_lin + (size_t)pair * 512 + l * 8) = o;
  } else {
    int idx = (blockIdx.x - 2268) * 256 + threadIdx.x;
    if (idx < VPAD * 32) {
      int v = idx >> 5, k = idx & 31;
      float f = (v < Vn && k < 24) ? W[(size_t)v * 24 + k] : 0.f;
      unsigned short hi = f2bf(f);
      W_hi[idx] = hi;
      W_lo[idx] = f2bf(f - bf2f(hi));
    }
  }
}

// ---------------- Kernel 3: MFMA v_posed GEMM + split-MFMA T-blend + epilogue ----------------
// grid = (32 b-tiles, 108 v-tiles), 256 threads (4 waves). Tile: 16 batches x 64 vertices.
__global__ __launch_bounds__(256) void k_mm(
    const float* __restrict__ transl,
    const unsigned short* __restrict__ pf_bf, const unsigned short* __restrict__ B_lin,
    const unsigned short* __restrict__ W_hi, const unsigned short* __restrict__ W_lo,
    const unsigned short* __restrict__ Ar_hi, const unsigned short* __restrict__ Ar_lo,
    float* __restrict__ out)
{
  const int tid = threadIdx.x;
  const int l = tid & 63;
  const int wave = tid >> 6;
  const int b0 = blockIdx.x * 16;
  const int v0 = blockIdx.y * 64;

  __shared__ __align__(16) float vp[16][196];      // v_posed tile (192 cols + pad)
  __shared__ __align__(16) float T_s[8][64][13];   // fp32 T, stride 13 (gcd(13,32)=1)
  __shared__ float transl_s[16][3];

  if (tid < 48) transl_s[tid / 3][tid % 3] = transl[(size_t)b0 * 3 + tid];

  // ---- phase 1: vp[b][n] = sum_k pf_ext[b][k] * B[k][n] (v_posed incl. shape + template)
  const unsigned short* pfb = pf_bf + (size_t)(b0 + (l & 15)) * KP + ((l >> 4) << 3);
  const int ntb = blockIdx.y * 12 + wave * 3;
  f32x4 acc0 = {0.f,0.f,0.f,0.f}, acc1 = {0.f,0.f,0.f,0.f}, acc2 = {0.f,0.f,0.f,0.f};
#pragma unroll
  for (int s = 0; s < 7; s++) {
    short8v a   = *(const short8v*)(pfb + s * 32);
    short8v bv0 = *(const short8v*)(B_lin + ((size_t)(ntb + 0) * 7 + s) * 512 + l * 8);
    short8v bv1 = *(const short8v*)(B_lin + ((size_t)(ntb + 1) * 7 + s) * 512 + l * 8);
    short8v bv2 = *(const short8v*)(B_lin + ((size_t)(ntb + 2) * 7 + s) * 512 + l * 8);
    acc0 = __builtin_amdgcn_mfma_f32_16x16x32_bf16(a, bv0, acc0, 0, 0, 0);
    acc1 = __builtin_amdgcn_mfma_f32_16x16x32_bf16(a, bv1, acc1, 0, 0, 0);
    acc2 = __builtin_amdgcn_mfma_f32_16x16x32_bf16(a, bv2, acc2, 0, 0, 0);
  }
  {
    const int colb = wave * 48 + (l & 15);
    const int rowb = (l >> 4) * 4;
#pragma unroll
    for (int r = 0; r < 4; r++) vp[rowb + r][colb]      = acc0[r];
#pragma unroll
    for (int r = 0; r < 4; r++) vp[rowb + r][colb + 16] = acc1[r];
#pragma unroll
    for (int r = 0; r < 4; r++) vp[rowb + r][colb + 32] = acc2[r];
  }
  __syncthreads();

  const int vl = tid & 63;
  const int v = v0 + vl;
  const bool vok = (v < Vn);

  for (int h = 0; h < 2; h++) {
    // ---- phase 2: T[v][e] = sum_j W[v][j]*Ar[b][j][e], split bf16 (3 MFMAs)
#pragma unroll
    for (int g = 0; g < 2; g++) {
      const int bl8 = wave + g * 4;          // 0..7
      const int bl = h * 8 + bl8;
      const int kk = (l >> 4) << 3;
      const int e = l & 15;
      const size_t abase = (size_t)(b0 + bl) * 512 + e * 32 + kk;
      short8v bhi = *(const short8v*)(Ar_hi + abase);
      short8v blo = *(const short8v*)(Ar_lo + abase);
#pragma unroll
      for (int mt = 0; mt < 4; mt++) {
        const size_t wbase = (size_t)(v0 + mt * 16 + e) * 32 + kk;
        short8v whi = *(const short8v*)(W_hi + wbase);
        short8v wlo = *(const short8v*)(W_lo + wbase);
        f32x4 tacc = {0.f, 0.f, 0.f, 0.f};
        tacc = __builtin_amdgcn_mfma_f32_16x16x32_bf16(wlo, bhi, tacc, 0, 0, 0);
        tacc = __builtin_amdgcn_mfma_f32_16x16x32_bf16(whi, blo, tacc, 0, 0, 0);
        tacc = __builtin_amdgcn_mfma_f32_16x16x32_bf16(whi, bhi, tacc, 0, 0, 0);
        if (e < 12) {
#pragma unroll
          for (int r = 0; r < 4; r++)
            T_s[bl8][mt * 16 + (l >> 4) * 4 + r][e] = tacc[r];
        }
      }
    }
    __syncthreads();

    // ---- phase 3: epilogue (each thread: 1 vertex x 2 batches)
#pragma unroll
    for (int q = 0; q < 2; q++) {
      const int bl8 = wave * 2 + q;          // 0..7
      const int bl = h * 8 + bl8;
      float x = vp[bl][3 * vl + 0];
      float y = vp[bl][3 * vl + 1];
      float z = vp[bl][3 * vl + 2];
      const float* tp = T_s[bl8][vl];
      float o0 = tp[0]*x + tp[1]*y + tp[2]*z  + tp[3]  + transl_s[bl][0];
      float o1 = tp[4]*x + tp[5]*y + tp[6]*z  + tp[7]  + transl_s[bl][1];
      float o2 = tp[8]*x + tp[9]*y + tp[10]*z + tp[11] + transl_s[bl][2];
      if (vok) {
        size_t o = ((size_t)(b0 + bl) * Vn + v) * 3;
        out[o] = o0; out[o + 1] = o1; out[o + 2] = o2;
      }
    }
    __syncthreads();   // protect T_s before next half overwrites
  }
}

// ---------------- Fallback (proven round-4 path) if ws too small ----------------
__global__ __launch_bounds__(192) void k_verts_fb(
    const float* __restrict__ betas, const float* __restrict__ transl,
    const float* __restrict__ vtpl, const float* __restrict__ sdirs,
    const float* __restrict__ pdirs, const float* __restrict__ W,
    const float* __restrict__ pf_ws, const float* __restrict__ Ar_ws,
    float* __restrict__ out)
{
  const int tid = threadIdx.x;
  const int b0 = blockIdx.x * 16;
  const int v0 = blockIdx.y * 128;
  const int n0 = v0 * 3;
  __shared__ __align__(16) float pf_s[Pn][16];
  __shared__ __align__(16) float Ar_s[16][288];
  __shared__ __align__(16) float vp_s[16][384];
  __shared__ float betas_s[16][NBn];
  __shared__ float transl_s[16][3];
  for (int idx = tid; idx < Pn * 16; idx += 192) {
    int p = idx >> 4, bi = idx & 15;
    pf_s[p][bi] = pf_ws[(size_t)(b0 + bi) * Pn + p];
  }
  for (int idx = tid; idx < 16 * 288; idx += 192)
    Ar_s[idx / 288][idx % 288] = Ar_ws[(size_t)b0 * 288 + idx];
  for (int idx = tid; idx < 16 * NBn; idx += 192)
    betas_s[idx / NBn][idx % NBn] = betas[(size_t)b0 * NBn + idx];
  for (int idx = tid; idx < 48; idx += 192)
    transl_s[idx / 3][idx % 3] = transl[(size_t)b0 * 3 + idx];
  __syncthreads();
  const int n = n0 + 2 * tid;
  const bool valid = (n < N3n);
  float acc0[16], acc1[16];
#pragma unroll
  for (int i = 0; i < 16; i++) { acc0[i] = 0.f; acc1[i] = 0.f; }
  for (int p = 0; p < Pn; p++) {
    float pd0 = 0.f, pd1 = 0.f;
    if (valid) { float2 t = *(const float2*)(pdirs + (size_t)p * N3n + n); pd0 = t.x; pd1 = t.y; }
    const float4* row = (const float4*)(pf_s[p]);
#pragma unroll
    for (int q = 0; q < 4; q++) {
      float4 f = row[q];
      acc0[4*q+0] += f.x * pd0;  acc1[4*q+0] += f.x * pd1;
      acc0[4*q+1] += f.y * pd0;  acc1[4*q+1] += f.y * pd1;
      acc0[4*q+2] += f.z * pd0;  acc1[4*q+2] += f.z * pd1;
      acc0[4*q+3] += f.w * pd0;  acc1[4*q+3] += f.w * pd1;
    }
  }
  float sd0[10], sd1[10], vt0 = 0.f, vt1 = 0.f;
#pragma unroll
  for (int l = 0; l < 10; l++) { sd0[l] = 0.f; sd1[l] = 0.f; }
  if (valid) {
    for (int l = 0; l < 10; l++) { sd0[l] = sdirs[(size_t)n*10 + l]; sd1[l] = sdirs[(size_t)n*10 + 10 + l]; }
    vt0 = vtpl[n]; vt1 = vtpl[n+1];
  }
#pragma unroll
  for (int bi = 0; bi < 16; bi++) {
    float s0 = vt0, s1 = vt1;
#pragma unroll
    for (int l = 0; l < 10; l++) { float bb = betas_s[bi][l]; s0 += bb*sd0[l]; s1 += bb*sd1[l]; }
    acc0[bi] += s0; acc1[bi] += s1;
  }
#pragma unroll
  for (int bi = 0; bi < 16; bi++) { vp_s[bi][2*tid] = acc0[bi]; vp_s[bi][2*tid+1] = acc1[bi]; }
  __syncthreads();
  const int m = tid / 64;
  const int vl = tid % 64;
  const int va = v0 + vl, vb = v0 + vl + 64;
  const bool va_ok = (va < Vn), vb_ok = (vb < Vn);
  float Wr0[24], Wr1[24];
#pragma unroll
  for (int j = 0; j < 24; j++) { Wr0[j] = 0.f; Wr1[j] = 0.f; }
  if (va_ok) { const float4* wp = (const float4*)(W + (size_t)va*24);
#pragma unroll
    for (int q = 0; q < 6; q++) { float4 f = wp[q]; Wr0[4*q]=f.x; Wr0[4*q+1]=f.y; Wr0[4*q+2]=f.z; Wr0[4*q+3]=f.w; } }
  if (vb_ok) { const float4* wp = (const float4*)(W + (size_t)vb*24);
#pragma unroll
    for (int q = 0; q < 6; q++) { float4 f = wp[q]; Wr1[4*q]=f.x; Wr1[4*q+1]=f.y; Wr1[4*q+2]=f.z; Wr1[4*q+3]=f.w; } }
  for (int bi = 0; bi < 16; bi++) {
    float Ta0=0.f,Ta1=0.f,Ta2=0.f,Ta3=0.f, Tb0=0.f,Tb1=0.f,Tb2=0.f,Tb3=0.f;
    const float4* arb = (const float4*)(Ar_s[bi]);
#pragma unroll
    for (int j = 0; j < 24; j++) {
      float4 a = arb[j*3 + m];
      float wa = Wr0[j], wb = Wr1[j];
      Ta0 += wa*a.x; Ta1 += wa*a.y; Ta2 += wa*a.z; Ta3 += wa*a.w;
      Tb0 += wb*a.x; Tb1 += wb*a.y; Tb2 += wb*a.z; Tb3 += wb*a.w;
    }
    float tr = transl_s[bi][m];
    if (va_ok) {
      float x = vp_s[bi][vl*3+0], y = vp_s[bi][vl*3+1], z = vp_s[bi][vl*3+2];
      out[((size_t)(b0+bi)*Vn + va)*3 + m] = Ta0*x + Ta1*y + Ta2*z + Ta3 + tr;
    }
    if (vb_ok) {
      float x = vp_s[bi][(vl+64)*3+0], y = vp_s[bi][(vl+64)*3+1], z = vp_s[bi][(vl+64)*3+2];
      out[((size_t)(b0+bi)*Vn + vb)*3 + m] = Tb0*x + Tb1*y + Tb2*z + Tb3 + tr;
    }
  }
}

extern "C" void kernel_launch(void* const* d_in, const int* in_sizes, int n_in,
                              void* d_out, int out_size, void* d_ws, size_t ws_size,
                              hipStream_t stream)
{
  const float *betas=nullptr, *bpose=nullptr, *gorient=nullptr, *transl=nullptr,
              *vtpl=nullptr, *sdirs=nullptr, *pdirs=nullptr, *Jreg=nullptr, *W=nullptr;
  int seen1536 = 0, seen165360 = 0;
  for (int i = 0; i < n_in; i++) {
    const float* p = (const float*)d_in[i];
    switch (in_sizes[i]) {
      case 5120:    betas = p; break;
      case 35328:   bpose = p; break;
      case 20670:   vtpl  = p; break;
      case 206700:  sdirs = p; break;
      case 4278690: pdirs = p; break;
      case 1536:    if (seen1536++ == 0) gorient = p; else transl = p; break;
      case 165360:  if (seen165360++ == 0) Jreg = p; else W = p; break;
      default: break;
    }
  }
  float* out = (float*)d_out;

  float* ws   = (float*)d_ws;
  float* part = ws;                                         // 6336 f
  float* JS   = ws + 6336;                                  // 720 f
  float* Jt   = ws + 7056;                                  // 72 f
  float* pf   = ws + 7128;                                  // 105984 f
  float* Ar   = ws + 113112;                                // 147456 f
  unsigned short* pf_bf = (unsigned short*)(ws + 260568);   // 114688 us (57344 f)
  unsigned short* B_lin = (unsigned short*)(ws + 317912);   // 4644864 us (2322432 f)
  unsigned short* W_hi  = (unsigned short*)(ws + 2640344);  // 221184 us (110592 f)
  unsigned short* W_lo  = (unsigned short*)(ws + 2750936);  // 221184 us (110592 f)
  unsigned short* Ar_hi = (unsigned short*)(ws + 2861528);  // 262144 us (131072 f)
  unsigned short* Ar_lo = (unsigned short*)(ws + 2992600);  // 262144 us (131072 f)
  const size_t WS_NEED = (size_t)3123672 * 4;               // 12,494,688 bytes
  const bool big = (ws_size >= WS_NEED);

  k_jsjt_part<<<dim3(72, 8), 256, 0, stream>>>(Jreg, vtpl, sdirs, part);
  k_jsjt_red<<<1, 1024, 0, stream>>>(part, JS, Jt);
  k_pose<<<Bn, 64, 0, stream>>>(betas, bpose, gorient, transl, JS, Jt,
                                pf, big ? pf_bf : (unsigned short*)nullptr, Ar,
                                big ? Ar_hi : (unsigned short*)nullptr,
                                big ? Ar_lo : (unsigned short*)nullptr,
                                out + (size_t)Bn * Vn * 3);
  if (big) {
    k_conv<<<3132, 256, 0, stream>>>(pdirs, sdirs, vtpl, W, B_lin, W_hi, W_lo);
    k_mm<<<dim3(32, 108), 256, 0, stream>>>(transl, pf_bf, B_lin,
                                            W_hi, W_lo, Ar_hi, Ar_lo, out);
  } else {
    k_verts_fb<<<dim3(32, 54), 192, 0, stream>>>(betas, transl, vtpl, sdirs,
                                                 pdirs, W, pf, Ar, out);
  }
}

// Round 8
// 79.736 us; speedup vs baseline: 4.1654x; 1.0563x over previous
//
#include <hip/hip_runtime.h>
#include <hip/hip_bf16.h>
#include <math.h>

#define Bn 512
#define Vn 6890
#define NBn 10
#define Pn 207
#define N3n 20670   // Vn*3
#define KP 224      // padded K for pose GEMM; rows: 0-206 pf, 207-216 betas, 217 vtpl_hi, 218 vtpl_lo
#define VPAD 6912   // padded vertex rows for W (108*64)

typedef __attribute__((ext_vector_type(8))) short short8v;
typedef __attribute__((ext_vector_type(4))) float f32x4;

__constant__ int c_par[24] = {-1,0,0,0,1,2,3,4,5,6,7,8,9,9,9,12,13,14,16,17,18,19,20,21};

static __device__ __forceinline__ unsigned short f2bf(float f) {
  union { float f; unsigned u; } x; x.f = f;
  unsigned r = x.u + 0x7FFFu + ((x.u >> 16) & 1u);   // RNE, finite inputs
  return (unsigned short)(r >> 16);
}
static __device__ __forceinline__ float bf2f(unsigned short h) {
  union { unsigned u; float f; } x; x.u = ((unsigned)h) << 16; return x.f;
}

// ---------------- Kernel 1a: partial JS/Jt sums over V chunks ----------------
__global__ __launch_bounds__(256) void k_jsjt_part(
    const float* __restrict__ Jreg, const float* __restrict__ vtpl,
    const float* __restrict__ sdirs, float* __restrict__ part)
{
  const int bid = blockIdx.x;           // 0..71 = j*3+c
  const int chunk = blockIdx.y;
  const int j = bid / 3, c = bid % 3;
  const int tid = threadIdx.x;
  const int vlo = chunk * 862;
  const int vhi = min(Vn, vlo + 862);
  float acc[11];
#pragma unroll
  for (int k = 0; k < 11; k++) acc[k] = 0.f;
  for (int v = vlo + tid; v < vhi; v += 256) {
    float w = Jreg[(size_t)j * Vn + v];
    int n = v * 3 + c;
#pragma unroll
    for (int l = 0; l < 10; l++) acc[l] += w * sdirs[(size_t)n * 10 + l];
    acc[10] += w * vtpl[n];
  }
  __shared__ float red[256];
  for (int k = 0; k < 11; k++) {
    red[tid] = acc[k];
    __syncthreads();
    for (int s = 128; s > 0; s >>= 1) {
      if (tid < s) red[tid] += red[tid + s];
      __syncthreads();
    }
    if (tid == 0) part[(size_t)chunk * 792 + bid * 11 + k] = red[0];
    __syncthreads();
  }
}

// ---------------- Kernel 1b: reduce partials -> JS, Jt ----------------
__global__ __launch_bounds__(1024) void k_jsjt_red(
    const float* __restrict__ part, float* __restrict__ JS, float* __restrict__ Jt)
{
  const int t = threadIdx.x;
  if (t >= 792) return;
  float s = 0.f;
#pragma unroll
  for (int y = 0; y < 8; y++) s += part[(size_t)y * 792 + t];
  int bid = t / 11, k = t % 11;
  if (k < 10) JS[bid * 10 + k] = s;
  else        Jt[bid] = s;
}

// ---------------- Kernel 2: per-batch pose pipeline (1 wave per batch) ----------------
__global__ __launch_bounds__(64) void k_pose(
    const float* __restrict__ betas, const float* __restrict__ body_pose,
    const float* __restrict__ gorient, const float* __restrict__ transl,
    const float* __restrict__ JS, const float* __restrict__ Jt,
    float* __restrict__ pf_ws, unsigned short* __restrict__ pf_bf,
    float* __restrict__ Ar_ws,
    unsigned short* __restrict__ Ar_hi, unsigned short* __restrict__ Ar_lo,
    float* __restrict__ out_joints)
{
  const int b = blockIdx.x;
  const int tid = threadIdx.x;
  __shared__ float Rs[24][9];
  __shared__ float jnt[24][3];
  __shared__ float rel[24][3];
  __shared__ float A_s[24][12];

  if (tid < 24) {
    float x, y, z;
    if (tid == 0) { x = gorient[b*3+0]; y = gorient[b*3+1]; z = gorient[b*3+2]; }
    else { int o = b*69 + (tid-1)*3; x = body_pose[o]; y = body_pose[o+1]; z = body_pose[o+2]; }
    float ang = sqrtf(x*x + y*y + z*z) + 1e-8f;
    float inv = 1.0f / ang;
    float ux = x*inv, uy = y*inv, uz = z*inv;
    float s = sinf(ang), cc = cosf(ang), omc = 1.0f - cc;
    float K[9] = {0.f, -uz, uy,  uz, 0.f, -ux,  -uy, ux, 0.f};
#pragma unroll
    for (int mm = 0; mm < 3; mm++)
#pragma unroll
      for (int nn = 0; nn < 3; nn++) {
        float kk = K[mm*3+0]*K[0+nn] + K[mm*3+1]*K[3+nn] + K[mm*3+2]*K[6+nn];
        float eye = (mm == nn) ? 1.0f : 0.0f;
        Rs[tid][mm*3+nn] = eye + s*K[mm*3+nn] + omc*kk;
      }
  }
  for (int idx = tid; idx < 72; idx += 64) {
    float a = Jt[idx];
#pragma unroll
    for (int l = 0; l < 10; l++) a += betas[b*10 + l] * JS[idx*10 + l];
    jnt[idx/3][idx%3] = a;
  }
  __syncthreads();
  for (int idx = tid; idx < Pn; idx += 64) {
    int j = 1 + idx / 9, e = idx % 9;
    float eye = (e == 0 || e == 4 || e == 8) ? 1.0f : 0.0f;
    pf_ws[(size_t)b * Pn + idx] = Rs[j][e] - eye;
  }
  if (pf_bf) {
    for (int idx = tid; idx < KP; idx += 64) {
      unsigned short u = 0;
      if (idx < Pn) {
        int j = 1 + idx / 9, e = idx % 9;
        float eye = (e == 0 || e == 4 || e == 8) ? 1.0f : 0.0f;
        u = f2bf(Rs[j][e] - eye);
      } else if (idx < 217) {
        u = f2bf(betas[b*10 + (idx - 207)]);
      } else if (idx < 219) {
        u = 0x3F80;   // 1.0f in bf16
      }
      pf_bf[(size_t)b * KP + idx] = u;
    }
  }
  for (int idx = tid; idx < 72; idx += 64) {
    int j = idx/3, cc = idx%3;
    float r = jnt[j][cc];
    if (j > 0) r -= jnt[c_par[j]][cc];
    rel[j][cc] = r;
  }
  __syncthreads();
  if (tid < 12) {
    int m = tid/4, nn = tid%4;
    A_s[0][tid] = (nn < 3) ? Rs[0][m*3+nn] : rel[0][m];
  }
  __syncthreads();
  for (int i = 1; i < 24; i++) {
    if (tid < 12) {
      int m = tid/4, nn = tid%4;
      int p = c_par[i];
      float v;
      if (nn < 3)
        v = A_s[p][m*4+0]*Rs[i][0+nn] + A_s[p][m*4+1]*Rs[i][3+nn] + A_s[p][m*4+2]*Rs[i][6+nn];
      else
        v = A_s[p][m*4+0]*rel[i][0] + A_s[p][m*4+1]*rel[i][1] + A_s[p][m*4+2]*rel[i][2] + A_s[p][m*4+3];
      A_s[i][tid] = v;
    }
    __syncthreads();
  }
  for (int idx = tid; idx < 72; idx += 64) {
    int j = idx/3, cc = idx%3;
    out_joints[(size_t)b * 72 + idx] = A_s[j][cc*4+3] + transl[b*3+cc];
  }
  // A_rel fp32 (fallback path)
  for (int idx = tid; idx < 288; idx += 64) {
    int j = idx/12, r = idx%12, m = r/4, nn = r%4;
    float v;
    if (nn < 3) v = A_s[j][m*4+nn];
    else v = A_s[j][m*4+3] - (A_s[j][m*4+0]*jnt[j][0] + A_s[j][m*4+1]*jnt[j][1] + A_s[j][m*4+2]*jnt[j][2]);
    Ar_ws[(size_t)b * 288 + idx] = v;
  }
  // A_rel MFMA fragments [e=16][k=32], split hi/lo bf16
  if (Ar_hi) {
    for (int idx = tid; idx < 512; idx += 64) {
      int e = idx >> 5, k = idx & 31;
      float a = 0.f;
      if (e < 12 && k < 24) {
        int m = e >> 2, nn = e & 3;
        if (nn < 3) a = A_s[k][m*4+nn];
        else a = A_s[k][m*4+3] - (A_s[k][m*4+0]*jnt[k][0] + A_s[k][m*4+1]*jnt[k][1] + A_s[k][m*4+2]*jnt[k][2]);
      }
      unsigned short hi = f2bf(a);
      Ar_hi[(size_t)b * 512 + idx] = hi;
      Ar_lo[(size_t)b * 512 + idx] = f2bf(a - bf2f(hi));
    }
  }
}

// ---------------- Kernel C: build bf16 B matrix (pdirs+sdirs+vtpl) and W hi/lo ----------------
__global__ __launch_bounds__(256) void k_conv(
    const float* __restrict__ pdirs, const float* __restrict__ sdirs,
    const float* __restrict__ vtpl, const float* __restrict__ W,
    unsigned short* __restrict__ B_lin,
    unsigned short* __restrict__ W_hi, unsigned short* __restrict__ W_lo)
{
  if (blockIdx.x < 2268) {
    const int pair = blockIdx.x * 4 + (threadIdx.x >> 6);   // nt*7+s, 0..9071
    const int l = threadIdx.x & 63;
    const int nt = pair / 7, s = pair % 7;
    const int col = nt * 16 + (l & 15);
    const int kb = s * 32 + ((l >> 4) << 3);
    unsigned short vals[8];
#pragma unroll
    for (int j = 0; j < 8; j++) {
      int k = kb + j;
      unsigned short u = 0;
      if (col < N3n) {
        if (k < Pn) u = f2bf(pdirs[(size_t)k * N3n + col]);
        else if (k < 217) u = f2bf(sdirs[(size_t)col * 10 + (k - 207)]);
        else if (k == 217) u = f2bf(vtpl[col]);
        else if (k == 218) {
          float t = vtpl[col];
          u = f2bf(t - bf2f(f2bf(t)));
        }
      }
      vals[j] = u;
    }
    uint4 o;
    o.x = (unsigned)vals[0] | ((unsigned)vals[1] << 16);
    o.y = (unsigned)vals[2] | ((unsigned)vals[3] << 16);
    o.z = (unsigned)vals[4] | ((unsigned)vals[5] << 16);
    o.w = (unsigned)vals[6] | ((unsigned)vals[7] << 16);
    *(uint4*)(B_lin + (size_t)pair * 512 + l * 8) = o;
  } else {
    int idx = (blockIdx.x - 2268) * 256 + threadIdx.x;
    if (idx < VPAD * 32) {
      int v = idx >> 5, k = idx & 31;
      float f = (v < Vn && k < 24) ? W[(size_t)v * 24 + k] : 0.f;
      unsigned short hi = f2bf(f);
      W_hi[idx] = hi;
      W_lo[idx] = f2bf(f - bf2f(hi));
    }
  }
}

// ---------------- Kernel 3: MFMA v_posed GEMM + swapped-operand T-blend + in-lane epilogue ----------------
// grid = (32 b-tiles, 108 v-tiles), 256 threads (4 waves). Tile: 16 batches x 64 vertices.
// Phase 2 trick: mfma(Ar_frag, W_frag) -> C[row=e][col=vertex]; lane group g=(l>>4) holds
// the 4 coefficients of output component g for vertex c=(l&15): no T staging, no barriers.
__global__ __launch_bounds__(256) void k_mm(
    const float* __restrict__ transl,
    const unsigned short* __restrict__ pf_bf, const unsigned short* __restrict__ B_lin,
    const unsigned short* __restrict__ W_hi, const unsigned short* __restrict__ W_lo,
    const unsigned short* __restrict__ Ar_hi, const unsigned short* __restrict__ Ar_lo,
    float* __restrict__ out)
{
  const int tid = threadIdx.x;
  const int l = tid & 63;
  const int wave = tid >> 6;
  const int b0 = blockIdx.x * 16;
  const int v0 = blockIdx.y * 64;

  __shared__ __align__(16) float vp[16][196];      // v_posed tile (192 cols + pad)
  __shared__ float transl_s[16][3];

  if (tid < 48) transl_s[tid / 3][tid % 3] = transl[(size_t)b0 * 3 + tid];

  // ---- phase 1: vp[b][n] = sum_k pf_ext[b][k] * B[k][n] (v_posed incl. shape + template)
  const unsigned short* pfb = pf_bf + (size_t)(b0 + (l & 15)) * KP + ((l >> 4) << 3);
  const int ntb = blockIdx.y * 12 + wave * 3;
  f32x4 acc0 = {0.f,0.f,0.f,0.f}, acc1 = {0.f,0.f,0.f,0.f}, acc2 = {0.f,0.f,0.f,0.f};
#pragma unroll
  for (int s = 0; s < 7; s++) {
    short8v a   = *(const short8v*)(pfb + s * 32);
    short8v bv0 = *(const short8v*)(B_lin + ((size_t)(ntb + 0) * 7 + s) * 512 + l * 8);
    short8v bv1 = *(const short8v*)(B_lin + ((size_t)(ntb + 1) * 7 + s) * 512 + l * 8);
    short8v bv2 = *(const short8v*)(B_lin + ((size_t)(ntb + 2) * 7 + s) * 512 + l * 8);
    acc0 = __builtin_amdgcn_mfma_f32_16x16x32_bf16(a, bv0, acc0, 0, 0, 0);
    acc1 = __builtin_amdgcn_mfma_f32_16x16x32_bf16(a, bv1, acc1, 0, 0, 0);
    acc2 = __builtin_amdgcn_mfma_f32_16x16x32_bf16(a, bv2, acc2, 0, 0, 0);
  }
  {
    const int colb = wave * 48 + (l & 15);
    const int rowb = (l >> 4) * 4;
#pragma unroll
    for (int r = 0; r < 4; r++) vp[rowb + r][colb]      = acc0[r];
#pragma unroll
    for (int r = 0; r < 4; r++) vp[rowb + r][colb + 16] = acc1[r];
#pragma unroll
    for (int r = 0; r < 4; r++) vp[rowb + r][colb + 32] = acc2[r];
  }
  __syncthreads();

  // ---- phase 2 + epilogue: each wave owns 4 batches. No further barriers.
  const int c = l & 15;         // vertex within 16-row block / e-col in frags
  const int g = l >> 4;         // output component (0..2), 3 = padding lanes
  const int kk = g << 3;

  short8v whi[4], wlo[4];
#pragma unroll
  for (int mt = 0; mt < 4; mt++) {
    const size_t wb = (size_t)(v0 + mt * 16 + c) * 32 + kk;
    whi[mt] = *(const short8v*)(W_hi + wb);
    wlo[mt] = *(const short8v*)(W_lo + wb);
  }

#pragma unroll
  for (int i = 0; i < 4; i++) {
    const int bl = wave * 4 + i;
    const size_t ab = (size_t)(b0 + bl) * 512 + c * 32 + kk;
    short8v ahi = *(const short8v*)(Ar_hi + ab);
    short8v alo = *(const short8v*)(Ar_lo + ab);
    const float trg = transl_s[bl][g < 3 ? g : 0];
#pragma unroll
    for (int mt = 0; mt < 4; mt++) {
      f32x4 t = {0.f, 0.f, 0.f, 0.f};
      t = __builtin_amdgcn_mfma_f32_16x16x32_bf16(alo, whi[mt], t, 0, 0, 0);
      t = __builtin_amdgcn_mfma_f32_16x16x32_bf16(ahi, wlo[mt], t, 0, 0, 0);
      t = __builtin_amdgcn_mfma_f32_16x16x32_bf16(ahi, whi[mt], t, 0, 0, 0);
      const int vl2 = mt * 16 + c;
      const int v = v0 + vl2;
      if (g < 3 && v < Vn) {
        float x = vp[bl][3 * vl2 + 0];
        float y = vp[bl][3 * vl2 + 1];
        float z = vp[bl][3 * vl2 + 2];
        out[((size_t)(b0 + bl) * Vn + v) * 3 + g] = t[0]*x + t[1]*y + t[2]*z + t[3] + trg;
      }
    }
  }
}

// ---------------- Fallback (proven round-4 path) if ws too small ----------------
__global__ __launch_bounds__(192) void k_verts_fb(
    const float* __restrict__ betas, const float* __restrict__ transl,
    const float* __restrict__ vtpl, const float* __restrict__ sdirs,
    const float* __restrict__ pdirs, const float* __restrict__ W,
    const float* __restrict__ pf_ws, const float* __restrict__ Ar_ws,
    float* __restrict__ out)
{
  const int tid = threadIdx.x;
  const int b0 = blockIdx.x * 16;
  const int v0 = blockIdx.y * 128;
  const int n0 = v0 * 3;
  __shared__ __align__(16) float pf_s[Pn][16];
  __shared__ __align__(16) float Ar_s[16][288];
  __shared__ __align__(16) float vp_s[16][384];
  __shared__ float betas_s[16][NBn];
  __shared__ float transl_s[16][3];
  for (int idx = tid; idx < Pn * 16; idx += 192) {
    int p = idx >> 4, bi = idx & 15;
    pf_s[p][bi] = pf_ws[(size_t)(b0 + bi) * Pn + p];
  }
  for (int idx = tid; idx < 16 * 288; idx += 192)
    Ar_s[idx / 288][idx % 288] = Ar_ws[(size_t)b0 * 288 + idx];
  for (int idx = tid; idx < 16 * NBn; idx += 192)
    betas_s[idx / NBn][idx % NBn] = betas[(size_t)b0 * NBn + idx];
  for (int idx = tid; idx < 48; idx += 192)
    transl_s[idx / 3][idx % 3] = transl[(size_t)b0 * 3 + idx];
  __syncthreads();
  const int n = n0 + 2 * tid;
  const bool valid = (n < N3n);
  float acc0[16], acc1[16];
#pragma unroll
  for (int i = 0; i < 16; i++) { acc0[i] = 0.f; acc1[i] = 0.f; }
  for (int p = 0; p < Pn; p++) {
    float pd0 = 0.f, pd1 = 0.f;
    if (valid) { float2 t = *(const float2*)(pdirs + (size_t)p * N3n + n); pd0 = t.x; pd1 = t.y; }
    const float4* row = (const float4*)(pf_s[p]);
#pragma unroll
    for (int q = 0; q < 4; q++) {
      float4 f = row[q];
      acc0[4*q+0] += f.x * pd0;  acc1[4*q+0] += f.x * pd1;
      acc0[4*q+1] += f.y * pd0;  acc1[4*q+1] += f.y * pd1;
      acc0[4*q+2] += f.z * pd0;  acc1[4*q+2] += f.z * pd1;
      acc0[4*q+3] += f.w * pd0;  acc1[4*q+3] += f.w * pd1;
    }
  }
  float sd0[10], sd1[10], vt0 = 0.f, vt1 = 0.f;
#pragma unroll
  for (int l = 0; l < 10; l++) { sd0[l] = 0.f; sd1[l] = 0.f; }
  if (valid) {
    for (int l = 0; l < 10; l++) { sd0[l] = sdirs[(size_t)n*10 + l]; sd1[l] = sdirs[(size_t)n*10 + 10 + l]; }
    vt0 = vtpl[n]; vt1 = vtpl[n+1];
  }
#pragma unroll
  for (int bi = 0; bi < 16; bi++) {
    float s0 = vt0, s1 = vt1;
#pragma unroll
    for (int l = 0; l < 10; l++) { float bb = betas_s[bi][l]; s0 += bb*sd0[l]; s1 += bb*sd1[l]; }
    acc0[bi] += s0; acc1[bi] += s1;
  }
#pragma unroll
  for (int bi = 0; bi < 16; bi++) { vp_s[bi][2*tid] = acc0[bi]; vp_s[bi][2*tid+1] = acc1[bi]; }
  __syncthreads();
  const int m = tid / 64;
  const int vl = tid % 64;
  const int va = v0 + vl, vb = v0 + vl + 64;
  const bool va_ok = (va < Vn), vb_ok = (vb < Vn);
  float Wr0[24], Wr1[24];
#pragma unroll
  for (int j = 0; j < 24; j++) { Wr0[j] = 0.f; Wr1[j] = 0.f; }
  if (va_ok) { const float4* wp = (const float4*)(W + (size_t)va*24);
#pragma unroll
    for (int q = 0; q < 6; q++) { float4 f = wp[q]; Wr0[4*q]=f.x; Wr0[4*q+1]=f.y; Wr0[4*q+2]=f.z; Wr0[4*q+3]=f.w; } }
  if (vb_ok) { const float4* wp = (const float4*)(W + (size_t)vb*24);
#pragma unroll
    for (int q = 0; q < 6; q++) { float4 f = wp[q]; Wr1[4*q]=f.x; Wr1[4*q+1]=f.y; Wr1[4*q+2]=f.z; Wr1[4*q+3]=f.w; } }
  for (int bi = 0; bi < 16; bi++) {
    float Ta0=0.f,Ta1=0.f,Ta2=0.f,Ta3=0.f, Tb0=0.f,Tb1=0.f,Tb2=0.f,Tb3=0.f;
    const float4* arb = (const float4*)(Ar_s[bi]);
#pragma unroll
    for (int j = 0; j < 24; j++) {
      float4 a = arb[j*3 + m];
      float wa = Wr0[j], wb = Wr1[j];
      Ta0 += wa*a.x; Ta1 += wa*a.y; Ta2 += wa*a.z; Ta3 += wa*a.w;
      Tb0 += wb*a.x; Tb1 += wb*a.y; Tb2 += wb*a.z; Tb3 += wb*a.w;
    }
    float tr = transl_s[bi][m];
    if (va_ok) {
      float x = vp_s[bi][vl*3+0], y = vp_s[bi][vl*3+1], z = vp_s[bi][vl*3+2];
      out[((size_t)(b0+bi)*Vn + va)*3 + m] = Ta0*x + Ta1*y + Ta2*z + Ta3 + tr;
    }
    if (vb_ok) {
      float x = vp_s[bi][(vl+64)*3+0], y = vp_s[bi][(vl+64)*3+1], z = vp_s[bi][(vl+64)*3+2];
      out[((size_t)(b0+bi)*Vn + vb)*3 + m] = Tb0*x + Tb1*y + Tb2*z + Tb3 + tr;
    }
  }
}

extern "C" void kernel_launch(void* const* d_in, const int* in_sizes, int n_in,
                              void* d_out, int out_size, void* d_ws, size_t ws_size,
                              hipStream_t stream)
{
  const float *betas=nullptr, *bpose=nullptr, *gorient=nullptr, *transl=nullptr,
              *vtpl=nullptr, *sdirs=nullptr, *pdirs=nullptr, *Jreg=nullptr, *W=nullptr;
  int seen1536 = 0, seen165360 = 0;
  for (int i = 0; i < n_in; i++) {
    const float* p = (const float*)d_in[i];
    switch (in_sizes[i]) {
      case 5120:    betas = p; break;
      case 35328:   bpose = p; break;
      case 20670:   vtpl  = p; break;
      case 206700:  sdirs = p; break;
      case 4278690: pdirs = p; break;
      case 1536:    if (seen1536++ == 0) gorient = p; else transl = p; break;
      case 165360:  if (seen165360++ == 0) Jreg = p; else W = p; break;
      default: break;
    }
  }
  float* out = (float*)d_out;

  float* ws   = (float*)d_ws;
  float* part = ws;                                         // 6336 f
  float* JS   = ws + 6336;                                  // 720 f
  float* Jt   = ws + 7056;                                  // 72 f
  float* pf   = ws + 7128;                                  // 105984 f
  float* Ar   = ws + 113112;                                // 147456 f
  unsigned short* pf_bf = (unsigned short*)(ws + 260568);   // 114688 us (57344 f)
  unsigned short* B_lin = (unsigned short*)(ws + 317912);   // 4644864 us (2322432 f)
  unsigned short* W_hi  = (unsigned short*)(ws + 2640344);  // 221184 us (110592 f)
  unsigned short* W_lo  = (unsigned short*)(ws + 2750936);  // 221184 us (110592 f)
  unsigned short* Ar_hi = (unsigned short*)(ws + 2861528);  // 262144 us (131072 f)
  unsigned short* Ar_lo = (unsigned short*)(ws + 2992600);  // 262144 us (131072 f)
  const size_t WS_NEED = (size_t)3123672 * 4;               // 12,494,688 bytes
  const bool big = (ws_size >= WS_NEED);

  k_jsjt_part<<<dim3(72, 8), 256, 0, stream>>>(Jreg, vtpl, sdirs, part);
  k_jsjt_red<<<1, 1024, 0, stream>>>(part, JS, Jt);
  k_pose<<<Bn, 64, 0, stream>>>(betas, bpose, gorient, transl, JS, Jt,
                                pf, big ? pf_bf : (unsigned short*)nullptr, Ar,
                                big ? Ar_hi : (unsigned short*)nullptr,
                                big ? Ar_lo : (unsigned short*)nullptr,
                                out + (size_t)Bn * Vn * 3);
  if (big) {
    k_conv<<<3132, 256, 0, stream>>>(pdirs, sdirs, vtpl, W, B_lin, W_hi, W_lo);
    k_mm<<<dim3(32, 108), 256, 0, stream>>>(transl, pf_bf, B_lin,
                                            W_hi, W_lo, Ar_hi, Ar_lo, out);
  } else {
    k_verts_fb<<<dim3(32, 54), 192, 0, stream>>>(betas, transl, vtpl, sdirs,
                                                 pdirs, W, pf, Ar, out);
  }
}

// Round 9
// 63.280 us; speedup vs baseline: 5.2486x; 1.2601x over previous
//
#include <hip/hip_runtime.h>
#include <hip/hip_bf16.h>
#include <math.h>

#define Bn 512
#define Vn 6890
#define NBn 10
#define Pn 207
#define N3n 20670   // Vn*3
#define KP 224      // padded K for pose GEMM; rows: 0-206 pf, 207-216 betas, 217 vtpl_hi, 218 vtpl_lo
#define VPAD 6912   // padded vertex rows for W (108*64)

typedef __attribute__((ext_vector_type(8))) short short8v;
typedef __attribute__((ext_vector_type(4))) float f32x4;

__constant__ int c_par[24] = {-1,0,0,0,1,2,3,4,5,6,7,8,9,9,9,12,13,14,16,17,18,19,20,21};
__constant__ int c_lvl[10] = {0,1,4,7,10,15,18,20,22,24};   // depth-level ranges (contiguous)

static __device__ __forceinline__ unsigned short f2bf(float f) {
  union { float f; unsigned u; } x; x.f = f;
  unsigned r = x.u + 0x7FFFu + ((x.u >> 16) & 1u);   // RNE, finite inputs
  return (unsigned short)(r >> 16);
}
static __device__ __forceinline__ float bf2f(unsigned short h) {
  union { unsigned u; float f; } x; x.u = ((unsigned)h) << 16; return x.f;
}

// ================= BIG PATH =================

// ---------------- k_prep: jsjt partials (blocks 0..575) U bf16 conversions (576..3707) ----------------
__global__ __launch_bounds__(256) void k_prep(
    const float* __restrict__ Jreg, const float* __restrict__ vtpl,
    const float* __restrict__ sdirs, const float* __restrict__ pdirs,
    const float* __restrict__ W, float* __restrict__ part,
    unsigned short* __restrict__ B_lin,
    unsigned short* __restrict__ W_hi, unsigned short* __restrict__ W_lo)
{
  const int tid = threadIdx.x;
  if (blockIdx.x < 576) {
    const int bid = blockIdx.x % 72;          // j*3+c
    const int chunk = blockIdx.x / 72;        // 0..7
    const int j = bid / 3, c = bid % 3;
    const int vlo = chunk * 862;
    const int vhi = min(Vn, vlo + 862);
    float acc[11];
#pragma unroll
    for (int k = 0; k < 11; k++) acc[k] = 0.f;
    for (int v = vlo + tid; v < vhi; v += 256) {
      float w = Jreg[(size_t)j * Vn + v];
      int n = v * 3 + c;
#pragma unroll
      for (int l = 0; l < 10; l++) acc[l] += w * sdirs[(size_t)n * 10 + l];
      acc[10] += w * vtpl[n];
    }
    __shared__ float red[256];
    for (int k = 0; k < 11; k++) {
      red[tid] = acc[k];
      __syncthreads();
      for (int s = 128; s > 0; s >>= 1) {
        if (tid < s) red[tid] += red[tid + s];
        __syncthreads();
      }
      if (tid == 0) part[(size_t)chunk * 792 + bid * 11 + k] = red[0];
      __syncthreads();
    }
  } else if (blockIdx.x < 576 + 2268) {
    // B_lin[((nt*7+s)*64 + l)*8 + j] = bf16(B[k][n]), k = s*32+(l>>4)*8+j, n = nt*16+(l&15)
    const int pair = (blockIdx.x - 576) * 4 + (tid >> 6);   // nt*7+s, 0..9071
    const int l = tid & 63;
    const int nt = pair / 7, s = pair % 7;
    const int col = nt * 16 + (l & 15);
    const int kb = s * 32 + ((l >> 4) << 3);
    unsigned short vals[8];
#pragma unroll
    for (int j = 0; j < 8; j++) {
      int k = kb + j;
      unsigned short u = 0;
      if (col < N3n) {
        if (k < Pn) u = f2bf(pdirs[(size_t)k * N3n + col]);
        else if (k < 217) u = f2bf(sdirs[(size_t)col * 10 + (k - 207)]);
        else if (k == 217) u = f2bf(vtpl[col]);
        else if (k == 218) {
          float t = vtpl[col];
          u = f2bf(t - bf2f(f2bf(t)));
        }
      }
      vals[j] = u;
    }
    uint4 o;
    o.x = (unsigned)vals[0] | ((unsigned)vals[1] << 16);
    o.y = (unsigned)vals[2] | ((unsigned)vals[3] << 16);
    o.z = (unsigned)vals[4] | ((unsigned)vals[5] << 16);
    o.w = (unsigned)vals[6] | ((unsigned)vals[7] << 16);
    *(uint4*)(B_lin + (size_t)pair * 512 + l * 8) = o;
  } else {
    int idx = (blockIdx.x - 576 - 2268) * 256 + tid;
    if (idx < VPAD * 32) {
      int v = idx >> 5, k = idx & 31;
      float f = (v < Vn && k < 24) ? W[(size_t)v * 24 + k] : 0.f;
      unsigned short hi = f2bf(f);
      W_hi[idx] = hi;
      W_lo[idx] = f2bf(f - bf2f(hi));
    }
  }
}

// ---------------- k_pose2: per-batch pose (1 wave), in-block jsjt reduce, level-parallel chain ----------------
__global__ __launch_bounds__(64) void k_pose2(
    const float* __restrict__ betas, const float* __restrict__ body_pose,
    const float* __restrict__ gorient, const float* __restrict__ transl,
    const float* __restrict__ part,
    unsigned short* __restrict__ pf_bf,
    unsigned short* __restrict__ Ar_hi, unsigned short* __restrict__ Ar_lo,
    float* __restrict__ out_joints)
{
  const int b = blockIdx.x;
  const int tid = threadIdx.x;
  __shared__ float JS_s[720];
  __shared__ float Jt_s[72];
  __shared__ float Rs[24][9];
  __shared__ float jnt[24][3];
  __shared__ float rel[24][3];
  __shared__ float A_s[24][12];

  // reduce jsjt partials (part is L2/L3-resident, 25 KB shared by all 512 blocks)
  for (int idx = tid; idx < 792; idx += 64) {
    float s = 0.f;
#pragma unroll
    for (int y = 0; y < 8; y++) s += part[(size_t)y * 792 + idx];
    int bid = idx / 11, k = idx % 11;
    if (k < 10) JS_s[bid * 10 + k] = s;
    else        Jt_s[bid] = s;
  }

  if (tid < 24) {
    float x, y, z;
    if (tid == 0) { x = gorient[b*3+0]; y = gorient[b*3+1]; z = gorient[b*3+2]; }
    else { int o = b*69 + (tid-1)*3; x = body_pose[o]; y = body_pose[o+1]; z = body_pose[o+2]; }
    float ang = sqrtf(x*x + y*y + z*z) + 1e-8f;
    float inv = 1.0f / ang;
    float ux = x*inv, uy = y*inv, uz = z*inv;
    float s = sinf(ang), cc = cosf(ang), omc = 1.0f - cc;
    float K[9] = {0.f, -uz, uy,  uz, 0.f, -ux,  -uy, ux, 0.f};
#pragma unroll
    for (int mm = 0; mm < 3; mm++)
#pragma unroll
      for (int nn = 0; nn < 3; nn++) {
        float kk = K[mm*3+0]*K[0+nn] + K[mm*3+1]*K[3+nn] + K[mm*3+2]*K[6+nn];
        float eye = (mm == nn) ? 1.0f : 0.0f;
        Rs[tid][mm*3+nn] = eye + s*K[mm*3+nn] + omc*kk;
      }
  }
  __syncthreads();

  // unposed joints from betas
  for (int idx = tid; idx < 72; idx += 64) {
    float a = Jt_s[idx];
#pragma unroll
    for (int l = 0; l < 10; l++) a += betas[b*10 + l] * JS_s[idx*10 + l];
    jnt[idx/3][idx%3] = a;
  }
  // pf_bf: extended K rows (pose feature | betas | 1 | 1)
  for (int idx = tid; idx < KP; idx += 64) {
    unsigned short u = 0;
    if (idx < Pn) {
      int j = 1 + idx / 9, e = idx % 9;
      float eye = (e == 0 || e == 4 || e == 8) ? 1.0f : 0.0f;
      u = f2bf(Rs[j][e] - eye);
    } else if (idx < 217) {
      u = f2bf(betas[b*10 + (idx - 207)]);
    } else if (idx < 219) {
      u = 0x3F80;   // 1.0f
    }
    pf_bf[(size_t)b * KP + idx] = u;
  }
  __syncthreads();
  for (int idx = tid; idx < 72; idx += 64) {
    int j = idx/3, cc = idx%3;
    float r = jnt[j][cc];
    if (j > 0) r -= jnt[c_par[j]][cc];
    rel[j][cc] = r;
  }
  __syncthreads();
  if (tid < 12) {
    int m = tid/4, nn = tid%4;
    A_s[0][tid] = (nn < 3) ? Rs[0][m*3+nn] : rel[0][m];
  }
  __syncthreads();
  // kinematic chain, level-parallel (8 levels)
  for (int lev = 1; lev <= 8; lev++) {
    const int s0 = c_lvl[lev], s1 = c_lvl[lev + 1];
    const int jj = tid / 12, r = tid % 12;
    if (jj < s1 - s0) {
      const int i = s0 + jj;
      const int p = c_par[i];
      const int m = r >> 2, nn = r & 3;
      float v;
      if (nn < 3)
        v = A_s[p][m*4+0]*Rs[i][0+nn] + A_s[p][m*4+1]*Rs[i][3+nn] + A_s[p][m*4+2]*Rs[i][6+nn];
      else
        v = A_s[p][m*4+0]*rel[i][0] + A_s[p][m*4+1]*rel[i][1] + A_s[p][m*4+2]*rel[i][2] + A_s[p][m*4+3];
      A_s[i][r] = v;
    }
    __syncthreads();
  }
  for (int idx = tid; idx < 72; idx += 64) {
    int j = idx/3, cc = idx%3;
    out_joints[(size_t)b * 72 + idx] = A_s[j][cc*4+3] + transl[b*3+cc];
  }
  // A_rel MFMA fragments [e=16][k=32], split hi/lo bf16
  for (int idx = tid; idx < 512; idx += 64) {
    int e = idx >> 5, k = idx & 31;
    float a = 0.f;
    if (e < 12 && k < 24) {
      int m = e >> 2, nn = e & 3;
      if (nn < 3) a = A_s[k][m*4+nn];
      else a = A_s[k][m*4+3] - (A_s[k][m*4+0]*jnt[k][0] + A_s[k][m*4+1]*jnt[k][1] + A_s[k][m*4+2]*jnt[k][2]);
    }
    unsigned short hi = f2bf(a);
    Ar_hi[(size_t)b * 512 + idx] = hi;
    Ar_lo[(size_t)b * 512 + idx] = f2bf(a - bf2f(hi));
  }
}

// ---------------- k_mm2: 32 batches x 64 vertices per block ----------------
// grid = (16, 108), 256 threads (4 waves). Phase-2 swapped-operand trick as round 8.
__global__ __launch_bounds__(256) void k_mm2(
    const float* __restrict__ transl,
    const unsigned short* __restrict__ pf_bf, const unsigned short* __restrict__ B_lin,
    const unsigned short* __restrict__ W_hi, const unsigned short* __restrict__ W_lo,
    const unsigned short* __restrict__ Ar_hi, const unsigned short* __restrict__ Ar_lo,
    float* __restrict__ out)
{
  const int tid = threadIdx.x;
  const int l = tid & 63;
  const int wave = tid >> 6;
  const int b0 = blockIdx.x * 32;
  const int v0 = blockIdx.y * 64;

  __shared__ __align__(16) float vp[32][196];
  __shared__ float transl_s[32][3];

  if (tid < 96) transl_s[tid / 3][tid % 3] = transl[(size_t)b0 * 3 + tid];

  // ---- phase 1: v_posed GEMM, two 16-row tiles share the B fragments
  const unsigned short* pfb0 = pf_bf + (size_t)(b0 + (l & 15)) * KP + ((l >> 4) << 3);
  const unsigned short* pfb1 = pfb0 + 16 * KP;
  const int ntb = blockIdx.y * 12 + wave * 3;
  f32x4 a00 = {0.f,0.f,0.f,0.f}, a01 = a00, a02 = a00, a10 = a00, a11 = a00, a12 = a00;
#pragma unroll
  for (int s = 0; s < 7; s++) {
    short8v fa0 = *(const short8v*)(pfb0 + s * 32);
    short8v fa1 = *(const short8v*)(pfb1 + s * 32);
    short8v bv0 = *(const short8v*)(B_lin + ((size_t)(ntb + 0) * 7 + s) * 512 + l * 8);
    short8v bv1 = *(const short8v*)(B_lin + ((size_t)(ntb + 1) * 7 + s) * 512 + l * 8);
    short8v bv2 = *(const short8v*)(B_lin + ((size_t)(ntb + 2) * 7 + s) * 512 + l * 8);
    a00 = __builtin_amdgcn_mfma_f32_16x16x32_bf16(fa0, bv0, a00, 0, 0, 0);
    a01 = __builtin_amdgcn_mfma_f32_16x16x32_bf16(fa0, bv1, a01, 0, 0, 0);
    a02 = __builtin_amdgcn_mfma_f32_16x16x32_bf16(fa0, bv2, a02, 0, 0, 0);
    a10 = __builtin_amdgcn_mfma_f32_16x16x32_bf16(fa1, bv0, a10, 0, 0, 0);
    a11 = __builtin_amdgcn_mfma_f32_16x16x32_bf16(fa1, bv1, a11, 0, 0, 0);
    a12 = __builtin_amdgcn_mfma_f32_16x16x32_bf16(fa1, bv2, a12, 0, 0, 0);
  }
  {
    const int colb = wave * 48 + (l & 15);
    const int rowb = (l >> 4) * 4;
#pragma unroll
    for (int r = 0; r < 4; r++) {
      vp[rowb + r][colb]           = a00[r];
      vp[rowb + r][colb + 16]      = a01[r];
      vp[rowb + r][colb + 32]      = a02[r];
      vp[16 + rowb + r][colb]      = a10[r];
      vp[16 + rowb + r][colb + 16] = a11[r];
      vp[16 + rowb + r][colb + 32] = a12[r];
    }
  }
  __syncthreads();

  // ---- phase 2 + epilogue: each wave owns 8 batches; W fragments hoisted.
  const int c = l & 15;         // vertex-within-16 / e-col in frags
  const int g = l >> 4;         // output component (0..2), 3 = padding lanes
  const int kk = g << 3;

  short8v whi[4], wlo[4];
#pragma unroll
  for (int mt = 0; mt < 4; mt++) {
    const size_t wb = (size_t)(v0 + mt * 16 + c) * 32 + kk;
    whi[mt] = *(const short8v*)(W_hi + wb);
    wlo[mt] = *(const short8v*)(W_lo + wb);
  }

#pragma unroll
  for (int i = 0; i < 8; i++) {
    const int bl = wave * 8 + i;
    const size_t ab = (size_t)(b0 + bl) * 512 + c * 32 + kk;
    short8v ahi = *(const short8v*)(Ar_hi + ab);
    short8v alo = *(const short8v*)(Ar_lo + ab);
    const float trg = transl_s[bl][g < 3 ? g : 0];
#pragma unroll
    for (int mt = 0; mt < 4; mt++) {
      f32x4 t = {0.f, 0.f, 0.f, 0.f};
      t = __builtin_amdgcn_mfma_f32_16x16x32_bf16(alo, whi[mt], t, 0, 0, 0);
      t = __builtin_amdgcn_mfma_f32_16x16x32_bf16(ahi, wlo[mt], t, 0, 0, 0);
      t = __builtin_amdgcn_mfma_f32_16x16x32_bf16(ahi, whi[mt], t, 0, 0, 0);
      const int vl2 = mt * 16 + c;
      const int v = v0 + vl2;
      if (g < 3 && v < Vn) {
        float x = vp[bl][3 * vl2 + 0];
        float y = vp[bl][3 * vl2 + 1];
        float z = vp[bl][3 * vl2 + 2];
        out[((size_t)(b0 + bl) * Vn + v) * 3 + g] = t[0]*x + t[1]*y + t[2]*z + t[3] + trg;
      }
    }
  }
}

// ================= FALLBACK PATH (proven round-4 kernels, used only if ws too small) =================

__global__ __launch_bounds__(256) void k_jsjt_part(
    const float* __restrict__ Jreg, const float* __restrict__ vtpl,
    const float* __restrict__ sdirs, float* __restrict__ part)
{
  const int bid = blockIdx.x;
  const int chunk = blockIdx.y;
  const int j = bid / 3, c = bid % 3;
  const int tid = threadIdx.x;
  const int vlo = chunk * 862;
  const int vhi = min(Vn, vlo + 862);
  float acc[11];
#pragma unroll
  for (int k = 0; k < 11; k++) acc[k] = 0.f;
  for (int v = vlo + tid; v < vhi; v += 256) {
    float w = Jreg[(size_t)j * Vn + v];
    int n = v * 3 + c;
#pragma unroll
    for (int l = 0; l < 10; l++) acc[l] += w * sdirs[(size_t)n * 10 + l];
    acc[10] += w * vtpl[n];
  }
  __shared__ float red[256];
  for (int k = 0; k < 11; k++) {
    red[tid] = acc[k];
    __syncthreads();
    for (int s = 128; s > 0; s >>= 1) {
      if (tid < s) red[tid] += red[tid + s];
      __syncthreads();
    }
    if (tid == 0) part[(size_t)chunk * 792 + bid * 11 + k] = red[0];
    __syncthreads();
  }
}

__global__ __launch_bounds__(1024) void k_jsjt_red(
    const float* __restrict__ part, float* __restrict__ JS, float* __restrict__ Jt)
{
  const int t = threadIdx.x;
  if (t >= 792) return;
  float s = 0.f;
#pragma unroll
  for (int y = 0; y < 8; y++) s += part[(size_t)y * 792 + t];
  int bid = t / 11, k = t % 11;
  if (k < 10) JS[bid * 10 + k] = s;
  else        Jt[bid] = s;
}

__global__ __launch_bounds__(64) void k_pose_fb(
    const float* __restrict__ betas, const float* __restrict__ body_pose,
    const float* __restrict__ gorient, const float* __restrict__ transl,
    const float* __restrict__ JS, const float* __restrict__ Jt,
    float* __restrict__ pf_ws, float* __restrict__ Ar_ws,
    float* __restrict__ out_joints)
{
  const int b = blockIdx.x;
  const int tid = threadIdx.x;
  __shared__ float Rs[24][9];
  __shared__ float jnt[24][3];
  __shared__ float rel[24][3];
  __shared__ float A_s[24][12];

  if (tid < 24) {
    float x, y, z;
    if (tid == 0) { x = gorient[b*3+0]; y = gorient[b*3+1]; z = gorient[b*3+2]; }
    else { int o = b*69 + (tid-1)*3; x = body_pose[o]; y = body_pose[o+1]; z = body_pose[o+2]; }
    float ang = sqrtf(x*x + y*y + z*z) + 1e-8f;
    float inv = 1.0f / ang;
    float ux = x*inv, uy = y*inv, uz = z*inv;
    float s = sinf(ang), cc = cosf(ang), omc = 1.0f - cc;
    float K[9] = {0.f, -uz, uy,  uz, 0.f, -ux,  -uy, ux, 0.f};
#pragma unroll
    for (int mm = 0; mm < 3; mm++)
#pragma unroll
      for (int nn = 0; nn < 3; nn++) {
        float kk = K[mm*3+0]*K[0+nn] + K[mm*3+1]*K[3+nn] + K[mm*3+2]*K[6+nn];
        float eye = (mm == nn) ? 1.0f : 0.0f;
        Rs[tid][mm*3+nn] = eye + s*K[mm*3+nn] + omc*kk;
      }
  }
  for (int idx = tid; idx < 72; idx += 64) {
    float a = Jt[idx];
#pragma unroll
    for (int l = 0; l < 10; l++) a += betas[b*10 + l] * JS[idx*10 + l];
    jnt[idx/3][idx%3] = a;
  }
  __syncthreads();
  for (int idx = tid; idx < Pn; idx += 64) {
    int j = 1 + idx / 9, e = idx % 9;
    float eye = (e == 0 || e == 4 || e == 8) ? 1.0f : 0.0f;
    pf_ws[(size_t)b * Pn + idx] = Rs[j][e] - eye;
  }
  for (int idx = tid; idx < 72; idx += 64) {
    int j = idx/3, cc = idx%3;
    float r = jnt[j][cc];
    if (j > 0) r -= jnt[c_par[j]][cc];
    rel[j][cc] = r;
  }
  __syncthreads();
  if (tid < 12) {
    int m = tid/4, nn = tid%4;
    A_s[0][tid] = (nn < 3) ? Rs[0][m*3+nn] : rel[0][m];
  }
  __syncthreads();
  for (int i = 1; i < 24; i++) {
    if (tid < 12) {
      int m = tid/4, nn = tid%4;
      int p = c_par[i];
      float v;
      if (nn < 3)
        v = A_s[p][m*4+0]*Rs[i][0+nn] + A_s[p][m*4+1]*Rs[i][3+nn] + A_s[p][m*4+2]*Rs[i][6+nn];
      else
        v = A_s[p][m*4+0]*rel[i][0] + A_s[p][m*4+1]*rel[i][1] + A_s[p][m*4+2]*rel[i][2] + A_s[p][m*4+3];
      A_s[i][tid] = v;
    }
    __syncthreads();
  }
  for (int idx = tid; idx < 72; idx += 64) {
    int j = idx/3, cc = idx%3;
    out_joints[(size_t)b * 72 + idx] = A_s[j][cc*4+3] + transl[b*3+cc];
  }
  for (int idx = tid; idx < 288; idx += 64) {
    int j = idx/12, r = idx%12, m = r/4, nn = r%4;
    float v;
    if (nn < 3) v = A_s[j][m*4+nn];
    else v = A_s[j][m*4+3] - (A_s[j][m*4+0]*jnt[j][0] + A_s[j][m*4+1]*jnt[j][1] + A_s[j][m*4+2]*jnt[j][2]);
    Ar_ws[(size_t)b * 288 + idx] = v;
  }
}

__global__ __launch_bounds__(192) void k_verts_fb(
    const float* __restrict__ betas, const float* __restrict__ transl,
    const float* __restrict__ vtpl, const float* __restrict__ sdirs,
    const float* __restrict__ pdirs, const float* __restrict__ W,
    const float* __restrict__ pf_ws, const float* __restrict__ Ar_ws,
    float* __restrict__ out)
{
  const int tid = threadIdx.x;
  const int b0 = blockIdx.x * 16;
  const int v0 = blockIdx.y * 128;
  const int n0 = v0 * 3;
  __shared__ __align__(16) float pf_s[Pn][16];
  __shared__ __align__(16) float Ar_s[16][288];
  __shared__ __align__(16) float vp_s[16][384];
  __shared__ float betas_s[16][NBn];
  __shared__ float transl_s[16][3];
  for (int idx = tid; idx < Pn * 16; idx += 192) {
    int p = idx >> 4, bi = idx & 15;
    pf_s[p][bi] = pf_ws[(size_t)(b0 + bi) * Pn + p];
  }
  for (int idx = tid; idx < 16 * 288; idx += 192)
    Ar_s[idx / 288][idx % 288] = Ar_ws[(size_t)b0 * 288 + idx];
  for (int idx = tid; idx < 16 * NBn; idx += 192)
    betas_s[idx / NBn][idx % NBn] = betas[(size_t)b0 * NBn + idx];
  for (int idx = tid; idx < 48; idx += 192)
    transl_s[idx / 3][idx % 3] = transl[(size_t)b0 * 3 + idx];
  __syncthreads();
  const int n = n0 + 2 * tid;
  const bool valid = (n < N3n);
  float acc0[16], acc1[16];
#pragma unroll
  for (int i = 0; i < 16; i++) { acc0[i] = 0.f; acc1[i] = 0.f; }
  for (int p = 0; p < Pn; p++) {
    float pd0 = 0.f, pd1 = 0.f;
    if (valid) { float2 t = *(const float2*)(pdirs + (size_t)p * N3n + n); pd0 = t.x; pd1 = t.y; }
    const float4* row = (const float4*)(pf_s[p]);
#pragma unroll
    for (int q = 0; q < 4; q++) {
      float4 f = row[q];
      acc0[4*q+0] += f.x * pd0;  acc1[4*q+0] += f.x * pd1;
      acc0[4*q+1] += f.y * pd0;  acc1[4*q+1] += f.y * pd1;
      acc0[4*q+2] += f.z * pd0;  acc1[4*q+2] += f.z * pd1;
      acc0[4*q+3] += f.w * pd0;  acc1[4*q+3] += f.w * pd1;
    }
  }
  float sd0[10], sd1[10], vt0 = 0.f, vt1 = 0.f;
#pragma unroll
  for (int l = 0; l < 10; l++) { sd0[l] = 0.f; sd1[l] = 0.f; }
  if (valid) {
    for (int l = 0; l < 10; l++) { sd0[l] = sdirs[(size_t)n*10 + l]; sd1[l] = sdirs[(size_t)n*10 + 10 + l]; }
    vt0 = vtpl[n]; vt1 = vtpl[n+1];
  }
#pragma unroll
  for (int bi = 0; bi < 16; bi++) {
    float s0 = vt0, s1 = vt1;
#pragma unroll
    for (int l = 0; l < 10; l++) { float bb = betas_s[bi][l]; s0 += bb*sd0[l]; s1 += bb*sd1[l]; }
    acc0[bi] += s0; acc1[bi] += s1;
  }
#pragma unroll
  for (int bi = 0; bi < 16; bi++) { vp_s[bi][2*tid] = acc0[bi]; vp_s[bi][2*tid+1] = acc1[bi]; }
  __syncthreads();
  const int m = tid / 64;
  const int vl = tid % 64;
  const int va = v0 + vl, vb = v0 + vl + 64;
  const bool va_ok = (va < Vn), vb_ok = (vb < Vn);
  float Wr0[24], Wr1[24];
#pragma unroll
  for (int j = 0; j < 24; j++) { Wr0[j] = 0.f; Wr1[j] = 0.f; }
  if (va_ok) { const float4* wp = (const float4*)(W + (size_t)va*24);
#pragma unroll
    for (int q = 0; q < 6; q++) { float4 f = wp[q]; Wr0[4*q]=f.x; Wr0[4*q+1]=f.y; Wr0[4*q+2]=f.z; Wr0[4*q+3]=f.w; } }
  if (vb_ok) { const float4* wp = (const float4*)(W + (size_t)vb*24);
#pragma unroll
    for (int q = 0; q < 6; q++) { float4 f = wp[q]; Wr1[4*q]=f.x; Wr1[4*q+1]=f.y; Wr1[4*q+2]=f.z; Wr1[4*q+3]=f.w; } }
  for (int bi = 0; bi < 16; bi++) {
    float Ta0=0.f,Ta1=0.f,Ta2=0.f,Ta3=0.f, Tb0=0.f,Tb1=0.f,Tb2=0.f,Tb3=0.f;
    const float4* arb = (const float4*)(Ar_s[bi]);
#pragma unroll
    for (int j = 0; j < 24; j++) {
      float4 a = arb[j*3 + m];
      float wa = Wr0[j], wb = Wr1[j];
      Ta0 += wa*a.x; Ta1 += wa*a.y; Ta2 += wa*a.z; Ta3 += wa*a.w;
      Tb0 += wb*a.x; Tb1 += wb*a.y; Tb2 += wb*a.z; Tb3 += wb*a.w;
    }
    float tr = transl_s[bi][m];
    if (va_ok) {
      float x = vp_s[bi][vl*3+0], y = vp_s[bi][vl*3+1], z = vp_s[bi][vl*3+2];
      out[((size_t)(b0+bi)*Vn + va)*3 + m] = Ta0*x + Ta1*y + Ta2*z + Ta3 + tr;
    }
    if (vb_ok) {
      float x = vp_s[bi][(vl+64)*3+0], y = vp_s[bi][(vl+64)*3+1], z = vp_s[bi][(vl+64)*3+2];
      out[((size_t)(b0+bi)*Vn + vb)*3 + m] = Tb0*x + Tb1*y + Tb2*z + Tb3 + tr;
    }
  }
}

extern "C" void kernel_launch(void* const* d_in, const int* in_sizes, int n_in,
                              void* d_out, int out_size, void* d_ws, size_t ws_size,
                              hipStream_t stream)
{
  const float *betas=nullptr, *bpose=nullptr, *gorient=nullptr, *transl=nullptr,
              *vtpl=nullptr, *sdirs=nullptr, *pdirs=nullptr, *Jreg=nullptr, *W=nullptr;
  int seen1536 = 0, seen165360 = 0;
  for (int i = 0; i < n_in; i++) {
    const float* p = (const float*)d_in[i];
    switch (in_sizes[i]) {
      case 5120:    betas = p; break;
      case 35328:   bpose = p; break;
      case 20670:   vtpl  = p; break;
      case 206700:  sdirs = p; break;
      case 4278690: pdirs = p; break;
      case 1536:    if (seen1536++ == 0) gorient = p; else transl = p; break;
      case 165360:  if (seen165360++ == 0) Jreg = p; else W = p; break;
      default: break;
    }
  }
  float* out = (float*)d_out;

  float* ws   = (float*)d_ws;
  float* part = ws;                                         // 6336 f
  float* JS   = ws + 6336;                                  // 720 f   (fallback)
  float* Jt   = ws + 7056;                                  // 72 f    (fallback)
  float* pf   = ws + 7128;                                  // 105984 f (fallback)
  float* Ar   = ws + 113112;                                // 147456 f (fallback)
  unsigned short* pf_bf = (unsigned short*)(ws + 260568);   // 114688 us
  unsigned short* B_lin = (unsigned short*)(ws + 317912);   // 4644864 us
  unsigned short* W_hi  = (unsigned short*)(ws + 2640344);  // 221184 us
  unsigned short* W_lo  = (unsigned short*)(ws + 2750936);  // 221184 us
  unsigned short* Ar_hi = (unsigned short*)(ws + 2861528);  // 262144 us
  unsigned short* Ar_lo = (unsigned short*)(ws + 2992600);  // 262144 us
  const size_t WS_NEED = (size_t)3123672 * 4;               // 12,494,688 bytes
  const bool big = (ws_size >= WS_NEED);

  if (big) {
    k_prep<<<3708, 256, 0, stream>>>(Jreg, vtpl, sdirs, pdirs, W,
                                     part, B_lin, W_hi, W_lo);
    k_pose2<<<Bn, 64, 0, stream>>>(betas, bpose, gorient, transl, part,
                                   pf_bf, Ar_hi, Ar_lo,
                                   out + (size_t)Bn * Vn * 3);
    k_mm2<<<dim3(16, 108), 256, 0, stream>>>(transl, pf_bf, B_lin,
                                             W_hi, W_lo, Ar_hi, Ar_lo, out);
  } else {
    k_jsjt_part<<<dim3(72, 8), 256, 0, stream>>>(Jreg, vtpl, sdirs, part);
    k_jsjt_red<<<1, 1024, 0, stream>>>(part, JS, Jt);
    k_pose_fb<<<Bn, 64, 0, stream>>>(betas, bpose, gorient, transl, JS, Jt, pf, Ar,
                                     out + (size_t)Bn * Vn * 3);
    k_verts_fb<<<dim3(32, 54), 192, 0, stream>>>(betas, transl, vtpl, sdirs,
                                                 pdirs, W, pf, Ar, out);
  }
}

// Round 10
// 59.889 us; speedup vs baseline: 5.5458x; 1.0566x over previous
//
#include <hip/hip_runtime.h>
#include <hip/hip_bf16.h>
#include <math.h>

#define Bn 512
#define Vn 6890
#define NBn 10
#define Pn 207
#define N3n 20670   // Vn*3
#define KP 224      // padded K: 0-206 pf, 207-216 betas, 217 vtpl_hi, 218 vtpl_lo
#define VPAD 6912   // padded vertex rows for W (108*64)

typedef __attribute__((ext_vector_type(8))) _Float16 half8;
typedef __attribute__((ext_vector_type(4))) float f32x4;

__constant__ int c_par[24] = {-1,0,0,0,1,2,3,4,5,6,7,8,9,9,9,12,13,14,16,17,18,19,20,21};
__constant__ int c_lvl[10] = {0,1,4,7,10,15,18,20,22,24};   // chain depth-level ranges

// ================= BIG PATH (fp16 MFMA) =================

// ---------------- k_prep: jsjt partials (0..575) U B fp16 (576..2843) U W fp16 (2844..3707) ----------------
__global__ __launch_bounds__(256) void k_prep(
    const float* __restrict__ Jreg, const float* __restrict__ vtpl,
    const float* __restrict__ sdirs, const float* __restrict__ pdirs,
    const float* __restrict__ W, float* __restrict__ part,
    _Float16* __restrict__ B_h, _Float16* __restrict__ W_h)
{
  const int tid = threadIdx.x;
  if (blockIdx.x < 576) {
    const int bid = blockIdx.x % 72;          // j*3+c
    const int chunk = blockIdx.x / 72;        // 0..7
    const int j = bid / 3, c = bid % 3;
    const int vlo = chunk * 862;
    const int vhi = min(Vn, vlo + 862);
    float acc[11];
#pragma unroll
    for (int k = 0; k < 11; k++) acc[k] = 0.f;
    for (int v = vlo + tid; v < vhi; v += 256) {
      float w = Jreg[(size_t)j * Vn + v];
      int n = v * 3 + c;
#pragma unroll
      for (int l = 0; l < 10; l++) acc[l] += w * sdirs[(size_t)n * 10 + l];
      acc[10] += w * vtpl[n];
    }
    __shared__ float red[256];
    for (int k = 0; k < 11; k++) {
      red[tid] = acc[k];
      __syncthreads();
      for (int s = 128; s > 0; s >>= 1) {
        if (tid < s) red[tid] += red[tid + s];
        __syncthreads();
      }
      if (tid == 0) part[(size_t)chunk * 792 + bid * 11 + k] = red[0];
      __syncthreads();
    }
  } else if (blockIdx.x < 576 + 2268) {
    // B_h[((nt*7+s)*64 + l)*8 + j] = f16(B[k][n]), k = s*32+(l>>4)*8+j, n = nt*16+(l&15)
    const int pair = (blockIdx.x - 576) * 4 + (tid >> 6);   // nt*7+s
    const int l = tid & 63;
    const int nt = pair / 7, s = pair % 7;
    const int col = nt * 16 + (l & 15);
    const int kb = s * 32 + ((l >> 4) << 3);
    half8 hv;
#pragma unroll
    for (int j = 0; j < 8; j++) {
      int k = kb + j;
      float f = 0.f;
      if (col < N3n) {
        if (k < Pn) f = pdirs[(size_t)k * N3n + col];
        else if (k < 217) f = sdirs[(size_t)col * 10 + (k - 207)];
        else if (k == 217) f = (float)(_Float16)vtpl[col];
        else if (k == 218) {
          float t = vtpl[col];
          f = t - (float)(_Float16)t;
        }
      }
      hv[j] = (_Float16)f;
    }
    *(half8*)(B_h + (size_t)pair * 512 + l * 8) = hv;
  } else {
    int idx = (blockIdx.x - 576 - 2268) * 256 + tid;
    if (idx < VPAD * 32) {
      int v = idx >> 5, k = idx & 31;
      float f = (v < Vn && k < 24) ? W[(size_t)v * 24 + k] : 0.f;
      W_h[idx] = (_Float16)f;
    }
  }
}

// ---------------- k_pose2: 8 batches/block (1 wave each), shared jsjt reduce ----------------
__global__ __launch_bounds__(512) void k_pose2(
    const float* __restrict__ betas, const float* __restrict__ body_pose,
    const float* __restrict__ gorient, const float* __restrict__ transl,
    const float* __restrict__ part,
    _Float16* __restrict__ pf_h, _Float16* __restrict__ Ar_h,
    float* __restrict__ out_joints)
{
  const int tid = threadIdx.x;
  const int wave = tid >> 6;
  const int lane = tid & 63;
  const int b = blockIdx.x * 8 + wave;

  __shared__ float JS_s[720];
  __shared__ float Jt_s[72];
  __shared__ float Rs[8][24][9];
  __shared__ float jnt[8][24][3];
  __shared__ float rel[8][24][3];
  __shared__ float A_s[8][24][12];

  // jsjt reduce (once per block)
  for (int idx = tid; idx < 792; idx += 512) {
    float s = 0.f;
#pragma unroll
    for (int y = 0; y < 8; y++) s += part[(size_t)y * 792 + idx];
    int bid = idx / 11, k = idx % 11;
    if (k < 10) JS_s[bid * 10 + k] = s;
    else        Jt_s[bid] = s;
  }

  if (lane < 24) {
    float x, y, z;
    if (lane == 0) { x = gorient[b*3+0]; y = gorient[b*3+1]; z = gorient[b*3+2]; }
    else { int o = b*69 + (lane-1)*3; x = body_pose[o]; y = body_pose[o+1]; z = body_pose[o+2]; }
    float ang = sqrtf(x*x + y*y + z*z) + 1e-8f;
    float inv = 1.0f / ang;
    float ux = x*inv, uy = y*inv, uz = z*inv;
    float s = sinf(ang), cc = cosf(ang), omc = 1.0f - cc;
    float K[9] = {0.f, -uz, uy,  uz, 0.f, -ux,  -uy, ux, 0.f};
#pragma unroll
    for (int mm = 0; mm < 3; mm++)
#pragma unroll
      for (int nn = 0; nn < 3; nn++) {
        float kk = K[mm*3+0]*K[0+nn] + K[mm*3+1]*K[3+nn] + K[mm*3+2]*K[6+nn];
        float eye = (mm == nn) ? 1.0f : 0.0f;
        Rs[wave][lane][mm*3+nn] = eye + s*K[mm*3+nn] + omc*kk;
      }
  }
  __syncthreads();   // JS_s + Rs visible

  // unposed joints from betas
  for (int idx = lane; idx < 72; idx += 64) {
    float a = Jt_s[idx];
#pragma unroll
    for (int l = 0; l < 10; l++) a += betas[b*10 + l] * JS_s[idx*10 + l];
    jnt[wave][idx/3][idx%3] = a;
  }
  // pf_h: extended K rows (pose feature | betas | 1 | 1)
  for (int idx = lane; idx < KP; idx += 64) {
    float f = 0.f;
    if (idx < Pn) {
      int j = 1 + idx / 9, e = idx % 9;
      float eye = (e == 0 || e == 4 || e == 8) ? 1.0f : 0.0f;
      f = Rs[wave][j][e] - eye;
    } else if (idx < 217) {
      f = betas[b*10 + (idx - 207)];
    } else if (idx < 219) {
      f = 1.0f;
    }
    pf_h[(size_t)b * KP + idx] = (_Float16)f;
  }
  __syncthreads();
  for (int idx = lane; idx < 72; idx += 64) {
    int j = idx/3, cc = idx%3;
    float r = jnt[wave][j][cc];
    if (j > 0) r -= jnt[wave][c_par[j]][cc];
    rel[wave][j][cc] = r;
  }
  __syncthreads();
  if (lane < 12) {
    int m = lane/4, nn = lane%4;
    A_s[wave][0][lane] = (nn < 3) ? Rs[wave][0][m*3+nn] : rel[wave][0][m];
  }
  __syncthreads();
  // kinematic chain, level-parallel
  for (int lev = 1; lev <= 8; lev++) {
    const int s0 = c_lvl[lev], s1 = c_lvl[lev + 1];
    const int jj = lane / 12, r = lane % 12;
    if (jj < s1 - s0) {
      const int i = s0 + jj;
      const int p = c_par[i];
      const int m = r >> 2, nn = r & 3;
      float v;
      if (nn < 3)
        v = A_s[wave][p][m*4+0]*Rs[wave][i][0+nn] + A_s[wave][p][m*4+1]*Rs[wave][i][3+nn] + A_s[wave][p][m*4+2]*Rs[wave][i][6+nn];
      else
        v = A_s[wave][p][m*4+0]*rel[wave][i][0] + A_s[wave][p][m*4+1]*rel[wave][i][1] + A_s[wave][p][m*4+2]*rel[wave][i][2] + A_s[wave][p][m*4+3];
      A_s[wave][i][r] = v;
    }
    __syncthreads();
  }
  for (int idx = lane; idx < 72; idx += 64) {
    int j = idx/3, cc = idx%3;
    out_joints[(size_t)b * 72 + idx] = A_s[wave][j][cc*4+3] + transl[b*3+cc];
  }
  // A_rel MFMA fragments [e=16][k=32], fp16
  for (int idx = lane; idx < 512; idx += 64) {
    int e = idx >> 5, k = idx & 31;
    float a = 0.f;
    if (e < 12 && k < 24) {
      int m = e >> 2, nn = e & 3;
      if (nn < 3) a = A_s[wave][k][m*4+nn];
      else a = A_s[wave][k][m*4+3] - (A_s[wave][k][m*4+0]*jnt[wave][k][0] + A_s[wave][k][m*4+1]*jnt[wave][k][1] + A_s[wave][k][m*4+2]*jnt[wave][k][2]);
    }
    Ar_h[(size_t)b * 512 + idx] = (_Float16)a;
  }
}

// ---------------- k_mm3: 64 batches x 64 vertices per block, fp16 MFMA ----------------
// 1-D grid 896, XCD co-location: v_tile = (lin%8)*14 + lin/64; b_tile = (lin>>3)&7.
__global__ __launch_bounds__(256) void k_mm3(
    const float* __restrict__ transl,
    const _Float16* __restrict__ pf_h, const _Float16* __restrict__ B_h,
    const _Float16* __restrict__ W_h, const _Float16* __restrict__ Ar_h,
    float* __restrict__ out)
{
  const int lin = blockIdx.x;
  const int r8 = lin & 7;
  const int k2 = lin >> 3;        // 0..111
  const int b_t = k2 & 7;
  const int m8 = k2 >> 3;         // 0..13
  const int v_t = r8 * 14 + m8;   // 0..111
  if (v_t >= 108) return;

  const int tid = threadIdx.x;
  const int l = tid & 63;
  const int wave = tid >> 6;
  const int b0 = b_t * 64;
  const int v0 = v_t * 64;

  __shared__ __align__(16) float vp[64][196];
  __shared__ float transl_s[64][3];

  if (tid < 192) transl_s[tid / 3][tid % 3] = transl[(size_t)b0 * 3 + tid];

  // ---- phase 1: v_posed GEMM; 4 A-row-tiles share B fragments
  const int c0 = l & 15;
  const int kk0 = (l >> 4) << 3;
  const int ntb = v_t * 12 + wave * 3;
  f32x4 acc[4][3];
#pragma unroll
  for (int t = 0; t < 4; t++)
#pragma unroll
    for (int n = 0; n < 3; n++) acc[t][n] = (f32x4){0.f, 0.f, 0.f, 0.f};

#pragma unroll
  for (int s = 0; s < 7; s++) {
    half8 bv[3];
#pragma unroll
    for (int n = 0; n < 3; n++)
      bv[n] = *(const half8*)(B_h + ((size_t)(ntb + n) * 7 + s) * 512 + l * 8);
#pragma unroll
    for (int t = 0; t < 4; t++) {
      half8 fa = *(const half8*)(pf_h + (size_t)(b0 + t * 16 + c0) * KP + kk0 + s * 32);
#pragma unroll
      for (int n = 0; n < 3; n++)
        acc[t][n] = __builtin_amdgcn_mfma_f32_16x16x32_f16(fa, bv[n], acc[t][n], 0, 0, 0);
    }
  }
  {
    const int colb = wave * 48 + c0;
    const int rowb = (l >> 4) * 4;
#pragma unroll
    for (int t = 0; t < 4; t++)
#pragma unroll
      for (int n = 0; n < 3; n++)
#pragma unroll
        for (int r = 0; r < 4; r++)
          vp[t * 16 + rowb + r][colb + n * 16] = acc[t][n][r];
  }
  __syncthreads();

  // ---- phase 2 + epilogue: each wave owns 16 batches; single fp16 MFMA per (batch, mt)
  const int c = l & 15;         // vertex-within-16 / e-row in A frag
  const int g = l >> 4;         // output component (0..2); 3 = padding lanes
  const int kk = g << 3;

  half8 wh[4];
#pragma unroll
  for (int mt = 0; mt < 4; mt++)
    wh[mt] = *(const half8*)(W_h + (size_t)(v0 + mt * 16 + c) * 32 + kk);

#pragma unroll
  for (int i = 0; i < 16; i++) {
    const int bl = wave * 16 + i;
    half8 ah = *(const half8*)(Ar_h + (size_t)(b0 + bl) * 512 + c * 32 + kk);
    const float trg = transl_s[bl][g < 3 ? g : 0];
#pragma unroll
    for (int mt = 0; mt < 4; mt++) {
      f32x4 t = {0.f, 0.f, 0.f, 0.f};
      t = __builtin_amdgcn_mfma_f32_16x16x32_f16(ah, wh[mt], t, 0, 0, 0);
      const int vl2 = mt * 16 + c;
      const int v = v0 + vl2;
      if (g < 3 && v < Vn) {
        float x = vp[bl][3 * vl2 + 0];
        float y = vp[bl][3 * vl2 + 1];
        float z = vp[bl][3 * vl2 + 2];
        out[((size_t)(b0 + bl) * Vn + v) * 3 + g] = t[0]*x + t[1]*y + t[2]*z + t[3] + trg;
      }
    }
  }
}

// ================= FALLBACK PATH (proven round-4 kernels) =================

__global__ __launch_bounds__(256) void k_jsjt_part(
    const float* __restrict__ Jreg, const float* __restrict__ vtpl,
    const float* __restrict__ sdirs, float* __restrict__ part)
{
  const int bid = blockIdx.x;
  const int chunk = blockIdx.y;
  const int j = bid / 3, c = bid % 3;
  const int tid = threadIdx.x;
  const int vlo = chunk * 862;
  const int vhi = min(Vn, vlo + 862);
  float acc[11];
#pragma unroll
  for (int k = 0; k < 11; k++) acc[k] = 0.f;
  for (int v = vlo + tid; v < vhi; v += 256) {
    float w = Jreg[(size_t)j * Vn + v];
    int n = v * 3 + c;
#pragma unroll
    for (int l = 0; l < 10; l++) acc[l] += w * sdirs[(size_t)n * 10 + l];
    acc[10] += w * vtpl[n];
  }
  __shared__ float red[256];
  for (int k = 0; k < 11; k++) {
    red[tid] = acc[k];
    __syncthreads();
    for (int s = 128; s > 0; s >>= 1) {
      if (tid < s) red[tid] += red[tid + s];
      __syncthreads();
    }
    if (tid == 0) part[(size_t)chunk * 792 + bid * 11 + k] = red[0];
    __syncthreads();
  }
}

__global__ __launch_bounds__(1024) void k_jsjt_red(
    const float* __restrict__ part, float* __restrict__ JS, float* __restrict__ Jt)
{
  const int t = threadIdx.x;
  if (t >= 792) return;
  float s = 0.f;
#pragma unroll
  for (int y = 0; y < 8; y++) s += part[(size_t)y * 792 + t];
  int bid = t / 11, k = t % 11;
  if (k < 10) JS[bid * 10 + k] = s;
  else        Jt[bid] = s;
}

__global__ __launch_bounds__(64) void k_pose_fb(
    const float* __restrict__ betas, const float* __restrict__ body_pose,
    const float* __restrict__ gorient, const float* __restrict__ transl,
    const float* __restrict__ JS, const float* __restrict__ Jt,
    float* __restrict__ pf_ws, float* __restrict__ Ar_ws,
    float* __restrict__ out_joints)
{
  const int b = blockIdx.x;
  const int tid = threadIdx.x;
  __shared__ float Rs[24][9];
  __shared__ float jnt[24][3];
  __shared__ float rel[24][3];
  __shared__ float A_s[24][12];

  if (tid < 24) {
    float x, y, z;
    if (tid == 0) { x = gorient[b*3+0]; y = gorient[b*3+1]; z = gorient[b*3+2]; }
    else { int o = b*69 + (tid-1)*3; x = body_pose[o]; y = body_pose[o+1]; z = body_pose[o+2]; }
    float ang = sqrtf(x*x + y*y + z*z) + 1e-8f;
    float inv = 1.0f / ang;
    float ux = x*inv, uy = y*inv, uz = z*inv;
    float s = sinf(ang), cc = cosf(ang), omc = 1.0f - cc;
    float K[9] = {0.f, -uz, uy,  uz, 0.f, -ux,  -uy, ux, 0.f};
#pragma unroll
    for (int mm = 0; mm < 3; mm++)
#pragma unroll
      for (int nn = 0; nn < 3; nn++) {
        float kk = K[mm*3+0]*K[0+nn] + K[mm*3+1]*K[3+nn] + K[mm*3+2]*K[6+nn];
        float eye = (mm == nn) ? 1.0f : 0.0f;
        Rs[tid][mm*3+nn] = eye + s*K[mm*3+nn] + omc*kk;
      }
  }
  for (int idx = tid; idx < 72; idx += 64) {
    float a = Jt[idx];
#pragma unroll
    for (int l = 0; l < 10; l++) a += betas[b*10 + l] * JS[idx*10 + l];
    jnt[idx/3][idx%3] = a;
  }
  __syncthreads();
  for (int idx = tid; idx < Pn; idx += 64) {
    int j = 1 + idx / 9, e = idx % 9;
    float eye = (e == 0 || e == 4 || e == 8) ? 1.0f : 0.0f;
    pf_ws[(size_t)b * Pn + idx] = Rs[j][e] - eye;
  }
  for (int idx = tid; idx < 72; idx += 64) {
    int j = idx/3, cc = idx%3;
    float r = jnt[j][cc];
    if (j > 0) r -= jnt[c_par[j]][cc];
    rel[j][cc] = r;
  }
  __syncthreads();
  if (tid < 12) {
    int m = tid/4, nn = tid%4;
    A_s[0][tid] = (nn < 3) ? Rs[0][m*3+nn] : rel[0][m];
  }
  __syncthreads();
  for (int i = 1; i < 24; i++) {
    if (tid < 12) {
      int m = tid/4, nn = tid%4;
      int p = c_par[i];
      float v;
      if (nn < 3)
        v = A_s[p][m*4+0]*Rs[i][0+nn] + A_s[p][m*4+1]*Rs[i][3+nn] + A_s[p][m*4+2]*Rs[i][6+nn];
      else
        v = A_s[p][m*4+0]*rel[i][0] + A_s[p][m*4+1]*rel[i][1] + A_s[p][m*4+2]*rel[i][2] + A_s[p][m*4+3];
      A_s[i][tid] = v;
    }
    __syncthreads();
  }
  for (int idx = tid; idx < 72; idx += 64) {
    int j = idx/3, cc = idx%3;
    out_joints[(size_t)b * 72 + idx] = A_s[j][cc*4+3] + transl[b*3+cc];
  }
  for (int idx = tid; idx < 288; idx += 64) {
    int j = idx/12, r = idx%12, m = r/4, nn = r%4;
    float v;
    if (nn < 3) v = A_s[j][m*4+nn];
    else v = A_s[j][m*4+3] - (A_s[j][m*4+0]*jnt[j][0] + A_s[j][m*4+1]*jnt[j][1] + A_s[j][m*4+2]*jnt[j][2]);
    Ar_ws[(size_t)b * 288 + idx] = v;
  }
}

__global__ __launch_bounds__(192) void k_verts_fb(
    const float* __restrict__ betas, const float* __restrict__ transl,
    const float* __restrict__ vtpl, const float* __restrict__ sdirs,
    const float* __restrict__ pdirs, const float* __restrict__ W,
    const float* __restrict__ pf_ws, const float* __restrict__ Ar_ws,
    float* __restrict__ out)
{
  const int tid = threadIdx.x;
  const int b0 = blockIdx.x * 16;
  const int v0 = blockIdx.y * 128;
  const int n0 = v0 * 3;
  __shared__ __align__(16) float pf_s[Pn][16];
  __shared__ __align__(16) float Ar_s[16][288];
  __shared__ __align__(16) float vp_s[16][384];
  __shared__ float betas_s[16][NBn];
  __shared__ float transl_s[16][3];
  for (int idx = tid; idx < Pn * 16; idx += 192) {
    int p = idx >> 4, bi = idx & 15;
    pf_s[p][bi] = pf_ws[(size_t)(b0 + bi) * Pn + p];
  }
  for (int idx = tid; idx < 16 * 288; idx += 192)
    Ar_s[idx / 288][idx % 288] = Ar_ws[(size_t)b0 * 288 + idx];
  for (int idx = tid; idx < 16 * NBn; idx += 192)
    betas_s[idx / NBn][idx % NBn] = betas[(size_t)b0 * NBn + idx];
  for (int idx = tid; idx < 48; idx += 192)
    transl_s[idx / 3][idx % 3] = transl[(size_t)b0 * 3 + idx];
  __syncthreads();
  const int n = n0 + 2 * tid;
  const bool valid = (n < N3n);
  float acc0[16], acc1[16];
#pragma unroll
  for (int i = 0; i < 16; i++) { acc0[i] = 0.f; acc1[i] = 0.f; }
  for (int p = 0; p < Pn; p++) {
    float pd0 = 0.f, pd1 = 0.f;
    if (valid) { float2 t = *(const float2*)(pdirs + (size_t)p * N3n + n); pd0 = t.x; pd1 = t.y; }
    const float4* row = (const float4*)(pf_s[p]);
#pragma unroll
    for (int q = 0; q < 4; q++) {
      float4 f = row[q];
      acc0[4*q+0] += f.x * pd0;  acc1[4*q+0] += f.x * pd1;
      acc0[4*q+1] += f.y * pd0;  acc1[4*q+1] += f.y * pd1;
      acc0[4*q+2] += f.z * pd0;  acc1[4*q+2] += f.z * pd1;
      acc0[4*q+3] += f.w * pd0;  acc1[4*q+3] += f.w * pd1;
    }
  }
  float sd0[10], sd1[10], vt0 = 0.f, vt1 = 0.f;
#pragma unroll
  for (int l = 0; l < 10; l++) { sd0[l] = 0.f; sd1[l] = 0.f; }
  if (valid) {
    for (int l = 0; l < 10; l++) { sd0[l] = sdirs[(size_t)n*10 + l]; sd1[l] = sdirs[(size_t)n*10 + 10 + l]; }
    vt0 = vtpl[n]; vt1 = vtpl[n+1];
  }
#pragma unroll
  for (int bi = 0; bi < 16; bi++) {
    float s0 = vt0, s1 = vt1;
#pragma unroll
    for (int l = 0; l < 10; l++) { float bb = betas_s[bi][l]; s0 += bb*sd0[l]; s1 += bb*sd1[l]; }
    acc0[bi] += s0; acc1[bi] += s1;
  }
#pragma unroll
  for (int bi = 0; bi < 16; bi++) { vp_s[bi][2*tid] = acc0[bi]; vp_s[bi][2*tid+1] = acc1[bi]; }
  __syncthreads();
  const int m = tid / 64;
  const int vl = tid % 64;
  const int va = v0 + vl, vb = v0 + vl + 64;
  const bool va_ok = (va < Vn), vb_ok = (vb < Vn);
  float Wr0[24], Wr1[24];
#pragma unroll
  for (int j = 0; j < 24; j++) { Wr0[j] = 0.f; Wr1[j] = 0.f; }
  if (va_ok) { const float4* wp = (const float4*)(W + (size_t)va*24);
#pragma unroll
    for (int q = 0; q < 6; q++) { float4 f = wp[q]; Wr0[4*q]=f.x; Wr0[4*q+1]=f.y; Wr0[4*q+2]=f.z; Wr0[4*q+3]=f.w; } }
  if (vb_ok) { const float4* wp = (const float4*)(W + (size_t)vb*24);
#pragma unroll
    for (int q = 0; q < 6; q++) { float4 f = wp[q]; Wr1[4*q]=f.x; Wr1[4*q+1]=f.y; Wr1[4*q+2]=f.z; Wr1[4*q+3]=f.w; } }
  for (int bi = 0; bi < 16; bi++) {
    float Ta0=0.f,Ta1=0.f,Ta2=0.f,Ta3=0.f, Tb0=0.f,Tb1=0.f,Tb2=0.f,Tb3=0.f;
    const float4* arb = (const float4*)(Ar_s[bi]);
#pragma unroll
    for (int j = 0; j < 24; j++) {
      float4 a = arb[j*3 + m];
      float wa = Wr0[j], wb = Wr1[j];
      Ta0 += wa*a.x; Ta1 += wa*a.y; Ta2 += wa*a.z; Ta3 += wa*a.w;
      Tb0 += wb*a.x; Tb1 += wb*a.y; Tb2 += wb*a.z; Tb3 += wb*a.w;
    }
    float tr = transl_s[bi][m];
    if (va_ok) {
      float x = vp_s[bi][vl*3+0], y = vp_s[bi][vl*3+1], z = vp_s[bi][vl*3+2];
      out[((size_t)(b0+bi)*Vn + va)*3 + m] = Ta0*x + Ta1*y + Ta2*z + Ta3 + tr;
    }
    if (vb_ok) {
      float x = vp_s[bi][(vl+64)*3+0], y = vp_s[bi][(vl+64)*3+1], z = vp_s[bi][(vl+64)*3+2];
      out[((size_t)(b0+bi)*Vn + vb)*3 + m] = Tb0*x + Tb1*y + Tb2*z + Tb3 + tr;
    }
  }
}

extern "C" void kernel_launch(void* const* d_in, const int* in_sizes, int n_in,
                              void* d_out, int out_size, void* d_ws, size_t ws_size,
                              hipStream_t stream)
{
  const float *betas=nullptr, *bpose=nullptr, *gorient=nullptr, *transl=nullptr,
              *vtpl=nullptr, *sdirs=nullptr, *pdirs=nullptr, *Jreg=nullptr, *W=nullptr;
  int seen1536 = 0, seen165360 = 0;
  for (int i = 0; i < n_in; i++) {
    const float* p = (const float*)d_in[i];
    switch (in_sizes[i]) {
      case 5120:    betas = p; break;
      case 35328:   bpose = p; break;
      case 20670:   vtpl  = p; break;
      case 206700:  sdirs = p; break;
      case 4278690: pdirs = p; break;
      case 1536:    if (seen1536++ == 0) gorient = p; else transl = p; break;
      case 165360:  if (seen165360++ == 0) Jreg = p; else W = p; break;
      default: break;
    }
  }
  float* out = (float*)d_out;

  float* ws   = (float*)d_ws;
  float* part = ws;                                   // 6336 f
  float* JS   = ws + 6336;                            // 720 f   (fallback)
  float* Jt   = ws + 7056;                            // 72 f    (fallback)
  float* pf   = ws + 7128;                            // 105984 f (fallback)
  float* Ar   = ws + 113112;                          // 147456 f (fallback)
  _Float16* pf_h = (_Float16*)(ws + 260568);          // 114688 h
  _Float16* B_h  = (_Float16*)(ws + 317912);          // 4644864 h
  _Float16* W_h  = (_Float16*)(ws + 2640344);         // 221184 h
  _Float16* Ar_h = (_Float16*)(ws + 2861528);         // 262144 h
  const size_t WS_NEED = (size_t)3123672 * 4;         // 12,494,688 bytes (conservative)
  const bool big = (ws_size >= WS_NEED);

  if (big) {
    k_prep<<<3708, 256, 0, stream>>>(Jreg, vtpl, sdirs, pdirs, W, part, B_h, W_h);
    k_pose2<<<64, 512, 0, stream>>>(betas, bpose, gorient, transl, part,
                                    pf_h, Ar_h, out + (size_t)Bn * Vn * 3);
    k_mm3<<<896, 256, 0, stream>>>(transl, pf_h, B_h, W_h, Ar_h, out);
  } else {
    k_jsjt_part<<<dim3(72, 8), 256, 0, stream>>>(Jreg, vtpl, sdirs, part);
    k_jsjt_red<<<1, 1024, 0, stream>>>(part, JS, Jt);
    k_pose_fb<<<Bn, 64, 0, stream>>>(betas, bpose, gorient, transl, JS, Jt, pf, Ar,
                                     out + (size_t)Bn * Vn * 3);
    k_verts_fb<<<dim3(32, 54), 192, 0, stream>>>(betas, transl, vtpl, sdirs,
                                                 pdirs, W, pf, Ar, out);
  }
}

// Round 11
// 58.644 us; speedup vs baseline: 5.6635x; 1.0212x over previous
//
#include <hip/hip_runtime.h>
#include <hip/hip_bf16.h>
#include <math.h>

#define Bn 512
#define Vn 6890
#define NBn 10
#define Pn 207
#define N3n 20670   // Vn*3
#define KP 224      // padded K: 0-206 pf, 207-216 betas, 217 vtpl_hi, 218 vtpl_lo
#define VPAD 6912   // padded vertex rows for W (108*64)

typedef __attribute__((ext_vector_type(8))) _Float16 half8;
typedef __attribute__((ext_vector_type(4))) float f32x4;

__constant__ int c_par[24] = {-1,0,0,0,1,2,3,4,5,6,7,8,9,9,9,12,13,14,16,17,18,19,20,21};
__constant__ int c_lvl[10] = {0,1,4,7,10,15,18,20,22,24};   // chain depth-level ranges

// ================= BIG PATH (fp16 MFMA) =================

// ---------------- k_prep: jsjt partials (0..191) U B fp16 (192..2459) U W fp16 (2460..3323) ----------------
__global__ __launch_bounds__(256) void k_prep(
    const float* __restrict__ Jreg, const float* __restrict__ vtpl,
    const float* __restrict__ sdirs, const float* __restrict__ pdirs,
    const float* __restrict__ W, float* __restrict__ part,
    _Float16* __restrict__ B_h, _Float16* __restrict__ W_h)
{
  const int tid = threadIdx.x;
  if (blockIdx.x < 192) {
    // per-joint partials: w loaded once for 3 components, sdirs contiguous
    const int j = blockIdx.x % 24;
    const int chunk = blockIdx.x / 24;        // 0..7
    const int lane = tid & 63, wv = tid >> 6;
    const int vlo = chunk * 862;
    const int vhi = min(Vn, vlo + 862);
    __shared__ float wred[4][33];
    float acc[33];
#pragma unroll
    for (int k = 0; k < 33; k++) acc[k] = 0.f;
    for (int v = vlo + tid; v < vhi; v += 256) {
      float w = Jreg[(size_t)j * Vn + v];
      const float* sp = sdirs + (size_t)v * 30;
#pragma unroll
      for (int c = 0; c < 3; c++) {
#pragma unroll
        for (int l = 0; l < 10; l++) acc[c*11 + l] += w * sp[c*10 + l];
        acc[c*11 + 10] += w * vtpl[v*3 + c];
      }
    }
#pragma unroll
    for (int k = 0; k < 33; k++) {
      float s = acc[k];
      for (int off = 32; off > 0; off >>= 1) s += __shfl_xor(s, off);
      if (lane == 0) wred[wv][k] = s;
    }
    __syncthreads();
    if (tid < 33) {
      float s = wred[0][tid] + wred[1][tid] + wred[2][tid] + wred[3][tid];
      int c = tid / 11, k = tid % 11;
      part[(size_t)chunk * 792 + (j*3 + c) * 11 + k] = s;
    }
  } else if (blockIdx.x < 192 + 2268) {
    // B_h[((nt*7+s)*64 + l)*8 + j] = f16(B[k][n]), k = s*32+(l>>4)*8+j, n = nt*16+(l&15)
    const int pair = (blockIdx.x - 192) * 4 + (tid >> 6);   // nt*7+s
    const int l = tid & 63;
    const int nt = pair / 7, s = pair % 7;
    const int col = nt * 16 + (l & 15);
    const int kb = s * 32 + ((l >> 4) << 3);
    half8 hv;
#pragma unroll
    for (int j = 0; j < 8; j++) {
      int k = kb + j;
      float f = 0.f;
      if (col < N3n) {
        if (k < Pn) f = pdirs[(size_t)k * N3n + col];
        else if (k < 217) f = sdirs[(size_t)col * 10 + (k - 207)];
        else if (k == 217) f = (float)(_Float16)vtpl[col];
        else if (k == 218) {
          float t = vtpl[col];
          f = t - (float)(_Float16)t;
        }
      }
      hv[j] = (_Float16)f;
    }
    *(half8*)(B_h + (size_t)pair * 512 + l * 8) = hv;
  } else {
    int idx = (blockIdx.x - 192 - 2268) * 256 + tid;
    if (idx < VPAD * 32) {
      int v = idx >> 5, k = idx & 31;
      float f;
      if (v < Vn && k < 24) f = W[(size_t)v * 24 + k];
      else if (k == 24)     f = 1.0f;     // affine slot: pairs with Ar[.,24] = transl
      else                  f = 0.f;
      W_h[idx] = (_Float16)f;
    }
  }
}

// ---------------- k_pose2: 8 batches/block (1 wave each), shared jsjt reduce ----------------
__global__ __launch_bounds__(512) void k_pose2(
    const float* __restrict__ betas, const float* __restrict__ body_pose,
    const float* __restrict__ gorient, const float* __restrict__ transl,
    const float* __restrict__ part,
    _Float16* __restrict__ pf_h, _Float16* __restrict__ Ar_h,
    float* __restrict__ out_joints)
{
  const int tid = threadIdx.x;
  const int wave = tid >> 6;
  const int lane = tid & 63;
  const int b = blockIdx.x * 8 + wave;

  __shared__ float JS_s[720];
  __shared__ float Jt_s[72];
  __shared__ float Rs[8][24][9];
  __shared__ float jnt[8][24][3];
  __shared__ float rel[8][24][3];
  __shared__ float A_s[8][24][12];

  // jsjt reduce (once per block)
  for (int idx = tid; idx < 792; idx += 512) {
    float s = 0.f;
#pragma unroll
    for (int y = 0; y < 8; y++) s += part[(size_t)y * 792 + idx];
    int bid = idx / 11, k = idx % 11;
    if (k < 10) JS_s[bid * 10 + k] = s;
    else        Jt_s[bid] = s;
  }

  if (lane < 24) {
    float x, y, z;
    if (lane == 0) { x = gorient[b*3+0]; y = gorient[b*3+1]; z = gorient[b*3+2]; }
    else { int o = b*69 + (lane-1)*3; x = body_pose[o]; y = body_pose[o+1]; z = body_pose[o+2]; }
    float ang = sqrtf(x*x + y*y + z*z) + 1e-8f;
    float inv = 1.0f / ang;
    float ux = x*inv, uy = y*inv, uz = z*inv;
    float s = sinf(ang), cc = cosf(ang), omc = 1.0f - cc;
    float K[9] = {0.f, -uz, uy,  uz, 0.f, -ux,  -uy, ux, 0.f};
#pragma unroll
    for (int mm = 0; mm < 3; mm++)
#pragma unroll
      for (int nn = 0; nn < 3; nn++) {
        float kk = K[mm*3+0]*K[0+nn] + K[mm*3+1]*K[3+nn] + K[mm*3+2]*K[6+nn];
        float eye = (mm == nn) ? 1.0f : 0.0f;
        Rs[wave][lane][mm*3+nn] = eye + s*K[mm*3+nn] + omc*kk;
      }
  }
  __syncthreads();   // JS_s + Rs visible

  // unposed joints from betas
  for (int idx = lane; idx < 72; idx += 64) {
    float a = Jt_s[idx];
#pragma unroll
    for (int l = 0; l < 10; l++) a += betas[b*10 + l] * JS_s[idx*10 + l];
    jnt[wave][idx/3][idx%3] = a;
  }
  // pf_h: extended K rows (pose feature | betas | 1 | 1)
  for (int idx = lane; idx < KP; idx += 64) {
    float f = 0.f;
    if (idx < Pn) {
      int j = 1 + idx / 9, e = idx % 9;
      float eye = (e == 0 || e == 4 || e == 8) ? 1.0f : 0.0f;
      f = Rs[wave][j][e] - eye;
    } else if (idx < 217) {
      f = betas[b*10 + (idx - 207)];
    } else if (idx < 219) {
      f = 1.0f;
    }
    pf_h[(size_t)b * KP + idx] = (_Float16)f;
  }
  __syncthreads();
  for (int idx = lane; idx < 72; idx += 64) {
    int j = idx/3, cc = idx%3;
    float r = jnt[wave][j][cc];
    if (j > 0) r -= jnt[wave][c_par[j]][cc];
    rel[wave][j][cc] = r;
  }
  __syncthreads();
  if (lane < 12) {
    int m = lane/4, nn = lane%4;
    A_s[wave][0][lane] = (nn < 3) ? Rs[wave][0][m*3+nn] : rel[wave][0][m];
  }
  __syncthreads();
  // kinematic chain, level-parallel
  for (int lev = 1; lev <= 8; lev++) {
    const int s0 = c_lvl[lev], s1 = c_lvl[lev + 1];
    const int jj = lane / 12, r = lane % 12;
    if (jj < s1 - s0) {
      const int i = s0 + jj;
      const int p = c_par[i];
      const int m = r >> 2, nn = r & 3;
      float v;
      if (nn < 3)
        v = A_s[wave][p][m*4+0]*Rs[wave][i][0+nn] + A_s[wave][p][m*4+1]*Rs[wave][i][3+nn] + A_s[wave][p][m*4+2]*Rs[wave][i][6+nn];
      else
        v = A_s[wave][p][m*4+0]*rel[wave][i][0] + A_s[wave][p][m*4+1]*rel[wave][i][1] + A_s[wave][p][m*4+2]*rel[wave][i][2] + A_s[wave][p][m*4+3];
      A_s[wave][i][r] = v;
    }
    __syncthreads();
  }
  for (int idx = lane; idx < 72; idx += 64) {
    int j = idx/3, cc = idx%3;
    out_joints[(size_t)b * 72 + idx] = A_s[wave][j][cc*4+3] + transl[b*3+cc];
  }
  // A_rel MFMA fragments [e=16][k=32], fp16; k=24 column carries transl (affine absorb)
  for (int idx = lane; idx < 512; idx += 64) {
    int e = idx >> 5, k = idx & 31;
    float a = 0.f;
    if (e < 12 && k < 24) {
      int m = e >> 2, nn = e & 3;
      if (nn < 3) a = A_s[wave][k][m*4+nn];
      else a = A_s[wave][k][m*4+3] - (A_s[wave][k][m*4+0]*jnt[wave][k][0] + A_s[wave][k][m*4+1]*jnt[wave][k][1] + A_s[wave][k][m*4+2]*jnt[wave][k][2]);
    } else if (k == 24 && e < 12 && (e & 3) == 3) {
      a = transl[b*3 + (e >> 2)];
    }
    Ar_h[(size_t)b * 512 + idx] = (_Float16)a;
  }
}

// ---------------- k_mm4: 32 batches x 64 vertices per block, fp16 MFMA, f16 vp ----------------
// grid 1792: r8 = lin&7 (XCD slot), k2 = lin>>3; b_t = k2&15, m8 = k2>>4; v_t = r8*14+m8.
__global__ __launch_bounds__(256) void k_mm4(
    const _Float16* __restrict__ pf_h, const _Float16* __restrict__ B_h,
    const _Float16* __restrict__ W_h, const _Float16* __restrict__ Ar_h,
    float* __restrict__ out)
{
  const int lin = blockIdx.x;
  const int r8 = lin & 7;
  const int k2 = lin >> 3;        // 0..223
  const int b_t = k2 & 15;
  const int m8 = k2 >> 4;         // 0..13
  const int v_t = r8 * 14 + m8;   // 0..111
  if (v_t >= 108) return;

  const int tid = threadIdx.x;
  const int l = tid & 63;
  const int wave = tid >> 6;
  const int b0 = b_t * 32;
  const int v0 = v_t * 64;

  __shared__ __align__(16) _Float16 vp[32][196];

  // ---- phase 1: v_posed GEMM; 2 A-row-tiles share B fragments
  const int c0 = l & 15;
  const int kk0 = (l >> 4) << 3;
  const int ntb = v_t * 12 + wave * 3;
  f32x4 acc[2][3];
#pragma unroll
  for (int t = 0; t < 2; t++)
#pragma unroll
    for (int n = 0; n < 3; n++) acc[t][n] = (f32x4){0.f, 0.f, 0.f, 0.f};

#pragma unroll
  for (int s = 0; s < 7; s++) {
    half8 bv[3];
#pragma unroll
    for (int n = 0; n < 3; n++)
      bv[n] = *(const half8*)(B_h + ((size_t)(ntb + n) * 7 + s) * 512 + l * 8);
#pragma unroll
    for (int t = 0; t < 2; t++) {
      half8 fa = *(const half8*)(pf_h + (size_t)(b0 + t * 16 + c0) * KP + kk0 + s * 32);
#pragma unroll
      for (int n = 0; n < 3; n++)
        acc[t][n] = __builtin_amdgcn_mfma_f32_16x16x32_f16(fa, bv[n], acc[t][n], 0, 0, 0);
    }
  }
  {
    const int colb = wave * 48 + c0;
    const int rowb = (l >> 4) * 4;
#pragma unroll
    for (int t = 0; t < 2; t++)
#pragma unroll
      for (int n = 0; n < 3; n++)
#pragma unroll
        for (int r = 0; r < 4; r++)
          vp[t * 16 + rowb + r][colb + n * 16] = (_Float16)acc[t][n][r];
  }
  __syncthreads();

  // ---- phase 2 + epilogue: each wave owns 8 batches; transl absorbed in k=24 column
  const int c = l & 15;         // vertex-within-16 / e-row in A frag
  const int g = l >> 4;         // output component (0..2); 3 = padding lanes
  const int kk = g << 3;

  half8 wh[4];
#pragma unroll
  for (int mt = 0; mt < 4; mt++)
    wh[mt] = *(const half8*)(W_h + (size_t)(v0 + mt * 16 + c) * 32 + kk);

#pragma unroll
  for (int i = 0; i < 8; i++) {
    const int bl = wave * 8 + i;
    half8 ah = *(const half8*)(Ar_h + (size_t)(b0 + bl) * 512 + c * 32 + kk);
#pragma unroll
    for (int mt = 0; mt < 4; mt++) {
      f32x4 t = {0.f, 0.f, 0.f, 0.f};
      t = __builtin_amdgcn_mfma_f32_16x16x32_f16(ah, wh[mt], t, 0, 0, 0);
      const int vl2 = mt * 16 + c;
      const int v = v0 + vl2;
      if (g < 3 && v < Vn) {
        float x = (float)vp[bl][3 * vl2 + 0];
        float y = (float)vp[bl][3 * vl2 + 1];
        float z = (float)vp[bl][3 * vl2 + 2];
        out[((size_t)(b0 + bl) * Vn + v) * 3 + g] = t[0]*x + t[1]*y + t[2]*z + t[3];
      }
    }
  }
}

// ================= FALLBACK PATH (proven round-4 kernels) =================

__global__ __launch_bounds__(256) void k_jsjt_part(
    const float* __restrict__ Jreg, const float* __restrict__ vtpl,
    const float* __restrict__ sdirs, float* __restrict__ part)
{
  const int bid = blockIdx.x;
  const int chunk = blockIdx.y;
  const int j = bid / 3, c = bid % 3;
  const int tid = threadIdx.x;
  const int vlo = chunk * 862;
  const int vhi = min(Vn, vlo + 862);
  float acc[11];
#pragma unroll
  for (int k = 0; k < 11; k++) acc[k] = 0.f;
  for (int v = vlo + tid; v < vhi; v += 256) {
    float w = Jreg[(size_t)j * Vn + v];
    int n = v * 3 + c;
#pragma unroll
    for (int l = 0; l < 10; l++) acc[l] += w * sdirs[(size_t)n * 10 + l];
    acc[10] += w * vtpl[n];
  }
  __shared__ float red[256];
  for (int k = 0; k < 11; k++) {
    red[tid] = acc[k];
    __syncthreads();
    for (int s = 128; s > 0; s >>= 1) {
      if (tid < s) red[tid] += red[tid + s];
      __syncthreads();
    }
    if (tid == 0) part[(size_t)chunk * 792 + bid * 11 + k] = red[0];
    __syncthreads();
  }
}

__global__ __launch_bounds__(1024) void k_jsjt_red(
    const float* __restrict__ part, float* __restrict__ JS, float* __restrict__ Jt)
{
  const int t = threadIdx.x;
  if (t >= 792) return;
  float s = 0.f;
#pragma unroll
  for (int y = 0; y < 8; y++) s += part[(size_t)y * 792 + t];
  int bid = t / 11, k = t % 11;
  if (k < 10) JS[bid * 10 + k] = s;
  else        Jt[bid] = s;
}

__global__ __launch_bounds__(64) void k_pose_fb(
    const float* __restrict__ betas, const float* __restrict__ body_pose,
    const float* __restrict__ gorient, const float* __restrict__ transl,
    const float* __restrict__ JS, const float* __restrict__ Jt,
    float* __restrict__ pf_ws, float* __restrict__ Ar_ws,
    float* __restrict__ out_joints)
{
  const int b = blockIdx.x;
  const int tid = threadIdx.x;
  __shared__ float Rs[24][9];
  __shared__ float jnt[24][3];
  __shared__ float rel[24][3];
  __shared__ float A_s[24][12];

  if (tid < 24) {
    float x, y, z;
    if (tid == 0) { x = gorient[b*3+0]; y = gorient[b*3+1]; z = gorient[b*3+2]; }
    else { int o = b*69 + (tid-1)*3; x = body_pose[o]; y = body_pose[o+1]; z = body_pose[o+2]; }
    float ang = sqrtf(x*x + y*y + z*z) + 1e-8f;
    float inv = 1.0f / ang;
    float ux = x*inv, uy = y*inv, uz = z*inv;
    float s = sinf(ang), cc = cosf(ang), omc = 1.0f - cc;
    float K[9] = {0.f, -uz, uy,  uz, 0.f, -ux,  -uy, ux, 0.f};
#pragma unroll
    for (int mm = 0; mm < 3; mm++)
#pragma unroll
      for (int nn = 0; nn < 3; nn++) {
        float kk = K[mm*3+0]*K[0+nn] + K[mm*3+1]*K[3+nn] + K[mm*3+2]*K[6+nn];
        float eye = (mm == nn) ? 1.0f : 0.0f;
        Rs[tid][mm*3+nn] = eye + s*K[mm*3+nn] + omc*kk;
      }
  }
  for (int idx = tid; idx < 72; idx += 64) {
    float a = Jt[idx];
#pragma unroll
    for (int l = 0; l < 10; l++) a += betas[b*10 + l] * JS[idx*10 + l];
    jnt[idx/3][idx%3] = a;
  }
  __syncthreads();
  for (int idx = tid; idx < Pn; idx += 64) {
    int j = 1 + idx / 9, e = idx % 9;
    float eye = (e == 0 || e == 4 || e == 8) ? 1.0f : 0.0f;
    pf_ws[(size_t)b * Pn + idx] = Rs[j][e] - eye;
  }
  for (int idx = tid; idx < 72; idx += 64) {
    int j = idx/3, cc = idx%3;
    float r = jnt[j][cc];
    if (j > 0) r -= jnt[c_par[j]][cc];
    rel[j][cc] = r;
  }
  __syncthreads();
  if (tid < 12) {
    int m = tid/4, nn = tid%4;
    A_s[0][tid] = (nn < 3) ? Rs[0][m*3+nn] : rel[0][m];
  }
  __syncthreads();
  for (int i = 1; i < 24; i++) {
    if (tid < 12) {
      int m = tid/4, nn = tid%4;
      int p = c_par[i];
      float v;
      if (nn < 3)
        v = A_s[p][m*4+0]*Rs[i][0+nn] + A_s[p][m*4+1]*Rs[i][3+nn] + A_s[p][m*4+2]*Rs[i][6+nn];
      else
        v = A_s[p][m*4+0]*rel[i][0] + A_s[p][m*4+1]*rel[i][1] + A_s[p][m*4+2]*rel[i][2] + A_s[p][m*4+3];
      A_s[i][tid] = v;
    }
    __syncthreads();
  }
  for (int idx = tid; idx < 72; idx += 64) {
    int j = idx/3, cc = idx%3;
    out_joints[(size_t)b * 72 + idx] = A_s[j][cc*4+3] + transl[b*3+cc];
  }
  for (int idx = tid; idx < 288; idx += 64) {
    int j = idx/12, r = idx%12, m = r/4, nn = r%4;
    float v;
    if (nn < 3) v = A_s[j][m*4+nn];
    else v = A_s[j][m*4+3] - (A_s[j][m*4+0]*jnt[j][0] + A_s[j][m*4+1]*jnt[j][1] + A_s[j][m*4+2]*jnt[j][2]);
    Ar_ws[(size_t)b * 288 + idx] = v;
  }
}

__global__ __launch_bounds__(192) void k_verts_fb(
    const float* __restrict__ betas, const float* __restrict__ transl,
    const float* __restrict__ vtpl, const float* __restrict__ sdirs,
    const float* __restrict__ pdirs, const float* __restrict__ W,
    const float* __restrict__ pf_ws, const float* __restrict__ Ar_ws,
    float* __restrict__ out)
{
  const int tid = threadIdx.x;
  const int b0 = blockIdx.x * 16;
  const int v0 = blockIdx.y * 128;
  const int n0 = v0 * 3;
  __shared__ __align__(16) float pf_s[Pn][16];
  __shared__ __align__(16) float Ar_s[16][288];
  __shared__ __align__(16) float vp_s[16][384];
  __shared__ float betas_s[16][NBn];
  __shared__ float transl_s[16][3];
  for (int idx = tid; idx < Pn * 16; idx += 192) {
    int p = idx >> 4, bi = idx & 15;
    pf_s[p][bi] = pf_ws[(size_t)(b0 + bi) * Pn + p];
  }
  for (int idx = tid; idx < 16 * 288; idx += 192)
    Ar_s[idx / 288][idx % 288] = Ar_ws[(size_t)b0 * 288 + idx];
  for (int idx = tid; idx < 16 * NBn; idx += 192)
    betas_s[idx / NBn][idx % NBn] = betas[(size_t)b0 * NBn + idx];
  for (int idx = tid; idx < 48; idx += 192)
    transl_s[idx / 3][idx % 3] = transl[(size_t)b0 * 3 + idx];
  __syncthreads();
  const int n = n0 + 2 * tid;
  const bool valid = (n < N3n);
  float acc0[16], acc1[16];
#pragma unroll
  for (int i = 0; i < 16; i++) { acc0[i] = 0.f; acc1[i] = 0.f; }
  for (int p = 0; p < Pn; p++) {
    float pd0 = 0.f, pd1 = 0.f;
    if (valid) { float2 t = *(const float2*)(pdirs + (size_t)p * N3n + n); pd0 = t.x; pd1 = t.y; }
    const float4* row = (const float4*)(pf_s[p]);
#pragma unroll
    for (int q = 0; q < 4; q++) {
      float4 f = row[q];
      acc0[4*q+0] += f.x * pd0;  acc1[4*q+0] += f.x * pd1;
      acc0[4*q+1] += f.y * pd0;  acc1[4*q+1] += f.y * pd1;
      acc0[4*q+2] += f.z * pd0;  acc1[4*q+2] += f.z * pd1;
      acc0[4*q+3] += f.w * pd0;  acc1[4*q+3] += f.w * pd1;
    }
  }
  float sd0[10], sd1[10], vt0 = 0.f, vt1 = 0.f;
#pragma unroll
  for (int l = 0; l < 10; l++) { sd0[l] = 0.f; sd1[l] = 0.f; }
  if (valid) {
    for (int l = 0; l < 10; l++) { sd0[l] = sdirs[(size_t)n*10 + l]; sd1[l] = sdirs[(size_t)n*10 + 10 + l]; }
    vt0 = vtpl[n]; vt1 = vtpl[n+1];
  }
#pragma unroll
  for (int bi = 0; bi < 16; bi++) {
    float s0 = vt0, s1 = vt1;
#pragma unroll
    for (int l = 0; l < 10; l++) { float bb = betas_s[bi][l]; s0 += bb*sd0[l]; s1 += bb*sd1[l]; }
    acc0[bi] += s0; acc1[bi] += s1;
  }
#pragma unroll
  for (int bi = 0; bi < 16; bi++) { vp_s[bi][2*tid] = acc0[bi]; vp_s[bi][2*tid+1] = acc1[bi]; }
  __syncthreads();
  const int m = tid / 64;
  const int vl = tid % 64;
  const int va = v0 + vl, vb = v0 + vl + 64;
  const bool va_ok = (va < Vn), vb_ok = (vb < Vn);
  float Wr0[24], Wr1[24];
#pragma unroll
  for (int j = 0; j < 24; j++) { Wr0[j] = 0.f; Wr1[j] = 0.f; }
  if (va_ok) { const float4* wp = (const float4*)(W + (size_t)va*24);
#pragma unroll
    for (int q = 0; q < 6; q++) { float4 f = wp[q]; Wr0[4*q]=f.x; Wr0[4*q+1]=f.y; Wr0[4*q+2]=f.z; Wr0[4*q+3]=f.w; } }
  if (vb_ok) { const float4* wp = (const float4*)(W + (size_t)vb*24);
#pragma unroll
    for (int q = 0; q < 6; q++) { float4 f = wp[q]; Wr1[4*q]=f.x; Wr1[4*q+1]=f.y; Wr1[4*q+2]=f.z; Wr1[4*q+3]=f.w; } }
  for (int bi = 0; bi < 16; bi++) {
    float Ta0=0.f,Ta1=0.f,Ta2=0.f,Ta3=0.f, Tb0=0.f,Tb1=0.f,Tb2=0.f,Tb3=0.f;
    const float4* arb = (const float4*)(Ar_s[bi]);
#pragma unroll
    for (int j = 0; j < 24; j++) {
      float4 a = arb[j*3 + m];
      float wa = Wr0[j], wb = Wr1[j];
      Ta0 += wa*a.x; Ta1 += wa*a.y; Ta2 += wa*a.z; Ta3 += wa*a.w;
      Tb0 += wb*a.x; Tb1 += wb*a.y; Tb2 += wb*a.z; Tb3 += wb*a.w;
    }
    float tr = transl_s[bi][m];
    if (va_ok) {
      float x = vp_s[bi][vl*3+0], y = vp_s[bi][vl*3+1], z = vp_s[bi][vl*3+2];
      out[((size_t)(b0+bi)*Vn + va)*3 + m] = Ta0*x + Ta1*y + Ta2*z + Ta3 + tr;
    }
    if (vb_ok) {
      float x = vp_s[bi][(vl+64)*3+0], y = vp_s[bi][(vl+64)*3+1], z = vp_s[bi][(vl+64)*3+2];
      out[((size_t)(b0+bi)*Vn + vb)*3 + m] = Tb0*x + Tb1*y + Tb2*z + Tb3 + tr;
    }
  }
}

extern "C" void kernel_launch(void* const* d_in, const int* in_sizes, int n_in,
                              void* d_out, int out_size, void* d_ws, size_t ws_size,
                              hipStream_t stream)
{
  const float *betas=nullptr, *bpose=nullptr, *gorient=nullptr, *transl=nullptr,
              *vtpl=nullptr, *sdirs=nullptr, *pdirs=nullptr, *Jreg=nullptr, *W=nullptr;
  int seen1536 = 0, seen165360 = 0;
  for (int i = 0; i < n_in; i++) {
    const float* p = (const float*)d_in[i];
    switch (in_sizes[i]) {
      case 5120:    betas = p; break;
      case 35328:   bpose = p; break;
      case 20670:   vtpl  = p; break;
      case 206700:  sdirs = p; break;
      case 4278690: pdirs = p; break;
      case 1536:    if (seen1536++ == 0) gorient = p; else transl = p; break;
      case 165360:  if (seen165360++ == 0) Jreg = p; else W = p; break;
      default: break;
    }
  }
  float* out = (float*)d_out;

  float* ws   = (float*)d_ws;
  float* part = ws;                                   // 6336 f
  float* JS   = ws + 6336;                            // 720 f   (fallback)
  float* Jt   = ws + 7056;                            // 72 f    (fallback)
  float* pf   = ws + 7128;                            // 105984 f (fallback)
  float* Ar   = ws + 113112;                          // 147456 f (fallback)
  _Float16* pf_h = (_Float16*)(ws + 260568);          // 114688 h
  _Float16* B_h  = (_Float16*)(ws + 317912);          // 4644864 h
  _Float16* W_h  = (_Float16*)(ws + 2640344);         // 221184 h
  _Float16* Ar_h = (_Float16*)(ws + 2861528);         // 262144 h
  const size_t WS_NEED = (size_t)3123672 * 4;         // 12,494,688 bytes (conservative)
  const bool big = (ws_size >= WS_NEED);

  if (big) {
    k_prep<<<3324, 256, 0, stream>>>(Jreg, vtpl, sdirs, pdirs, W, part, B_h, W_h);
    k_pose2<<<64, 512, 0, stream>>>(betas, bpose, gorient, transl, part,
                                    pf_h, Ar_h, out + (size_t)Bn * Vn * 3);
    k_mm4<<<1792, 256, 0, stream>>>(pf_h, B_h, W_h, Ar_h, out);
  } else {
    k_jsjt_part<<<dim3(72, 8), 256, 0, stream>>>(Jreg, vtpl, sdirs, part);
    k_jsjt_red<<<1, 1024, 0, stream>>>(part, JS, Jt);
    k_pose_fb<<<Bn, 64, 0, stream>>>(betas, bpose, gorient, transl, JS, Jt, pf, Ar,
                                     out + (size_t)Bn * Vn * 3);
    k_verts_fb<<<dim3(32, 54), 192, 0, stream>>>(betas, transl, vtpl, sdirs,
                                                 pdirs, W, pf, Ar, out);
  }
}

// Round 12
// 53.381 us; speedup vs baseline: 6.2218x; 1.0986x over previous
//
#include <hip/hip_runtime.h>
#include <hip/hip_bf16.h>
#include <math.h>

#define Bn 512
#define Vn 6890
#define NBn 10
#define Pn 207
#define N3n 20670   // Vn*3
#define KP 224      // padded K: 0-206 pf, 207-216 betas, 217 vtpl_hi, 218 vtpl_lo
#define VPAD 6912   // padded vertex rows for W (108*64)

typedef __attribute__((ext_vector_type(8))) _Float16 half8;
typedef __attribute__((ext_vector_type(4))) float f32x4;

__constant__ int c_par[24] = {-1,0,0,0,1,2,3,4,5,6,7,8,9,9,9,12,13,14,16,17,18,19,20,21};
__constant__ int c_lvl[10] = {0,1,4,7,10,15,18,20,22,24};   // chain depth-level ranges

// ================= BIG PATH (fp16 MFMA) =================

// ---- k_prep: jsjt partials (0..191) U B f16 staged-conv (192..839) U W f16 (840..1703) ----
__global__ __launch_bounds__(256) void k_prep(
    const float* __restrict__ Jreg, const float* __restrict__ vtpl,
    const float* __restrict__ sdirs, const float* __restrict__ pdirs,
    const float* __restrict__ W, float* __restrict__ part,
    _Float16* __restrict__ B_h, _Float16* __restrict__ W_h)
{
  const int tid = threadIdx.x;
  __shared__ float wred[4][33];
  __shared__ __align__(16) float tile[224][36];

  if (blockIdx.x < 192) {
    // per-joint jsjt partials: w loaded once for 3 components, sdirs contiguous
    const int j = blockIdx.x % 24;
    const int chunk = blockIdx.x / 24;        // 0..7
    const int lane = tid & 63, wv = tid >> 6;
    const int vlo = chunk * 862;
    const int vhi = min(Vn, vlo + 862);
    float acc[33];
#pragma unroll
    for (int k = 0; k < 33; k++) acc[k] = 0.f;
    for (int v = vlo + tid; v < vhi; v += 256) {
      float w = Jreg[(size_t)j * Vn + v];
      const float* sp = sdirs + (size_t)v * 30;
#pragma unroll
      for (int c = 0; c < 3; c++) {
#pragma unroll
        for (int l = 0; l < 10; l++) acc[c*11 + l] += w * sp[c*10 + l];
        acc[c*11 + 10] += w * vtpl[v*3 + c];
      }
    }
#pragma unroll
    for (int k = 0; k < 33; k++) {
      float s = acc[k];
      for (int off = 32; off > 0; off >>= 1) s += __shfl_xor(s, off);
      if (lane == 0) wred[wv][k] = s;
    }
    __syncthreads();
    if (tid < 33) {
      float s = wred[0][tid] + wred[1][tid] + wred[2][tid] + wred[3][tid];
      int c = tid / 11, k = tid % 11;
      part[(size_t)chunk * 792 + (j*3 + c) * 11 + k] = s;
    }
  } else if (blockIdx.x < 840) {
    // B-conv: block owns 32 columns (128B-aligned) -> pdirs read exactly once, coalesced
    const int p = blockIdx.x - 192;           // 0..647
    const int cols0 = p * 32;
    // stage pdirs rows 0..206 (float4, guarded at the ragged edge)
    for (int idx = tid; idx < 207 * 8; idx += 256) {
      int row = idx >> 3, cq = (idx & 7) << 2;
      int gc = cols0 + cq;
      float4 v4 = {0.f, 0.f, 0.f, 0.f};
      if (gc + 3 < N3n) {
        v4 = *(const float4*)(pdirs + (size_t)row * N3n + gc);
      } else if (gc < N3n) {
        float t[4];
#pragma unroll
        for (int e = 0; e < 4; e++) t[e] = (gc + e < N3n) ? pdirs[(size_t)row * N3n + gc + e] : 0.f;
        v4 = make_float4(t[0], t[1], t[2], t[3]);
      }
      *(float4*)&tile[row][cq] = v4;
    }
    // stage rows 207..223 (sdirs | vtpl_hi | vtpl_lo | zeros)
    for (int idx = tid; idx < 17 * 32; idx += 256) {
      int r = idx >> 5, cc = idx & 31;
      int k = 207 + r;
      int gc = cols0 + cc;
      float f = 0.f;
      if (gc < N3n) {
        if (k < 217)      f = sdirs[(size_t)gc * 10 + (k - 207)];
        else if (k == 217) f = (float)(_Float16)vtpl[gc];
        else if (k == 218) { float tv = vtpl[gc]; f = tv - (float)(_Float16)tv; }
      }
      tile[k][cc] = f;
    }
    __syncthreads();
    // emit fragment-linear f16: 14 (nt-local, s) pairs x 64 lanes
    for (int idx = tid; idx < 896; idx += 256) {
      int pl = idx >> 6;                      // 0..13
      int l  = idx & 63;
      int ntl = pl / 7, s = pl % 7;
      int colc = ntl * 16 + (l & 15);
      int kb = s * 32 + ((l >> 4) << 3);
      half8 hv;
#pragma unroll
      for (int j = 0; j < 8; j++) hv[j] = (_Float16)tile[kb + j][colc];
      *(half8*)(B_h + ((size_t)(2 * p + ntl) * 7 + s) * 512 + (size_t)l * 8) = hv;
    }
  } else {
    int idx = (blockIdx.x - 840) * 256 + tid;
    if (idx < VPAD * 32) {
      int v = idx >> 5, k = idx & 31;
      float f;
      if (v < Vn && k < 24) f = W[(size_t)v * 24 + k];
      else if (k == 24)     f = 1.0f;     // affine slot pairs with Ar[.,24] = transl
      else                  f = 0.f;
      W_h[idx] = (_Float16)f;
    }
  }
}

// ---- k_pose2: 4 batches/block (1 wave each), shared jsjt reduce ----
__global__ __launch_bounds__(256) void k_pose2(
    const float* __restrict__ betas, const float* __restrict__ body_pose,
    const float* __restrict__ gorient, const float* __restrict__ transl,
    const float* __restrict__ part,
    _Float16* __restrict__ pf_h, _Float16* __restrict__ Ar_h,
    float* __restrict__ out_joints)
{
  const int tid = threadIdx.x;
  const int wave = tid >> 6;
  const int lane = tid & 63;
  const int b = blockIdx.x * 4 + wave;

  __shared__ float JS_s[720];
  __shared__ float Jt_s[72];
  __shared__ float Rs[4][24][9];
  __shared__ float jnt[4][24][3];
  __shared__ float rel[4][24][3];
  __shared__ float A_s[4][24][12];

  for (int idx = tid; idx < 792; idx += 256) {
    float s = 0.f;
#pragma unroll
    for (int y = 0; y < 8; y++) s += part[(size_t)y * 792 + idx];
    int bid = idx / 11, k = idx % 11;
    if (k < 10) JS_s[bid * 10 + k] = s;
    else        Jt_s[bid] = s;
  }

  if (lane < 24) {
    float x, y, z;
    if (lane == 0) { x = gorient[b*3+0]; y = gorient[b*3+1]; z = gorient[b*3+2]; }
    else { int o = b*69 + (lane-1)*3; x = body_pose[o]; y = body_pose[o+1]; z = body_pose[o+2]; }
    float ang = sqrtf(x*x + y*y + z*z) + 1e-8f;
    float inv = 1.0f / ang;
    float ux = x*inv, uy = y*inv, uz = z*inv;
    float s = sinf(ang), cc = cosf(ang), omc = 1.0f - cc;
    float K[9] = {0.f, -uz, uy,  uz, 0.f, -ux,  -uy, ux, 0.f};
#pragma unroll
    for (int mm = 0; mm < 3; mm++)
#pragma unroll
      for (int nn = 0; nn < 3; nn++) {
        float kk = K[mm*3+0]*K[0+nn] + K[mm*3+1]*K[3+nn] + K[mm*3+2]*K[6+nn];
        float eye = (mm == nn) ? 1.0f : 0.0f;
        Rs[wave][lane][mm*3+nn] = eye + s*K[mm*3+nn] + omc*kk;
      }
  }
  __syncthreads();   // JS_s + Rs visible

  for (int idx = lane; idx < 72; idx += 64) {
    float a = Jt_s[idx];
#pragma unroll
    for (int l = 0; l < 10; l++) a += betas[b*10 + l] * JS_s[idx*10 + l];
    jnt[wave][idx/3][idx%3] = a;
  }
  for (int idx = lane; idx < KP; idx += 64) {
    float f = 0.f;
    if (idx < Pn) {
      int j = 1 + idx / 9, e = idx % 9;
      float eye = (e == 0 || e == 4 || e == 8) ? 1.0f : 0.0f;
      f = Rs[wave][j][e] - eye;
    } else if (idx < 217) {
      f = betas[b*10 + (idx - 207)];
    } else if (idx < 219) {
      f = 1.0f;
    }
    pf_h[(size_t)b * KP + idx] = (_Float16)f;
  }
  __syncthreads();
  for (int idx = lane; idx < 72; idx += 64) {
    int j = idx/3, cc = idx%3;
    float r = jnt[wave][j][cc];
    if (j > 0) r -= jnt[wave][c_par[j]][cc];
    rel[wave][j][cc] = r;
  }
  __syncthreads();
  if (lane < 12) {
    int m = lane/4, nn = lane%4;
    A_s[wave][0][lane] = (nn < 3) ? Rs[wave][0][m*3+nn] : rel[wave][0][m];
  }
  __syncthreads();
  for (int lev = 1; lev <= 8; lev++) {
    const int s0 = c_lvl[lev], s1 = c_lvl[lev + 1];
    const int jj = lane / 12, r = lane % 12;
    if (jj < s1 - s0) {
      const int i = s0 + jj;
      const int p = c_par[i];
      const int m = r >> 2, nn = r & 3;
      float v;
      if (nn < 3)
        v = A_s[wave][p][m*4+0]*Rs[wave][i][0+nn] + A_s[wave][p][m*4+1]*Rs[wave][i][3+nn] + A_s[wave][p][m*4+2]*Rs[wave][i][6+nn];
      else
        v = A_s[wave][p][m*4+0]*rel[wave][i][0] + A_s[wave][p][m*4+1]*rel[wave][i][1] + A_s[wave][p][m*4+2]*rel[wave][i][2] + A_s[wave][p][m*4+3];
      A_s[wave][i][r] = v;
    }
    __syncthreads();
  }
  for (int idx = lane; idx < 72; idx += 64) {
    int j = idx/3, cc = idx%3;
    out_joints[(size_t)b * 72 + idx] = A_s[wave][j][cc*4+3] + transl[b*3+cc];
  }
  for (int idx = lane; idx < 512; idx += 64) {
    int e = idx >> 5, k = idx & 31;
    float a = 0.f;
    if (e < 12 && k < 24) {
      int m = e >> 2, nn = e & 3;
      if (nn < 3) a = A_s[wave][k][m*4+nn];
      else a = A_s[wave][k][m*4+3] - (A_s[wave][k][m*4+0]*jnt[wave][k][0] + A_s[wave][k][m*4+1]*jnt[wave][k][1] + A_s[wave][k][m*4+2]*jnt[wave][k][2]);
    } else if (k == 24 && e < 12 && (e & 3) == 3) {
      a = transl[b*3 + (e >> 2)];
    }
    Ar_h[(size_t)b * 512 + idx] = (_Float16)a;
  }
}

// ---- k_mm5: 32 batches x 64 vertices, fp16 MFMA, fp32 vpT (XOR-swizzled, b128 LDS ops) ----
// grid 1792: r8 = lin&7 (XCD slot), k2 = lin>>3; b_t = k2&15, m8 = k2>>4; v_t = r8*14+m8.
__global__ __launch_bounds__(256) void k_mm5(
    const _Float16* __restrict__ pf_h, const _Float16* __restrict__ B_h,
    const _Float16* __restrict__ W_h, const _Float16* __restrict__ Ar_h,
    float* __restrict__ out)
{
  const int lin = blockIdx.x;
  const int r8 = lin & 7;
  const int k2 = lin >> 3;
  const int b_t = k2 & 15;
  const int m8 = k2 >> 4;
  const int v_t = r8 * 14 + m8;
  if (v_t >= 108) return;

  const int tid = threadIdx.x;
  const int l = tid & 63;
  const int wave = tid >> 6;
  const int b0 = b_t * 32;
  const int v0 = v_t * 64;

  __shared__ __align__(16) float vpT[192 * 32];   // [col=3v+comp][row=batch], XOR-swizzled

  // ---- phase 1: v_posed GEMM; 2 A-row-tiles share B fragments
  const int c0 = l & 15;
  const int kk0 = (l >> 4) << 3;
  const int ntb = v_t * 12 + wave * 3;
  f32x4 acc[2][3];
#pragma unroll
  for (int t = 0; t < 2; t++)
#pragma unroll
    for (int n = 0; n < 3; n++) acc[t][n] = (f32x4){0.f, 0.f, 0.f, 0.f};

#pragma unroll
  for (int s = 0; s < 7; s++) {
    half8 bv[3];
#pragma unroll
    for (int n = 0; n < 3; n++)
      bv[n] = *(const half8*)(B_h + ((size_t)(ntb + n) * 7 + s) * 512 + l * 8);
#pragma unroll
    for (int t = 0; t < 2; t++) {
      half8 fa = *(const half8*)(pf_h + (size_t)(b0 + t * 16 + c0) * KP + kk0 + s * 32);
#pragma unroll
      for (int n = 0; n < 3; n++)
        acc[t][n] = __builtin_amdgcn_mfma_f32_16x16x32_f16(fa, bv[n], acc[t][n], 0, 0, 0);
    }
  }
  {
    const int rowq = (l >> 4) * 4;
#pragma unroll
    for (int t = 0; t < 2; t++)
#pragma unroll
      for (int n = 0; n < 3; n++) {
        const int col = wave * 48 + n * 16 + c0;
        const int rowb = t * 16 + rowq;
        *(f32x4*)&vpT[col * 32 + (rowb ^ ((col & 7) << 2))] = acc[t][n];
      }
  }
  __syncthreads();

  // ---- phase 2 + epilogue
  const int c = c0;             // vertex-within-16 / e-row in Ar frag
  const int g = l >> 4;         // output component (0..2); 3 = padding lanes
  const int kk = g << 3;

  half8 wh[4], ah[8];
#pragma unroll
  for (int mt = 0; mt < 4; mt++)
    wh[mt] = *(const half8*)(W_h + (size_t)(v0 + mt * 16 + c) * 32 + kk);
#pragma unroll
  for (int i = 0; i < 8; i++)
    ah[i] = *(const half8*)(Ar_h + (size_t)(b0 + wave * 8 + i) * 512 + c * 32 + kk);

#pragma unroll
  for (int mt = 0; mt < 4; mt++) {
    const int vl2 = mt * 16 + c;
    const int v = v0 + vl2;
    const bool ok = (g < 3) && (v < Vn);
    const int colx = 3 * vl2, coly = colx + 1, colz = colx + 2;
#pragma unroll
    for (int q = 0; q < 2; q++) {
      const int rb = wave * 8 + q * 4;
      f32x4 X = *(const f32x4*)&vpT[colx * 32 + (rb ^ ((colx & 7) << 2))];
      f32x4 Y = *(const f32x4*)&vpT[coly * 32 + (rb ^ ((coly & 7) << 2))];
      f32x4 Z = *(const f32x4*)&vpT[colz * 32 + (rb ^ ((colz & 7) << 2))];
#pragma unroll
      for (int r = 0; r < 4; r++) {
        f32x4 t = {0.f, 0.f, 0.f, 0.f};
        t = __builtin_amdgcn_mfma_f32_16x16x32_f16(ah[q * 4 + r], wh[mt], t, 0, 0, 0);
        if (ok) {
          const int bl = wave * 8 + q * 4 + r;
          out[((size_t)(b0 + bl) * Vn + v) * 3 + g] = t[0]*X[r] + t[1]*Y[r] + t[2]*Z[r] + t[3];
        }
      }
    }
  }
}

// ================= FALLBACK PATH (proven round-4 kernels) =================

__global__ __launch_bounds__(256) void k_jsjt_part(
    const float* __restrict__ Jreg, const float* __restrict__ vtpl,
    const float* __restrict__ sdirs, float* __restrict__ part)
{
  const int bid = blockIdx.x;
  const int chunk = blockIdx.y;
  const int j = bid / 3, c = bid % 3;
  const int tid = threadIdx.x;
  const int vlo = chunk * 862;
  const int vhi = min(Vn, vlo + 862);
  float acc[11];
#pragma unroll
  for (int k = 0; k < 11; k++) acc[k] = 0.f;
  for (int v = vlo + tid; v < vhi; v += 256) {
    float w = Jreg[(size_t)j * Vn + v];
    int n = v * 3 + c;
#pragma unroll
    for (int l = 0; l < 10; l++) acc[l] += w * sdirs[(size_t)n * 10 + l];
    acc[10] += w * vtpl[n];
  }
  __shared__ float red[256];
  for (int k = 0; k < 11; k++) {
    red[tid] = acc[k];
    __syncthreads();
    for (int s = 128; s > 0; s >>= 1) {
      if (tid < s) red[tid] += red[tid + s];
      __syncthreads();
    }
    if (tid == 0) part[(size_t)chunk * 792 + bid * 11 + k] = red[0];
    __syncthreads();
  }
}

__global__ __launch_bounds__(1024) void k_jsjt_red(
    const float* __restrict__ part, float* __restrict__ JS, float* __restrict__ Jt)
{
  const int t = threadIdx.x;
  if (t >= 792) return;
  float s = 0.f;
#pragma unroll
  for (int y = 0; y < 8; y++) s += part[(size_t)y * 792 + t];
  int bid = t / 11, k = t % 11;
  if (k < 10) JS[bid * 10 + k] = s;
  else        Jt[bid] = s;
}

__global__ __launch_bounds__(64) void k_pose_fb(
    const float* __restrict__ betas, const float* __restrict__ body_pose,
    const float* __restrict__ gorient, const float* __restrict__ transl,
    const float* __restrict__ JS, const float* __restrict__ Jt,
    float* __restrict__ pf_ws, float* __restrict__ Ar_ws,
    float* __restrict__ out_joints)
{
  const int b = blockIdx.x;
  const int tid = threadIdx.x;
  __shared__ float Rs[24][9];
  __shared__ float jnt[24][3];
  __shared__ float rel[24][3];
  __shared__ float A_s[24][12];

  if (tid < 24) {
    float x, y, z;
    if (tid == 0) { x = gorient[b*3+0]; y = gorient[b*3+1]; z = gorient[b*3+2]; }
    else { int o = b*69 + (tid-1)*3; x = body_pose[o]; y = body_pose[o+1]; z = body_pose[o+2]; }
    float ang = sqrtf(x*x + y*y + z*z) + 1e-8f;
    float inv = 1.0f / ang;
    float ux = x*inv, uy = y*inv, uz = z*inv;
    float s = sinf(ang), cc = cosf(ang), omc = 1.0f - cc;
    float K[9] = {0.f, -uz, uy,  uz, 0.f, -ux,  -uy, ux, 0.f};
#pragma unroll
    for (int mm = 0; mm < 3; mm++)
#pragma unroll
      for (int nn = 0; nn < 3; nn++) {
        float kk = K[mm*3+0]*K[0+nn] + K[mm*3+1]*K[3+nn] + K[mm*3+2]*K[6+nn];
        float eye = (mm == nn) ? 1.0f : 0.0f;
        Rs[tid][mm*3+nn] = eye + s*K[mm*3+nn] + omc*kk;
      }
  }
  for (int idx = tid; idx < 72; idx += 64) {
    float a = Jt[idx];
#pragma unroll
    for (int l = 0; l < 10; l++) a += betas[b*10 + l] * JS[idx*10 + l];
    jnt[idx/3][idx%3] = a;
  }
  __syncthreads();
  for (int idx = tid; idx < Pn; idx += 64) {
    int j = 1 + idx / 9, e = idx % 9;
    float eye = (e == 0 || e == 4 || e == 8) ? 1.0f : 0.0f;
    pf_ws[(size_t)b * Pn + idx] = Rs[j][e] - eye;
  }
  for (int idx = tid; idx < 72; idx += 64) {
    int j = idx/3, cc = idx%3;
    float r = jnt[j][cc];
    if (j > 0) r -= jnt[c_par[j]][cc];
    rel[j][cc] = r;
  }
  __syncthreads();
  if (tid < 12) {
    int m = tid/4, nn = tid%4;
    A_s[0][tid] = (nn < 3) ? Rs[0][m*3+nn] : rel[0][m];
  }
  __syncthreads();
  for (int i = 1; i < 24; i++) {
    if (tid < 12) {
      int m = tid/4, nn = tid%4;
      int p = c_par[i];
      float v;
      if (nn < 3)
        v = A_s[p][m*4+0]*Rs[i][0+nn] + A_s[p][m*4+1]*Rs[i][3+nn] + A_s[p][m*4+2]*Rs[i][6+nn];
      else
        v = A_s[p][m*4+0]*rel[i][0] + A_s[p][m*4+1]*rel[i][1] + A_s[p][m*4+2]*rel[i][2] + A_s[p][m*4+3];
      A_s[i][tid] = v;
    }
    __syncthreads();
  }
  for (int idx = tid; idx < 72; idx += 64) {
    int j = idx/3, cc = idx%3;
    out_joints[(size_t)b * 72 + idx] = A_s[j][cc*4+3] + transl[b*3+cc];
  }
  for (int idx = tid; idx < 288; idx += 64) {
    int j = idx/12, r = idx%12, m = r/4, nn = r%4;
    float v;
    if (nn < 3) v = A_s[j][m*4+nn];
    else v = A_s[j][m*4+3] - (A_s[j][m*4+0]*jnt[j][0] + A_s[j][m*4+1]*jnt[j][1] + A_s[j][m*4+2]*jnt[j][2]);
    Ar_ws[(size_t)b * 288 + idx] = v;
  }
}

__global__ __launch_bounds__(192) void k_verts_fb(
    const float* __restrict__ betas, const float* __restrict__ transl,
    const float* __restrict__ vtpl, const float* __restrict__ sdirs,
    const float* __restrict__ pdirs, const float* __restrict__ W,
    const float* __restrict__ pf_ws, const float* __restrict__ Ar_ws,
    float* __restrict__ out)
{
  const int tid = threadIdx.x;
  const int b0 = blockIdx.x * 16;
  const int v0 = blockIdx.y * 128;
  const int n0 = v0 * 3;
  __shared__ __align__(16) float pf_s[Pn][16];
  __shared__ __align__(16) float Ar_s[16][288];
  __shared__ __align__(16) float vp_s[16][384];
  __shared__ float betas_s[16][NBn];
  __shared__ float transl_s[16][3];
  for (int idx = tid; idx < Pn * 16; idx += 192) {
    int p = idx >> 4, bi = idx & 15;
    pf_s[p][bi] = pf_ws[(size_t)(b0 + bi) * Pn + p];
  }
  for (int idx = tid; idx < 16 * 288; idx += 192)
    Ar_s[idx / 288][idx % 288] = Ar_ws[(size_t)b0 * 288 + idx];
  for (int idx = tid; idx < 16 * NBn; idx += 192)
    betas_s[idx / NBn][idx % NBn] = betas[(size_t)b0 * NBn + idx];
  for (int idx = tid; idx < 48; idx += 192)
    transl_s[idx / 3][idx % 3] = transl[(size_t)b0 * 3 + idx];
  __syncthreads();
  const int n = n0 + 2 * tid;
  const bool valid = (n < N3n);
  float acc0[16], acc1[16];
#pragma unroll
  for (int i = 0; i < 16; i++) { acc0[i] = 0.f; acc1[i] = 0.f; }
  for (int p = 0; p < Pn; p++) {
    float pd0 = 0.f, pd1 = 0.f;
    if (valid) { float2 t = *(const float2*)(pdirs + (size_t)p * N3n + n); pd0 = t.x; pd1 = t.y; }
    const float4* row = (const float4*)(pf_s[p]);
#pragma unroll
    for (int q = 0; q < 4; q++) {
      float4 f = row[q];
      acc0[4*q+0] += f.x * pd0;  acc1[4*q+0] += f.x * pd1;
      acc0[4*q+1] += f.y * pd0;  acc1[4*q+1] += f.y * pd1;
      acc0[4*q+2] += f.z * pd0;  acc1[4*q+2] += f.z * pd1;
      acc0[4*q+3] += f.w * pd0;  acc1[4*q+3] += f.w * pd1;
    }
  }
  float sd0[10], sd1[10], vt0 = 0.f, vt1 = 0.f;
#pragma unroll
  for (int l = 0; l < 10; l++) { sd0[l] = 0.f; sd1[l] = 0.f; }
  if (valid) {
    for (int l = 0; l < 10; l++) { sd0[l] = sdirs[(size_t)n*10 + l]; sd1[l] = sdirs[(size_t)n*10 + 10 + l]; }
    vt0 = vtpl[n]; vt1 = vtpl[n+1];
  }
#pragma unroll
  for (int bi = 0; bi < 16; bi++) {
    float s0 = vt0, s1 = vt1;
#pragma unroll
    for (int l = 0; l < 10; l++) { float bb = betas_s[bi][l]; s0 += bb*sd0[l]; s1 += bb*sd1[l]; }
    acc0[bi] += s0; acc1[bi] += s1;
  }
#pragma unroll
  for (int bi = 0; bi < 16; bi++) { vp_s[bi][2*tid] = acc0[bi]; vp_s[bi][2*tid+1] = acc1[bi]; }
  __syncthreads();
  const int m = tid / 64;
  const int vl = tid % 64;
  const int va = v0 + vl, vb = v0 + vl + 64;
  const bool va_ok = (va < Vn), vb_ok = (vb < Vn);
  float Wr0[24], Wr1[24];
#pragma unroll
  for (int j = 0; j < 24; j++) { Wr0[j] = 0.f; Wr1[j] = 0.f; }
  if (va_ok) { const float4* wp = (const float4*)(W + (size_t)va*24);
#pragma unroll
    for (int q = 0; q < 6; q++) { float4 f = wp[q]; Wr0[4*q]=f.x; Wr0[4*q+1]=f.y; Wr0[4*q+2]=f.z; Wr0[4*q+3]=f.w; } }
  if (vb_ok) { const float4* wp = (const float4*)(W + (size_t)vb*24);
#pragma unroll
    for (int q = 0; q < 6; q++) { float4 f = wp[q]; Wr1[4*q]=f.x; Wr1[4*q+1]=f.y; Wr1[4*q+2]=f.z; Wr1[4*q+3]=f.w; } }
  for (int bi = 0; bi < 16; bi++) {
    float Ta0=0.f,Ta1=0.f,Ta2=0.f,Ta3=0.f, Tb0=0.f,Tb1=0.f,Tb2=0.f,Tb3=0.f;
    const float4* arb = (const float4*)(Ar_s[bi]);
#pragma unroll
    for (int j = 0; j < 24; j++) {
      float4 a = arb[j*3 + m];
      float wa = Wr0[j], wb = Wr1[j];
      Ta0 += wa*a.x; Ta1 += wa*a.y; Ta2 += wa*a.z; Ta3 += wa*a.w;
      Tb0 += wb*a.x; Tb1 += wb*a.y; Tb2 += wb*a.z; Tb3 += wb*a.w;
    }
    float tr = transl_s[bi][m];
    if (va_ok) {
      float x = vp_s[bi][vl*3+0], y = vp_s[bi][vl*3+1], z = vp_s[bi][vl*3+2];
      out[((size_t)(b0+bi)*Vn + va)*3 + m] = Ta0*x + Ta1*y + Ta2*z + Ta3 + tr;
    }
    if (vb_ok) {
      float x = vp_s[bi][(vl+64)*3+0], y = vp_s[bi][(vl+64)*3+1], z = vp_s[bi][(vl+64)*3+2];
      out[((size_t)(b0+bi)*Vn + vb)*3 + m] = Tb0*x + Tb1*y + Tb2*z + Tb3 + tr;
    }
  }
}

extern "C" void kernel_launch(void* const* d_in, const int* in_sizes, int n_in,
                              void* d_out, int out_size, void* d_ws, size_t ws_size,
                              hipStream_t stream)
{
  const float *betas=nullptr, *bpose=nullptr, *gorient=nullptr, *transl=nullptr,
              *vtpl=nullptr, *sdirs=nullptr, *pdirs=nullptr, *Jreg=nullptr, *W=nullptr;
  int seen1536 = 0, seen165360 = 0;
  for (int i = 0; i < n_in; i++) {
    const float* p = (const float*)d_in[i];
    switch (in_sizes[i]) {
      case 5120:    betas = p; break;
      case 35328:   bpose = p; break;
      case 20670:   vtpl  = p; break;
      case 206700:  sdirs = p; break;
      case 4278690: pdirs = p; break;
      case 1536:    if (seen1536++ == 0) gorient = p; else transl = p; break;
      case 165360:  if (seen165360++ == 0) Jreg = p; else W = p; break;
      default: break;
    }
  }
  float* out = (float*)d_out;

  float* ws   = (float*)d_ws;
  float* part = ws;                                   // 6336 f
  float* JS   = ws + 6336;                            // 720 f   (fallback)
  float* Jt   = ws + 7056;                            // 72 f    (fallback)
  float* pf   = ws + 7128;                            // 105984 f (fallback)
  float* Ar   = ws + 113112;                          // 147456 f (fallback)
  _Float16* pf_h = (_Float16*)(ws + 260568);          // 114688 h
  _Float16* B_h  = (_Float16*)(ws + 317912);          // 4644864 h
  _Float16* W_h  = (_Float16*)(ws + 2640344);         // 221184 h
  _Float16* Ar_h = (_Float16*)(ws + 2861528);         // 262144 h
  const size_t WS_NEED = (size_t)3123672 * 4;         // 12,494,688 bytes (conservative)
  const bool big = (ws_size >= WS_NEED);

  if (big) {
    k_prep<<<1704, 256, 0, stream>>>(Jreg, vtpl, sdirs, pdirs, W, part, B_h, W_h);
    k_pose2<<<128, 256, 0, stream>>>(betas, bpose, gorient, transl, part,
                                     pf_h, Ar_h, out + (size_t)Bn * Vn * 3);
    k_mm5<<<1792, 256, 0, stream>>>(pf_h, B_h, W_h, Ar_h, out);
  } else {
    k_jsjt_part<<<dim3(72, 8), 256, 0, stream>>>(Jreg, vtpl, sdirs, part);
    k_jsjt_red<<<1, 1024, 0, stream>>>(part, JS, Jt);
    k_pose_fb<<<Bn, 64, 0, stream>>>(betas, bpose, gorient, transl, JS, Jt, pf, Ar,
                                     out + (size_t)Bn * Vn * 3);
    k_verts_fb<<<dim3(32, 54), 192, 0, stream>>>(betas, transl, vtpl, sdirs,
                                                 pdirs, W, pf, Ar, out);
  }
}